// Round 1
// baseline (444.961 us; speedup 1.0000x reference)
//
#include <hip/hip_runtime.h>
#include <hip/hip_bf16.h>

#define LTOT 2304
#define ECH  192
#define NCH  16
#define CCH  96   // chunks over L
#define SCH  24   // steps per chunk

__device__ __forceinline__ int permS(int k, int l) {
  if (k == 0) return l;
  if (k == 1) return LTOT - 1 - l;
  int m = (k == 2) ? l : (LTOT - 1 - l);
  return (m % 48) * 48 + (m / 48);
}

__device__ __forceinline__ float softplusf(float x) {
  return (x > 20.f) ? x : log1pf(__expf(x));
}

// ---------------- K1: in_proj GEMM (384x96) -> xi_pre (B,L,E), z (B,L,E) ----------------
__global__ __launch_bounds__(256) void k1_inproj(const float* __restrict__ x,
                                                 const float* __restrict__ W,
                                                 float* __restrict__ xi_pre,
                                                 float* __restrict__ z) {
  const int l0 = blockIdx.x * 64;
  const int o0 = blockIdx.y * 64;
  const int b  = blockIdx.z;
  __shared__ float xl[96 * 68];
  __shared__ float ol[4][64 * 17];
  const int tid = threadIdx.x;
  for (int idx = tid; idx < 96 * 64; idx += 256) {
    int c = idx >> 6, i = idx & 63;
    xl[c * 68 + i] = x[(b * 96 + c) * LTOT + l0 + i];
  }
  __syncthreads();
  const int lane = tid & 63, w = tid >> 6;
  const int ow = o0 + w * 16;
  float acc[16];
#pragma unroll
  for (int t = 0; t < 16; ++t) acc[t] = 0.f;
#pragma unroll 4
  for (int c = 0; c < 96; ++c) {
    float xv = xl[c * 68 + lane];
#pragma unroll
    for (int t = 0; t < 16; ++t) acc[t] = fmaf(W[(ow + t) * 96 + c], xv, acc[t]);
  }
#pragma unroll
  for (int t = 0; t < 16; ++t) ol[w][lane * 17 + t] = acc[t];
  __syncthreads();
  for (int idx = tid; idx < 64 * 64; idx += 256) {
    int li = idx >> 6, oi = idx & 63;
    float v = ol[oi >> 4][li * 17 + (oi & 15)];
    int o = o0 + oi;
    int l = l0 + li;
    if (o < ECH) xi_pre[(b * LTOT + l) * ECH + o] = v;
    else         z[(b * LTOT + l) * ECH + (o - ECH)] = v;
  }
}

// ---------------- K2: depthwise 3x3 conv + SiLU -> xi (B,L,E) ----------------
__global__ __launch_bounds__(256) void k2_dwconv(const float* __restrict__ xi_pre,
                                                 const float* __restrict__ cw,
                                                 const float* __restrict__ cb,
                                                 float* __restrict__ xi) {
  int g = blockIdx.x * 256 + threadIdx.x;
  if (g >= 2 * LTOT * ECH) return;
  int e = g % ECH; int l = (g / ECH) % LTOT; int b = g / (ECH * LTOT);
  int h = l / 48, wq = l % 48;
  float acc = cb[e];
#pragma unroll
  for (int kh = 0; kh < 3; ++kh) {
    int hh = h + kh - 1; if (hh < 0 || hh >= 48) continue;
#pragma unroll
    for (int kw = 0; kw < 3; ++kw) {
      int ww = wq + kw - 1; if (ww < 0 || ww >= 48) continue;
      acc = fmaf(cw[e * 9 + kh * 3 + kw], xi_pre[(b * LTOT + hh * 48 + ww) * ECH + e], acc);
    }
  }
  xi[g] = acc / (1.f + __expf(-acc));
}

// ---------------- K3: x_proj (38x192) + dt_proj (192x6) + softplus ----------------
__global__ __launch_bounds__(256) void k3_xproj(const float* __restrict__ xi,
                                                const float* __restrict__ xw,
                                                const float* __restrict__ dtw,
                                                const float* __restrict__ dtb,
                                                float* __restrict__ dlt,
                                                float* __restrict__ bT,
                                                float* __restrict__ cT) {
  const int l0 = blockIdx.x * 64;  // 36
  const int k  = blockIdx.y;       // 4
  const int b  = blockIdx.z;       // 2
  __shared__ float xs[64 * 193];
  __shared__ float dl6[6 * 65];
  const int tid = threadIdx.x;
  for (int idx = tid; idx < 64 * 192; idx += 256) {
    int j = idx / 192, c = idx - j * 192;
    int s = permS(k, l0 + j);
    xs[j * 193 + c] = xi[(b * LTOT + s) * ECH + c];
  }
  __syncthreads();
  const int i = tid & 63, rg = tid >> 6;
  const int bk = b * 4 + k;
  for (int r = rg; r < 38; r += 4) {
    const float* wr = xw + (k * 38 + r) * ECH;
    float acc = 0.f;
#pragma unroll 4
    for (int c = 0; c < ECH; ++c) acc = fmaf(wr[c], xs[i * 193 + c], acc);
    if (r < 6)       dl6[r * 65 + i] = acc;
    else if (r < 22) bT[((bk * LTOT) + l0 + i) * NCH + (r - 6)] = acc;
    else             cT[((bk * LTOT) + l0 + i) * NCH + (r - 22)] = acc;
  }
  __syncthreads();
  for (int idx = tid; idx < 64 * 192; idx += 256) {
    int j = idx / 192, d = idx - j * 192;
    float acc = dtb[k * ECH + d];
    const float* wd = dtw + (k * ECH + d) * 6;
#pragma unroll
    for (int r = 0; r < 6; ++r) acc = fmaf(wd[r], dl6[r * 65 + j], acc);
    dlt[((bk * LTOT) + l0 + j) * ECH + d] = softplusf(acc);
  }
}

// ---------------- K4a: chunk scan pass1 -> q (end states), Ts (chunk dlt sums) ----------------
__global__ __launch_bounds__(256) void k4a_scan1(const float* __restrict__ dlt,
                                                 const float* __restrict__ xi,
                                                 const float* __restrict__ bT,
                                                 const float* __restrict__ Alog,
                                                 float* __restrict__ q,
                                                 float* __restrict__ Ts) {
  const int cb = blockIdx.x;  // 24
  const int db = blockIdx.y;  // 3
  const int bk = blockIdx.z;  // 8
  const int b = bk >> 2, k = bk & 3;
  const int l0 = cb * 96;
  __shared__ float sdl[96 * 64];
  __shared__ float sxi[96 * 64];
  __shared__ float sb[96 * NCH];
  const int tid = threadIdx.x;
  const int dd = tid & 63, cg = tid >> 6;
  const int dg = db * 64 + dd;
  for (int j = cg; j < 96; j += 4) {
    sdl[j * 64 + dd] = dlt[(bk * LTOT + l0 + j) * ECH + dg];
    int s = permS(k, l0 + j);
    sxi[j * 64 + dd] = xi[(b * LTOT + s) * ECH + dg];
  }
  for (int idx = tid; idx < 96 * NCH; idx += 256) sb[idx] = bT[(bk * LTOT + l0) * NCH + idx];
  __syncthreads();
  float C1[16], C2[16], C3[16], h[16];
#pragma unroll
  for (int n = 0; n < 16; ++n) {
    float a = Alog[(k * ECH + dg) * NCH + n];
    C1[n] = a; C2[n] = 0.5f * a * a; C3[n] = (1.f / 6.f) * a * a * a;
    h[n] = 0.f;
  }
  float Tsum = 0.f;
  const int c = cb * 4 + cg;
  for (int i = 0; i < SCH; ++i) {
    int j = cg * SCH + i;
    float dl = sdl[j * 64 + dd];
    float u  = dl * sxi[j * 64 + dd];
    Tsum += dl;
    const float* bb = sb + j * NCH;
    if (dl <= 0.018f) {
#pragma unroll
      for (int n = 0; n < 16; ++n) {
        float e = fmaf(dl, fmaf(dl, fmaf(dl, -C3[n], C2[n]), -C1[n]), 1.f);
        h[n] = fmaf(e, h[n], u * bb[n]);
      }
    } else {
#pragma unroll
      for (int n = 0; n < 16; ++n) {
        float e = __expf(-C1[n] * dl);
        h[n] = fmaf(e, h[n], u * bb[n]);
      }
    }
  }
  float* qp = q + ((bk * CCH + c) * ECH + dg) * NCH;
#pragma unroll
  for (int n = 0; n < 16; ++n) qp[n] = h[n];
  Ts[(bk * CCH + c) * ECH + dg] = Tsum;
}

// ---------------- K4b: cross-chunk combine (q -> per-chunk init states, in place) ----------------
__global__ __launch_bounds__(256) void k4b_comb(const float* __restrict__ Alog,
                                                const float* __restrict__ Ts,
                                                float* __restrict__ q) {
  int t = blockIdx.x * 256 + threadIdx.x;
  if (t >= 8 * ECH * NCH) return;
  int n = t & 15, d = (t >> 4) % ECH, bk = t / (NCH * ECH);
  int k = bk & 3;
  float A = Alog[(k * ECH + d) * NCH + n];
  float h = 0.f;
  for (int c = 0; c < CCH; ++c) {
    int base = ((bk * CCH + c) * ECH + d) * NCH + n;
    float qc = q[base];
    q[base] = h;  // becomes h_init for chunk c
    float xv = A * Ts[(bk * CCH + c) * ECH + d];
    float P = (xv <= 0.05f)
                  ? fmaf(xv, fmaf(xv, fmaf(xv, -(1.f / 6.f), 0.5f), -1.f), 1.f)
                  : __expf(-xv);
    h = fmaf(P, h, qc);
  }
}

// ---------------- K4c: chunk scan pass2 -> y, atomic accumulate into ys (B,L,E) ----------------
__global__ __launch_bounds__(256) void k4c_scan2(const float* __restrict__ dlt,
                                                 const float* __restrict__ xi,
                                                 const float* __restrict__ bT,
                                                 const float* __restrict__ cT,
                                                 const float* __restrict__ Alog,
                                                 const float* __restrict__ hin,
                                                 float* __restrict__ ys) {
  const int cb = blockIdx.x;
  const int db = blockIdx.y;
  const int bk = blockIdx.z;
  const int b = bk >> 2, k = bk & 3;
  const int l0 = cb * 96;
  __shared__ float sdl[96 * 64];
  __shared__ float sxi[96 * 64];
  __shared__ float sb[96 * NCH];
  __shared__ float sc[96 * NCH];
  const int tid = threadIdx.x;
  const int dd = tid & 63, cg = tid >> 6;
  const int dg = db * 64 + dd;
  for (int j = cg; j < 96; j += 4) {
    sdl[j * 64 + dd] = dlt[(bk * LTOT + l0 + j) * ECH + dg];
    int s = permS(k, l0 + j);
    sxi[j * 64 + dd] = xi[(b * LTOT + s) * ECH + dg];
  }
  for (int idx = tid; idx < 96 * NCH; idx += 256) {
    sb[idx] = bT[(bk * LTOT + l0) * NCH + idx];
    sc[idx] = cT[(bk * LTOT + l0) * NCH + idx];
  }
  __syncthreads();
  float C1[16], C2[16], C3[16], h[16];
  const int c = cb * 4 + cg;
  const float* hp = hin + ((bk * CCH + c) * ECH + dg) * NCH;
#pragma unroll
  for (int n = 0; n < 16; ++n) {
    float a = Alog[(k * ECH + dg) * NCH + n];
    C1[n] = a; C2[n] = 0.5f * a * a; C3[n] = (1.f / 6.f) * a * a * a;
    h[n] = hp[n];
  }
  for (int i = 0; i < SCH; ++i) {
    int j = cg * SCH + i;
    int l = l0 + j;
    float dl = sdl[j * 64 + dd];
    float u  = dl * sxi[j * 64 + dd];
    const float* bb = sb + j * NCH;
    if (dl <= 0.018f) {
#pragma unroll
      for (int n = 0; n < 16; ++n) {
        float e = fmaf(dl, fmaf(dl, fmaf(dl, -C3[n], C2[n]), -C1[n]), 1.f);
        h[n] = fmaf(e, h[n], u * bb[n]);
      }
    } else {
#pragma unroll
      for (int n = 0; n < 16; ++n) {
        float e = __expf(-C1[n] * dl);
        h[n] = fmaf(e, h[n], u * bb[n]);
      }
    }
    const float* cc = sc + j * NCH;
    float y = 0.f;
#pragma unroll
    for (int n = 0; n < 16; ++n) y = fmaf(h[n], cc[n], y);
    int s = permS(k, l);
    atomicAdd(&ys[(b * LTOT + s) * ECH + dg], y);
  }
}

// ---------------- K5: LayerNorm over E (+Ds) then multiply by z (in-place over z) ----------------
__global__ __launch_bounds__(256) void k5_ln(const float* __restrict__ ys,
                                             const float* __restrict__ Ds,
                                             const float* __restrict__ lng,
                                             const float* __restrict__ lnb,
                                             float* __restrict__ zu) {
  int p = blockIdx.x * 4 + (threadIdx.x >> 6);
  int lane = threadIdx.x & 63;
  const float* yp = ys + p * ECH;
  float vd[3], sd[3];
#pragma unroll
  for (int t = 0; t < 3; ++t) {
    int d = lane + t * 64;
    vd[t] = yp[d];
    sd[t] = Ds[d] + Ds[ECH + d] + Ds[2 * ECH + d] + Ds[3 * ECH + d];
  }
  float s1 = vd[0] + vd[1] + vd[2];
  float s2 = sd[0] + sd[1] + sd[2];
#pragma unroll
  for (int off = 32; off > 0; off >>= 1) {
    s1 += __shfl_xor(s1, off, 64);
    s2 += __shfl_xor(s2, off, 64);
  }
  float mean_dot = s1 * (1.f / 192.f);
  float mean_sd  = s2 * (1.f / 192.f);
  float dev[3];
  float ss = 0.f;
#pragma unroll
  for (int t = 0; t < 3; ++t) {
    dev[t] = (vd[t] - mean_dot) + (sd[t] - mean_sd);
    ss = fmaf(dev[t], dev[t], ss);
  }
#pragma unroll
  for (int off = 32; off > 0; off >>= 1) ss += __shfl_xor(ss, off, 64);
  float rstd = 1.f / sqrtf(ss * (1.f / 192.f) + 1e-5f);
#pragma unroll
  for (int t = 0; t < 3; ++t) {
    int d = lane + t * 64;
    float yn = (dev[t] * rstd) * lng[d] + lnb[d];
    zu[p * ECH + d] = yn * zu[p * ECH + d];
  }
}

// ---------------- K6: c1 1x1 GEMM (384x192) + bn1 + relu -> t1 (B,L,384) ----------------
__global__ __launch_bounds__(256) void k6_c1(const float* __restrict__ u,
                                             const float* __restrict__ W,
                                             const float* __restrict__ c1b,
                                             const float* __restrict__ g1,
                                             const float* __restrict__ b1,
                                             const float* __restrict__ m1,
                                             const float* __restrict__ v1,
                                             float* __restrict__ t1) {
  const int l0 = blockIdx.x * 64;
  const int o0 = blockIdx.y * 64;
  const int b  = blockIdx.z;
  __shared__ float xl[192 * 68];  // reused as output staging after compute
  const int tid = threadIdx.x;
  for (int idx = tid; idx < 192 * 64; idx += 256) {
    int c = idx % 192, i = idx / 192;
    xl[c * 68 + i] = u[(b * LTOT + l0 + i) * ECH + c];
  }
  __syncthreads();
  const int lane = tid & 63, w = tid >> 6;
  const int ow = o0 + w * 16;
  float acc[16];
#pragma unroll
  for (int t = 0; t < 16; ++t) acc[t] = 0.f;
#pragma unroll 4
  for (int c = 0; c < 192; ++c) {
    float xv = xl[c * 68 + lane];
#pragma unroll
    for (int t = 0; t < 16; ++t) acc[t] = fmaf(W[(ow + t) * ECH + c], xv, acc[t]);
  }
  __syncthreads();  // everyone done reading xl
  float* ol = xl + w * (64 * 17);
#pragma unroll
  for (int t = 0; t < 16; ++t) {
    int o = ow + t;
    float sc = g1[o] / sqrtf(v1[o] + 1e-5f);
    float val = (acc[t] + c1b[o] - m1[o]) * sc + b1[o];
    ol[lane * 17 + t] = fmaxf(val, 0.f);
  }
  __syncthreads();
  for (int idx = tid; idx < 64 * 64; idx += 256) {
    int li = idx >> 6, oi = idx & 63;
    t1[(b * LTOT + l0 + li) * 384 + o0 + oi] = xl[(oi >> 4) * (64 * 17) + li * 17 + (oi & 15)];
  }
}

// ---------------- K7: depthwise 3x3 on t1 + bn2 + relu -> t2 (B,L,384) ----------------
__global__ __launch_bounds__(256) void k7_dw2(const float* __restrict__ t1,
                                              const float* __restrict__ cw,
                                              const float* __restrict__ cb,
                                              const float* __restrict__ g2,
                                              const float* __restrict__ b2,
                                              const float* __restrict__ m2,
                                              const float* __restrict__ v2,
                                              float* __restrict__ t2) {
  int g = blockIdx.x * 256 + threadIdx.x;
  if (g >= 2 * LTOT * 384) return;
  int o = g % 384; int l = (g / 384) % LTOT; int b = g / (384 * LTOT);
  int h = l / 48, wq = l % 48;
  float acc = cb[o];
#pragma unroll
  for (int kh = 0; kh < 3; ++kh) {
    int hh = h + kh - 1; if (hh < 0 || hh >= 48) continue;
#pragma unroll
    for (int kw = 0; kw < 3; ++kw) {
      int ww = wq + kw - 1; if (ww < 0 || ww >= 48) continue;
      acc = fmaf(cw[o * 9 + kh * 3 + kw], t1[(b * LTOT + hh * 48 + ww) * 384 + o], acc);
    }
  }
  float sc = g2[o] / sqrtf(v2[o] + 1e-5f);
  float val = (acc - m2[o]) * sc + b2[o];
  t2[g] = fmaxf(val, 0.f);
}

// ---------------- K8: c3 1x1 GEMM (96x384) -> t3 (B,L,96) + SE partial sums ----------------
__global__ __launch_bounds__(192) void k8_c3(const float* __restrict__ t2,
                                             const float* __restrict__ W,
                                             const float* __restrict__ c3b,
                                             float* __restrict__ t3,
                                             float* __restrict__ se) {
  const int l0 = blockIdx.x * 64;  // 36
  const int ot = blockIdx.y;       // 2
  const int b  = blockIdx.z;
  __shared__ float xl[96 * 68];
  __shared__ float ol[3][64 * 17];
  const int tid = threadIdx.x;
  const int lane = tid & 63, w = tid / 64;  // w < 3
  const int ow = ot * 48 + w * 16;
  float acc[16];
#pragma unroll
  for (int t = 0; t < 16; ++t) acc[t] = c3b[ow + t];
  for (int kc = 0; kc < 4; ++kc) {
    __syncthreads();
    for (int idx = tid; idx < 96 * 64; idx += 192) {
      int c = idx % 96, i = idx / 96;
      xl[c * 68 + i] = t2[(b * LTOT + l0 + i) * 384 + kc * 96 + c];
    }
    __syncthreads();
#pragma unroll 4
    for (int c = 0; c < 96; ++c) {
      float xv = xl[c * 68 + lane];
#pragma unroll
      for (int t = 0; t < 16; ++t) acc[t] = fmaf(W[(ow + t) * 384 + kc * 96 + c], xv, acc[t]);
    }
  }
#pragma unroll
  for (int t = 0; t < 16; ++t) ol[w][lane * 17 + t] = acc[t];
  __syncthreads();
  for (int idx = tid; idx < 64 * 48; idx += 192) {
    int li = idx / 48, oi = idx % 48;
    t3[(b * LTOT + l0 + li) * 96 + ot * 48 + oi] = ol[oi >> 4][li * 17 + (oi & 15)];
  }
  if (tid < 48) {
    float ssum = 0.f;
#pragma unroll 8
    for (int li = 0; li < 64; ++li) ssum += ol[tid >> 4][li * 17 + (tid & 15)];
    atomicAdd(&se[b * 96 + ot * 48 + tid], ssum);
  }
}

// ---------------- K9a: SE MLP -> smul = 1 + sigmoid(...) ----------------
__global__ __launch_bounds__(256) void k9a_se(const float* __restrict__ se,
                                              const float* __restrict__ w1,
                                              const float* __restrict__ sb1,
                                              const float* __restrict__ w2,
                                              const float* __restrict__ sb2,
                                              float* __restrict__ smul) {
  __shared__ float sm[192];
  __shared__ float s1[96];
  int t = threadIdx.x;
  if (t < 192) sm[t] = se[t] * (1.f / 2304.f);
  __syncthreads();
  if (t < 96) {
    int b = t / 48, i = t % 48;
    float acc = sb1[i];
    for (int m = 0; m < 96; ++m) acc = fmaf(w1[i * 96 + m], sm[b * 96 + m], acc);
    s1[t] = fmaxf(acc, 0.f);
  }
  __syncthreads();
  if (t < 192) {
    int b = t / 96, j = t % 96;
    float acc = sb2[j];
    for (int i = 0; i < 48; ++i) acc = fmaf(w2[j * 48 + i], s1[b * 48 + i], acc);
    smul[t] = 1.f + 1.f / (1.f + __expf(-acc));
  }
}

// ---------------- K9b: out[b,j,l] = t3[b,l,j] * smul[b,j] ----------------
__global__ __launch_bounds__(256) void k9b_out(const float* __restrict__ t3,
                                               const float* __restrict__ smul,
                                               float* __restrict__ out) {
  int g = blockIdx.x * 256 + threadIdx.x;
  if (g >= 2 * 96 * LTOT) return;
  int l = g % LTOT; int j = (g / LTOT) % 96; int b = g / (LTOT * 96);
  out[g] = t3[(b * LTOT + l) * 96 + j] * smul[b * 96 + j];
}

extern "C" void kernel_launch(void* const* d_in, const int* in_sizes, int n_in,
                              void* d_out, int out_size, void* d_ws, size_t ws_size,
                              hipStream_t stream) {
  const float* x     = (const float*)d_in[0];
  const float* inw   = (const float*)d_in[1];
  const float* convw = (const float*)d_in[2];
  const float* convb = (const float*)d_in[3];
  const float* xpw   = (const float*)d_in[4];
  const float* dtw   = (const float*)d_in[5];
  const float* dtb   = (const float*)d_in[6];
  const float* Alog  = (const float*)d_in[7];
  const float* Ds    = (const float*)d_in[8];
  const float* lng   = (const float*)d_in[9];
  const float* lnb   = (const float*)d_in[10];
  const float* c1w   = (const float*)d_in[11];
  const float* c1b   = (const float*)d_in[12];
  const float* bn1g  = (const float*)d_in[13];
  const float* bn1b  = (const float*)d_in[14];
  const float* bn1m  = (const float*)d_in[15];
  const float* bn1v  = (const float*)d_in[16];
  const float* c2w   = (const float*)d_in[17];
  const float* c2b   = (const float*)d_in[18];
  const float* bn2g  = (const float*)d_in[19];
  const float* bn2b  = (const float*)d_in[20];
  const float* bn2m  = (const float*)d_in[21];
  const float* bn2v  = (const float*)d_in[22];
  const float* c3w   = (const float*)d_in[23];
  const float* c3b   = (const float*)d_in[24];
  const float* se1w  = (const float*)d_in[25];
  const float* se1b  = (const float*)d_in[26];
  const float* se2w  = (const float*)d_in[27];
  const float* se2b  = (const float*)d_in[28];

  float* ws = (float*)d_ws;
  float* xi_pre = ws;                    // 884736
  float* z      = ws + 884736;           // 884736  (becomes u after k5)
  float* xi     = ws + 1769472;          // 884736
  float* dlt    = ws + 2654208;          // 3538944 (reused as t1/t2)
  float* bT     = ws + 6193152;          // 589824
  float* cT     = ws + 6782976;          // 589824  (reused as t3)
  float* ys     = ws + 7372800;          // 884736
  float* q      = ws + 8257536;          // 2359296
  float* Ts     = ws + 10616832;         // 147456
  float* se     = ws + 10764288;         // 192
  float* smul   = ws + 10764480;         // 192
  float* t1 = dlt;
  float* t2 = dlt + 1769472;
  float* t3 = cT;

  hipMemsetAsync(ys, 0, 884736 * sizeof(float), stream);
  hipMemsetAsync(se, 0, 192 * sizeof(float), stream);

  k1_inproj<<<dim3(36, 6, 2), 256, 0, stream>>>(x, inw, xi_pre, z);
  k2_dwconv<<<3456, 256, 0, stream>>>(xi_pre, convw, convb, xi);
  k3_xproj<<<dim3(36, 4, 2), 256, 0, stream>>>(xi, xpw, dtw, dtb, dlt, bT, cT);
  k4a_scan1<<<dim3(24, 3, 8), 256, 0, stream>>>(dlt, xi, bT, Alog, q, Ts);
  k4b_comb<<<96, 256, 0, stream>>>(Alog, Ts, q);
  k4c_scan2<<<dim3(24, 3, 8), 256, 0, stream>>>(dlt, xi, bT, cT, Alog, q, ys);
  k5_ln<<<1152, 256, 0, stream>>>(ys, Ds, lng, lnb, z);
  k6_c1<<<dim3(36, 6, 2), 256, 0, stream>>>(z, c1w, c1b, bn1g, bn1b, bn1m, bn1v, t1);
  k7_dw2<<<6912, 256, 0, stream>>>(t1, c2w, c2b, bn2g, bn2b, bn2m, bn2v, t2);
  k8_c3<<<dim3(36, 2, 2), 192, 0, stream>>>(t2, c3w, c3b, t3, se);
  k9a_se<<<1, 256, 0, stream>>>(se, se1w, se1b, se2w, se2b, smul);
  k9b_out<<<1728, 256, 0, stream>>>(t3, smul, (float*)d_out);
}

// Round 2
// 430.281 us; speedup vs baseline: 1.0341x; 1.0341x over previous
//
#include <hip/hip_runtime.h>
#include <hip/hip_bf16.h>

#define LTOT 2304
#define ECH  192
#define NCH  16
#define CCH  96   // chunks over L
#define SCH  24   // steps per chunk

__device__ __forceinline__ int permS(int k, int l) {
  if (k == 0) return l;
  if (k == 1) return LTOT - 1 - l;
  int m = (k == 2) ? l : (LTOT - 1 - l);
  return (m % 48) * 48 + (m / 48);
}

__device__ __forceinline__ float softplusf(float x) {
  return (x > 20.f) ? x : log1pf(__expf(x));
}

// ---------------- K1: in_proj GEMM (384x96) -> xi_pre (B,L,E), z (B,L,E) ----------------
__global__ __launch_bounds__(256) void k1_inproj(const float* __restrict__ x,
                                                 const float* __restrict__ W,
                                                 float* __restrict__ xi_pre,
                                                 float* __restrict__ z) {
  const int l0 = blockIdx.x * 64;
  const int o0 = blockIdx.y * 64;
  const int b  = blockIdx.z;
  __shared__ float xl[96 * 68];
  __shared__ float ol[4][64 * 17];
  const int tid = threadIdx.x;
  for (int idx = tid; idx < 96 * 64; idx += 256) {
    int c = idx >> 6, i = idx & 63;
    xl[c * 68 + i] = x[(b * 96 + c) * LTOT + l0 + i];
  }
  __syncthreads();
  const int lane = tid & 63, w = tid >> 6;
  const int ow = o0 + w * 16;
  float acc[16];
#pragma unroll
  for (int t = 0; t < 16; ++t) acc[t] = 0.f;
#pragma unroll 4
  for (int c = 0; c < 96; ++c) {
    float xv = xl[c * 68 + lane];
#pragma unroll
    for (int t = 0; t < 16; ++t) acc[t] = fmaf(W[(ow + t) * 96 + c], xv, acc[t]);
  }
#pragma unroll
  for (int t = 0; t < 16; ++t) ol[w][lane * 17 + t] = acc[t];
  __syncthreads();
  for (int idx = tid; idx < 64 * 64; idx += 256) {
    int li = idx >> 6, oi = idx & 63;
    float v = ol[oi >> 4][li * 17 + (oi & 15)];
    int o = o0 + oi;
    int l = l0 + li;
    if (o < ECH) xi_pre[(b * LTOT + l) * ECH + o] = v;
    else         z[(b * LTOT + l) * ECH + (o - ECH)] = v;
  }
}

// ---------------- K2: depthwise 3x3 conv + SiLU -> xi (B,L,E) ----------------
__global__ __launch_bounds__(256) void k2_dwconv(const float* __restrict__ xi_pre,
                                                 const float* __restrict__ cw,
                                                 const float* __restrict__ cb,
                                                 float* __restrict__ xi) {
  int g = blockIdx.x * 256 + threadIdx.x;
  if (g >= 2 * LTOT * ECH) return;
  int e = g % ECH; int l = (g / ECH) % LTOT; int b = g / (ECH * LTOT);
  int h = l / 48, wq = l % 48;
  float acc = cb[e];
#pragma unroll
  for (int kh = 0; kh < 3; ++kh) {
    int hh = h + kh - 1; if (hh < 0 || hh >= 48) continue;
#pragma unroll
    for (int kw = 0; kw < 3; ++kw) {
      int ww = wq + kw - 1; if (ww < 0 || ww >= 48) continue;
      acc = fmaf(cw[e * 9 + kh * 3 + kw], xi_pre[(b * LTOT + hh * 48 + ww) * ECH + e], acc);
    }
  }
  xi[g] = acc / (1.f + __expf(-acc));
}

// ---------------- K3: x_proj (38x192) + dt_proj (192x6) + softplus ----------------
// Rewritten: 10 independent accumulators per thread; W via wave-uniform (scalar)
// loads; xs staged c-major in LDS (pad 67 -> only 2-way bank aliasing, free).
__global__ __launch_bounds__(256) void k3_xproj(const float* __restrict__ xi,
                                                const float* __restrict__ xw,
                                                const float* __restrict__ dtw,
                                                const float* __restrict__ dtb,
                                                float* __restrict__ dlt,
                                                float* __restrict__ bT,
                                                float* __restrict__ cT) {
  const int l0 = blockIdx.x * 64;  // 36
  const int k  = blockIdx.y;       // 4
  const int b  = blockIdx.z;       // 2
  __shared__ float xs[192 * 67];   // [c][j]
  __shared__ float dl6[6 * 65];
  const int tid = threadIdx.x;
  for (int idx = tid; idx < 64 * 192; idx += 256) {
    int j = idx / 192, c = idx - j * 192;
    int s = permS(k, l0 + j);
    xs[c * 67 + j] = xi[(b * LTOT + s) * ECH + c];
  }
  __syncthreads();
  const int i = tid & 63, rg = tid >> 6;
  const int bk = b * 4 + k;
  const float* wbase = xw + k * 38 * ECH;
  float acc[10];
#pragma unroll
  for (int t = 0; t < 10; ++t) acc[t] = 0.f;
  int rowi[10];
#pragma unroll
  for (int t = 0; t < 10; ++t) {
    int r = rg + 4 * t;
    rowi[t] = (r < 38 ? r : 37) * ECH;  // clamp keeps loads in-bounds; store guarded
  }
#pragma unroll 4
  for (int c = 0; c < 192; ++c) {
    float xv = xs[c * 67 + i];
#pragma unroll
    for (int t = 0; t < 10; ++t) acc[t] = fmaf(wbase[rowi[t] + c], xv, acc[t]);
  }
#pragma unroll
  for (int t = 0; t < 10; ++t) {
    int r = rg + 4 * t;
    if (r >= 38) continue;
    if (r < 6)       dl6[r * 65 + i] = acc[t];
    else if (r < 22) bT[((bk * LTOT) + l0 + i) * NCH + (r - 6)] = acc[t];
    else             cT[((bk * LTOT) + l0 + i) * NCH + (r - 22)] = acc[t];
  }
  __syncthreads();
  for (int idx = tid; idx < 64 * 192; idx += 256) {
    int j = idx / 192, d = idx - j * 192;
    float acc2 = dtb[k * ECH + d];
    const float* wd = dtw + (k * ECH + d) * 6;
#pragma unroll
    for (int r = 0; r < 6; ++r) acc2 = fmaf(wd[r], dl6[r * 65 + j], acc2);
    dlt[((bk * LTOT) + l0 + j) * ECH + d] = softplusf(acc2);
  }
}

// ---------------- K4a: chunk scan pass1 -> q (end states), Ts (chunk dlt sums) ----------------
__global__ __launch_bounds__(256) void k4a_scan1(const float* __restrict__ dlt,
                                                 const float* __restrict__ xi,
                                                 const float* __restrict__ bT,
                                                 const float* __restrict__ Alog,
                                                 float* __restrict__ q,
                                                 float* __restrict__ Ts) {
  const int cb = blockIdx.x;  // 24
  const int db = blockIdx.y;  // 3
  const int bk = blockIdx.z;  // 8
  const int b = bk >> 2, k = bk & 3;
  const int l0 = cb * 96;
  __shared__ float sdl[96 * 64];
  __shared__ float sxi[96 * 64];
  __shared__ float sb[96 * NCH];
  const int tid = threadIdx.x;
  const int dd = tid & 63, cg = tid >> 6;
  const int dg = db * 64 + dd;
  for (int j = cg; j < 96; j += 4) {
    sdl[j * 64 + dd] = dlt[(bk * LTOT + l0 + j) * ECH + dg];
    int s = permS(k, l0 + j);
    sxi[j * 64 + dd] = xi[(b * LTOT + s) * ECH + dg];
  }
  for (int idx = tid; idx < 96 * NCH; idx += 256) sb[idx] = bT[(bk * LTOT + l0) * NCH + idx];
  __syncthreads();
  float C1[16], C2[16], C3[16], h[16];
#pragma unroll
  for (int n = 0; n < 16; ++n) {
    float a = Alog[(k * ECH + dg) * NCH + n];
    C1[n] = a; C2[n] = 0.5f * a * a; C3[n] = (1.f / 6.f) * a * a * a;
    h[n] = 0.f;
  }
  float Tsum = 0.f;
  const int c = cb * 4 + cg;
  for (int i = 0; i < SCH; ++i) {
    int j = cg * SCH + i;
    float dl = sdl[j * 64 + dd];
    float u  = dl * sxi[j * 64 + dd];
    Tsum += dl;
    const float* bb = sb + j * NCH;
    if (dl <= 0.018f) {
#pragma unroll
      for (int n = 0; n < 16; ++n) {
        float e = fmaf(dl, fmaf(dl, fmaf(dl, -C3[n], C2[n]), -C1[n]), 1.f);
        h[n] = fmaf(e, h[n], u * bb[n]);
      }
    } else {
#pragma unroll
      for (int n = 0; n < 16; ++n) {
        float e = __expf(-C1[n] * dl);
        h[n] = fmaf(e, h[n], u * bb[n]);
      }
    }
  }
  float* qp = q + ((bk * CCH + c) * ECH + dg) * NCH;
#pragma unroll
  for (int n = 0; n < 16; ++n) qp[n] = h[n];
  Ts[(bk * CCH + c) * ECH + dg] = Tsum;
}

// ---------------- K4b: cross-chunk combine (q -> per-chunk init states, in place) ----------------
__global__ __launch_bounds__(256) void k4b_comb(const float* __restrict__ Alog,
                                                const float* __restrict__ Ts,
                                                float* __restrict__ q) {
  int t = blockIdx.x * 256 + threadIdx.x;
  if (t >= 8 * ECH * NCH) return;
  int n = t & 15, d = (t >> 4) % ECH, bk = t / (NCH * ECH);
  int k = bk & 3;
  float A = Alog[(k * ECH + d) * NCH + n];
  float h = 0.f;
  for (int c = 0; c < CCH; ++c) {
    int base = ((bk * CCH + c) * ECH + d) * NCH + n;
    float qc = q[base];
    q[base] = h;  // becomes h_init for chunk c
    float xv = A * Ts[(bk * CCH + c) * ECH + d];
    float P = (xv <= 0.05f)
                  ? fmaf(xv, fmaf(xv, fmaf(xv, -(1.f / 6.f), 0.5f), -1.f), 1.f)
                  : __expf(-xv);
    h = fmaf(P, h, qc);
  }
}

// ---------------- K4c: chunk scan pass2 -> y, atomic accumulate into ys (B,L,E) ----------------
__global__ __launch_bounds__(256) void k4c_scan2(const float* __restrict__ dlt,
                                                 const float* __restrict__ xi,
                                                 const float* __restrict__ bT,
                                                 const float* __restrict__ cT,
                                                 const float* __restrict__ Alog,
                                                 const float* __restrict__ hin,
                                                 float* __restrict__ ys) {
  const int cb = blockIdx.x;
  const int db = blockIdx.y;
  const int bk = blockIdx.z;
  const int b = bk >> 2, k = bk & 3;
  const int l0 = cb * 96;
  __shared__ float sdl[96 * 64];
  __shared__ float sxi[96 * 64];
  __shared__ float sb[96 * NCH];
  __shared__ float sc[96 * NCH];
  const int tid = threadIdx.x;
  const int dd = tid & 63, cg = tid >> 6;
  const int dg = db * 64 + dd;
  for (int j = cg; j < 96; j += 4) {
    sdl[j * 64 + dd] = dlt[(bk * LTOT + l0 + j) * ECH + dg];
    int s = permS(k, l0 + j);
    sxi[j * 64 + dd] = xi[(b * LTOT + s) * ECH + dg];
  }
  for (int idx = tid; idx < 96 * NCH; idx += 256) {
    sb[idx] = bT[(bk * LTOT + l0) * NCH + idx];
    sc[idx] = cT[(bk * LTOT + l0) * NCH + idx];
  }
  __syncthreads();
  float C1[16], C2[16], C3[16], h[16];
  const int c = cb * 4 + cg;
  const float* hp = hin + ((bk * CCH + c) * ECH + dg) * NCH;
#pragma unroll
  for (int n = 0; n < 16; ++n) {
    float a = Alog[(k * ECH + dg) * NCH + n];
    C1[n] = a; C2[n] = 0.5f * a * a; C3[n] = (1.f / 6.f) * a * a * a;
    h[n] = hp[n];
  }
  for (int i = 0; i < SCH; ++i) {
    int j = cg * SCH + i;
    int l = l0 + j;
    float dl = sdl[j * 64 + dd];
    float u  = dl * sxi[j * 64 + dd];
    const float* bb = sb + j * NCH;
    if (dl <= 0.018f) {
#pragma unroll
      for (int n = 0; n < 16; ++n) {
        float e = fmaf(dl, fmaf(dl, fmaf(dl, -C3[n], C2[n]), -C1[n]), 1.f);
        h[n] = fmaf(e, h[n], u * bb[n]);
      }
    } else {
#pragma unroll
      for (int n = 0; n < 16; ++n) {
        float e = __expf(-C1[n] * dl);
        h[n] = fmaf(e, h[n], u * bb[n]);
      }
    }
    const float* cc = sc + j * NCH;
    float y = 0.f;
#pragma unroll
    for (int n = 0; n < 16; ++n) y = fmaf(h[n], cc[n], y);
    int s = permS(k, l);
    atomicAdd(&ys[(b * LTOT + s) * ECH + dg], y);
  }
}

// ---------------- K5: LayerNorm over E (+Ds) then multiply by z (in-place over z) ----------------
__global__ __launch_bounds__(256) void k5_ln(const float* __restrict__ ys,
                                             const float* __restrict__ Ds,
                                             const float* __restrict__ lng,
                                             const float* __restrict__ lnb,
                                             float* __restrict__ zu) {
  int p = blockIdx.x * 4 + (threadIdx.x >> 6);
  int lane = threadIdx.x & 63;
  const float* yp = ys + p * ECH;
  float vd[3], sd[3];
#pragma unroll
  for (int t = 0; t < 3; ++t) {
    int d = lane + t * 64;
    vd[t] = yp[d];
    sd[t] = Ds[d] + Ds[ECH + d] + Ds[2 * ECH + d] + Ds[3 * ECH + d];
  }
  float s1 = vd[0] + vd[1] + vd[2];
  float s2 = sd[0] + sd[1] + sd[2];
#pragma unroll
  for (int off = 32; off > 0; off >>= 1) {
    s1 += __shfl_xor(s1, off, 64);
    s2 += __shfl_xor(s2, off, 64);
  }
  float mean_dot = s1 * (1.f / 192.f);
  float mean_sd  = s2 * (1.f / 192.f);
  float dev[3];
  float ss = 0.f;
#pragma unroll
  for (int t = 0; t < 3; ++t) {
    dev[t] = (vd[t] - mean_dot) + (sd[t] - mean_sd);
    ss = fmaf(dev[t], dev[t], ss);
  }
#pragma unroll
  for (int off = 32; off > 0; off >>= 1) ss += __shfl_xor(ss, off, 64);
  float rstd = 1.f / sqrtf(ss * (1.f / 192.f) + 1e-5f);
#pragma unroll
  for (int t = 0; t < 3; ++t) {
    int d = lane + t * 64;
    float yn = (dev[t] * rstd) * lng[d] + lnb[d];
    zu[p * ECH + d] = yn * zu[p * ECH + d];
  }
}

// ---------------- K6: c1 1x1 GEMM (384x192) + bn1 + relu -> t1 (B,L,384) ----------------
__global__ __launch_bounds__(256) void k6_c1(const float* __restrict__ u,
                                             const float* __restrict__ W,
                                             const float* __restrict__ c1b,
                                             const float* __restrict__ g1,
                                             const float* __restrict__ b1,
                                             const float* __restrict__ m1,
                                             const float* __restrict__ v1,
                                             float* __restrict__ t1) {
  const int l0 = blockIdx.x * 64;
  const int o0 = blockIdx.y * 64;
  const int b  = blockIdx.z;
  __shared__ float xl[192 * 68];  // reused as output staging after compute
  const int tid = threadIdx.x;
  for (int idx = tid; idx < 192 * 64; idx += 256) {
    int c = idx % 192, i = idx / 192;
    xl[c * 68 + i] = u[(b * LTOT + l0 + i) * ECH + c];
  }
  __syncthreads();
  const int lane = tid & 63, w = tid >> 6;
  const int ow = o0 + w * 16;
  float acc[16];
#pragma unroll
  for (int t = 0; t < 16; ++t) acc[t] = 0.f;
#pragma unroll 4
  for (int c = 0; c < 192; ++c) {
    float xv = xl[c * 68 + lane];
#pragma unroll
    for (int t = 0; t < 16; ++t) acc[t] = fmaf(W[(ow + t) * ECH + c], xv, acc[t]);
  }
  __syncthreads();  // everyone done reading xl
  float* ol = xl + w * (64 * 17);
#pragma unroll
  for (int t = 0; t < 16; ++t) {
    int o = ow + t;
    float sc = g1[o] / sqrtf(v1[o] + 1e-5f);
    float val = (acc[t] + c1b[o] - m1[o]) * sc + b1[o];
    ol[lane * 17 + t] = fmaxf(val, 0.f);
  }
  __syncthreads();
  for (int idx = tid; idx < 64 * 64; idx += 256) {
    int li = idx >> 6, oi = idx & 63;
    t1[(b * LTOT + l0 + li) * 384 + o0 + oi] = xl[(oi >> 4) * (64 * 17) + li * 17 + (oi & 15)];
  }
}

// ---------------- K7: depthwise 3x3 on t1 + bn2 + relu -> t2 (B,L,384) ----------------
__global__ __launch_bounds__(256) void k7_dw2(const float* __restrict__ t1,
                                              const float* __restrict__ cw,
                                              const float* __restrict__ cb,
                                              const float* __restrict__ g2,
                                              const float* __restrict__ b2,
                                              const float* __restrict__ m2,
                                              const float* __restrict__ v2,
                                              float* __restrict__ t2) {
  int g = blockIdx.x * 256 + threadIdx.x;
  if (g >= 2 * LTOT * 384) return;
  int o = g % 384; int l = (g / 384) % LTOT; int b = g / (384 * LTOT);
  int h = l / 48, wq = l % 48;
  float acc = cb[o];
#pragma unroll
  for (int kh = 0; kh < 3; ++kh) {
    int hh = h + kh - 1; if (hh < 0 || hh >= 48) continue;
#pragma unroll
    for (int kw = 0; kw < 3; ++kw) {
      int ww = wq + kw - 1; if (ww < 0 || ww >= 48) continue;
      acc = fmaf(cw[o * 9 + kh * 3 + kw], t1[(b * LTOT + hh * 48 + ww) * 384 + o], acc);
    }
  }
  float sc = g2[o] / sqrtf(v2[o] + 1e-5f);
  float val = (acc - m2[o]) * sc + b2[o];
  t2[g] = fmaxf(val, 0.f);
}

// ---------------- K8: c3 1x1 GEMM (96x384) -> t3 (B,96,L) + SE partial sums ----------------
__global__ __launch_bounds__(192) void k8_c3(const float* __restrict__ t2,
                                             const float* __restrict__ W,
                                             const float* __restrict__ c3b,
                                             float* __restrict__ t3,
                                             float* __restrict__ se) {
  const int l0 = blockIdx.x * 64;  // 36
  const int ot = blockIdx.y;       // 2
  const int b  = blockIdx.z;
  __shared__ float xl[96 * 68];
  __shared__ float ol[3][64 * 17];
  const int tid = threadIdx.x;
  const int lane = tid & 63, w = tid / 64;  // w < 3
  const int ow = ot * 48 + w * 16;
  float acc[16];
#pragma unroll
  for (int t = 0; t < 16; ++t) acc[t] = c3b[ow + t];
  for (int kc = 0; kc < 4; ++kc) {
    __syncthreads();
    for (int idx = tid; idx < 96 * 64; idx += 192) {
      int c = idx % 96, i = idx / 96;
      xl[c * 68 + i] = t2[(b * LTOT + l0 + i) * 384 + kc * 96 + c];
    }
    __syncthreads();
#pragma unroll 4
    for (int c = 0; c < 96; ++c) {
      float xv = xl[c * 68 + lane];
#pragma unroll
      for (int t = 0; t < 16; ++t) acc[t] = fmaf(W[(ow + t) * 384 + kc * 96 + c], xv, acc[t]);
    }
  }
#pragma unroll
  for (int t = 0; t < 16; ++t) ol[w][lane * 17 + t] = acc[t];
  __syncthreads();
  // store t3 in OUTPUT layout (b, o, l): consecutive tid -> consecutive li -> coalesced
  for (int idx = tid; idx < 64 * 48; idx += 192) {
    int oi = idx / 64, li = idx % 64;
    t3[(b * 96 + ot * 48 + oi) * LTOT + l0 + li] = ol[oi >> 4][li * 17 + (oi & 15)];
  }
  if (tid < 48) {
    float ssum = 0.f;
#pragma unroll 8
    for (int li = 0; li < 64; ++li) ssum += ol[tid >> 4][li * 17 + (tid & 15)];
    atomicAdd(&se[b * 96 + ot * 48 + tid], ssum);
  }
}

// ---------------- K9a: SE MLP -> smul = 1 + sigmoid(...) ----------------
__global__ __launch_bounds__(256) void k9a_se(const float* __restrict__ se,
                                              const float* __restrict__ w1,
                                              const float* __restrict__ sb1,
                                              const float* __restrict__ w2,
                                              const float* __restrict__ sb2,
                                              float* __restrict__ smul) {
  __shared__ float sm[192];
  __shared__ float s1[96];
  int t = threadIdx.x;
  if (t < 192) sm[t] = se[t] * (1.f / 2304.f);
  __syncthreads();
  if (t < 96) {
    int b = t / 48, i = t % 48;
    float acc = sb1[i];
    for (int m = 0; m < 96; ++m) acc = fmaf(w1[i * 96 + m], sm[b * 96 + m], acc);
    s1[t] = fmaxf(acc, 0.f);
  }
  __syncthreads();
  if (t < 192) {
    int b = t / 96, j = t % 96;
    float acc = sb2[j];
    for (int i = 0; i < 48; ++i) acc = fmaf(w2[j * 48 + i], s1[b * 48 + i], acc);
    smul[t] = 1.f + 1.f / (1.f + __expf(-acc));
  }
}

// ---------------- K9b: out[b,j,l] = t3[b,j,l] * smul[b,j] (pure streaming) ----------------
__global__ __launch_bounds__(256) void k9b_out(const float* __restrict__ t3,
                                               const float* __restrict__ smul,
                                               float* __restrict__ out) {
  int g = blockIdx.x * 256 + threadIdx.x;
  if (g >= 2 * 96 * LTOT) return;
  int bj = g / LTOT;
  out[g] = t3[g] * smul[bj];
}

extern "C" void kernel_launch(void* const* d_in, const int* in_sizes, int n_in,
                              void* d_out, int out_size, void* d_ws, size_t ws_size,
                              hipStream_t stream) {
  const float* x     = (const float*)d_in[0];
  const float* inw   = (const float*)d_in[1];
  const float* convw = (const float*)d_in[2];
  const float* convb = (const float*)d_in[3];
  const float* xpw   = (const float*)d_in[4];
  const float* dtw   = (const float*)d_in[5];
  const float* dtb   = (const float*)d_in[6];
  const float* Alog  = (const float*)d_in[7];
  const float* Ds    = (const float*)d_in[8];
  const float* lng   = (const float*)d_in[9];
  const float* lnb   = (const float*)d_in[10];
  const float* c1w   = (const float*)d_in[11];
  const float* c1b   = (const float*)d_in[12];
  const float* bn1g  = (const float*)d_in[13];
  const float* bn1b  = (const float*)d_in[14];
  const float* bn1m  = (const float*)d_in[15];
  const float* bn1v  = (const float*)d_in[16];
  const float* c2w   = (const float*)d_in[17];
  const float* c2b   = (const float*)d_in[18];
  const float* bn2g  = (const float*)d_in[19];
  const float* bn2b  = (const float*)d_in[20];
  const float* bn2m  = (const float*)d_in[21];
  const float* bn2v  = (const float*)d_in[22];
  const float* c3w   = (const float*)d_in[23];
  const float* c3b   = (const float*)d_in[24];
  const float* se1w  = (const float*)d_in[25];
  const float* se1b  = (const float*)d_in[26];
  const float* se2w  = (const float*)d_in[27];
  const float* se2b  = (const float*)d_in[28];

  float* ws = (float*)d_ws;
  float* xi_pre = ws;                    // 884736
  float* z      = ws + 884736;           // 884736  (becomes u after k5)
  float* xi     = ws + 1769472;          // 884736
  float* dlt    = ws + 2654208;          // 3538944 (reused as t1/t2)
  float* bT     = ws + 6193152;          // 589824
  float* cT     = ws + 6782976;          // 589824  (reused as t3)
  float* ys     = ws + 7372800;          // 884736
  float* q      = ws + 8257536;          // 2359296
  float* Ts     = ws + 10616832;         // 147456
  float* se     = ws + 10764288;         // 192
  float* smul   = ws + 10764480;         // 192
  float* t1 = dlt;
  float* t2 = dlt + 1769472;
  float* t3 = cT;

  hipMemsetAsync(ys, 0, 884736 * sizeof(float), stream);
  hipMemsetAsync(se, 0, 192 * sizeof(float), stream);

  k1_inproj<<<dim3(36, 6, 2), 256, 0, stream>>>(x, inw, xi_pre, z);
  k2_dwconv<<<3456, 256, 0, stream>>>(xi_pre, convw, convb, xi);
  k3_xproj<<<dim3(36, 4, 2), 256, 0, stream>>>(xi, xpw, dtw, dtb, dlt, bT, cT);
  k4a_scan1<<<dim3(24, 3, 8), 256, 0, stream>>>(dlt, xi, bT, Alog, q, Ts);
  k4b_comb<<<96, 256, 0, stream>>>(Alog, Ts, q);
  k4c_scan2<<<dim3(24, 3, 8), 256, 0, stream>>>(dlt, xi, bT, cT, Alog, q, ys);
  k5_ln<<<1152, 256, 0, stream>>>(ys, Ds, lng, lnb, z);
  k6_c1<<<dim3(36, 6, 2), 256, 0, stream>>>(z, c1w, c1b, bn1g, bn1b, bn1m, bn1v, t1);
  k7_dw2<<<6912, 256, 0, stream>>>(t1, c2w, c2b, bn2g, bn2b, bn2m, bn2v, t2);
  k8_c3<<<dim3(36, 2, 2), 192, 0, stream>>>(t2, c3w, c3b, t3, se);
  k9a_se<<<1, 256, 0, stream>>>(se, se1w, se1b, se2w, se2b, smul);
  k9b_out<<<1728, 256, 0, stream>>>(t3, smul, (float*)d_out);
}

// Round 3
// 396.893 us; speedup vs baseline: 1.1211x; 1.0841x over previous
//
#include <hip/hip_runtime.h>
#include <hip/hip_bf16.h>

#define LTOT 2304
#define ECH  192
#define NCH  16
#define CCH  96   // chunks over L
#define SCH  24   // steps per chunk

__device__ __forceinline__ int permS(int k, int l) {
  if (k == 0) return l;
  if (k == 1) return LTOT - 1 - l;
  int m = (k == 2) ? l : (LTOT - 1 - l);
  return (m % 48) * 48 + (m / 48);
}

__device__ __forceinline__ float softplusf(float x) {
  return (x > 20.f) ? x : log1pf(__expf(x));
}

// ---------------- K1: in_proj GEMM (384x96) -> xi_pre (B,L,E), z (B,L,E) ----------------
__global__ __launch_bounds__(256) void k1_inproj(const float* __restrict__ x,
                                                 const float* __restrict__ W,
                                                 float* __restrict__ xi_pre,
                                                 float* __restrict__ z) {
  const int l0 = blockIdx.x * 64;
  const int o0 = blockIdx.y * 64;
  const int b  = blockIdx.z;
  __shared__ float xl[96 * 68];
  __shared__ float ol[4][64 * 17];
  const int tid = threadIdx.x;
  for (int idx = tid; idx < 96 * 64; idx += 256) {
    int c = idx >> 6, i = idx & 63;
    xl[c * 68 + i] = x[(b * 96 + c) * LTOT + l0 + i];
  }
  __syncthreads();
  const int lane = tid & 63;
  const int w = __builtin_amdgcn_readfirstlane(tid >> 6);  // SGPR -> W loads go scalar
  const int ow = o0 + w * 16;
  const float* __restrict__ Wp = W + ow * 96;  // scalar base
  float acc[16];
#pragma unroll
  for (int t = 0; t < 16; ++t) acc[t] = 0.f;
#pragma unroll 4
  for (int c = 0; c < 96; ++c) {
    float xv = xl[c * 68 + lane];
#pragma unroll
    for (int t = 0; t < 16; ++t) acc[t] = fmaf(Wp[t * 96 + c], xv, acc[t]);
  }
#pragma unroll
  for (int t = 0; t < 16; ++t) ol[w][lane * 17 + t] = acc[t];
  __syncthreads();
  for (int idx = tid; idx < 64 * 64; idx += 256) {
    int li = idx >> 6, oi = idx & 63;
    float v = ol[oi >> 4][li * 17 + (oi & 15)];
    int o = o0 + oi;
    int l = l0 + li;
    if (o < ECH) xi_pre[(b * LTOT + l) * ECH + o] = v;
    else         z[(b * LTOT + l) * ECH + (o - ECH)] = v;
  }
}

// ---------------- K2: depthwise 3x3 conv + SiLU -> xi (B,L,E) ----------------
__global__ __launch_bounds__(256) void k2_dwconv(const float* __restrict__ xi_pre,
                                                 const float* __restrict__ cw,
                                                 const float* __restrict__ cb,
                                                 float* __restrict__ xi) {
  int g = blockIdx.x * 256 + threadIdx.x;
  if (g >= 2 * LTOT * ECH) return;
  int e = g % ECH; int l = (g / ECH) % LTOT; int b = g / (ECH * LTOT);
  int h = l / 48, wq = l % 48;
  float acc = cb[e];
#pragma unroll
  for (int kh = 0; kh < 3; ++kh) {
    int hh = h + kh - 1; if (hh < 0 || hh >= 48) continue;
#pragma unroll
    for (int kw = 0; kw < 3; ++kw) {
      int ww = wq + kw - 1; if (ww < 0 || ww >= 48) continue;
      acc = fmaf(cw[e * 9 + kh * 3 + kw], xi_pre[(b * LTOT + hh * 48 + ww) * ECH + e], acc);
    }
  }
  xi[g] = acc / (1.f + __expf(-acc));
}

// ---------------- K3: x_proj (38x192) + dt_proj (192x6) + softplus ----------------
__global__ __launch_bounds__(256) void k3_xproj(const float* __restrict__ xi,
                                                const float* __restrict__ xw,
                                                const float* __restrict__ dtw,
                                                const float* __restrict__ dtb,
                                                float* __restrict__ dlt,
                                                float* __restrict__ bT,
                                                float* __restrict__ cT) {
  const int l0 = blockIdx.x * 64;  // 36
  const int k  = blockIdx.y;       // 4
  const int b  = blockIdx.z;       // 2
  __shared__ float xs[192 * 67];   // [c][j]
  __shared__ float dl6[6 * 65];
  const int tid = threadIdx.x;
  for (int idx = tid; idx < 64 * 192; idx += 256) {
    int j = idx / 192, c = idx - j * 192;
    int s = permS(k, l0 + j);
    xs[c * 67 + j] = xi[(b * LTOT + s) * ECH + c];
  }
  __syncthreads();
  const int i = tid & 63;
  const int rg = __builtin_amdgcn_readfirstlane(tid >> 6);  // SGPR wave id
  const int bk = b * 4 + k;
  const float* wbase = xw + k * 38 * ECH;
  // scalar row pointers (clamped; tail stores guarded below)
  const float* wr[10];
#pragma unroll
  for (int t = 0; t < 10; ++t) {
    int r = rg + 4 * t;
    wr[t] = wbase + (r < 38 ? r : 37) * ECH;
  }
  float acc[10];
#pragma unroll
  for (int t = 0; t < 10; ++t) acc[t] = 0.f;
#pragma unroll 4
  for (int c = 0; c < 192; ++c) {
    float xv = xs[c * 67 + i];
#pragma unroll
    for (int t = 0; t < 10; ++t) acc[t] = fmaf(wr[t][c], xv, acc[t]);
  }
#pragma unroll
  for (int t = 0; t < 10; ++t) {
    int r = rg + 4 * t;
    if (r >= 38) continue;
    if (r < 6)       dl6[r * 65 + i] = acc[t];
    else if (r < 22) bT[((bk * LTOT) + l0 + i) * NCH + (r - 6)] = acc[t];
    else             cT[((bk * LTOT) + l0 + i) * NCH + (r - 22)] = acc[t];
  }
  __syncthreads();
  for (int idx = tid; idx < 64 * 192; idx += 256) {
    int j = idx / 192, d = idx - j * 192;
    float acc2 = dtb[k * ECH + d];
    const float* wd = dtw + (k * ECH + d) * 6;
#pragma unroll
    for (int r = 0; r < 6; ++r) acc2 = fmaf(wd[r], dl6[r * 65 + j], acc2);
    dlt[((bk * LTOT) + l0 + j) * ECH + d] = softplusf(acc2);
  }
}

// ---------------- K4a: chunk scan pass1 -> q (end states), Ts (chunk dlt sums) ----------------
__global__ __launch_bounds__(256) void k4a_scan1(const float* __restrict__ dlt,
                                                 const float* __restrict__ xi,
                                                 const float* __restrict__ bT,
                                                 const float* __restrict__ Alog,
                                                 float* __restrict__ q,
                                                 float* __restrict__ Ts) {
  const int cb = blockIdx.x;  // 24
  const int db = blockIdx.y;  // 3
  const int bk = blockIdx.z;  // 8
  const int b = bk >> 2, k = bk & 3;
  const int l0 = cb * 96;
  __shared__ float sdl[96 * 64];
  __shared__ float sxi[96 * 64];
  __shared__ float sb[96 * NCH];
  const int tid = threadIdx.x;
  const int dd = tid & 63, cg = tid >> 6;
  const int dg = db * 64 + dd;
  for (int j = cg; j < 96; j += 4) {
    sdl[j * 64 + dd] = dlt[(bk * LTOT + l0 + j) * ECH + dg];
    int s = permS(k, l0 + j);
    sxi[j * 64 + dd] = xi[(b * LTOT + s) * ECH + dg];
  }
  for (int idx = tid; idx < 96 * NCH; idx += 256) sb[idx] = bT[(bk * LTOT + l0) * NCH + idx];
  __syncthreads();
  float C1[16], C2[16], C3[16], h[16];
#pragma unroll
  for (int n = 0; n < 16; ++n) {
    float a = Alog[(k * ECH + dg) * NCH + n];
    C1[n] = a; C2[n] = 0.5f * a * a; C3[n] = (1.f / 6.f) * a * a * a;
    h[n] = 0.f;
  }
  float Tsum = 0.f;
  const int c = cb * 4 + cg;
  for (int i = 0; i < SCH; ++i) {
    int j = cg * SCH + i;
    float dl = sdl[j * 64 + dd];
    float u  = dl * sxi[j * 64 + dd];
    Tsum += dl;
    const float* bb = sb + j * NCH;
    if (dl <= 0.018f) {
#pragma unroll
      for (int n = 0; n < 16; ++n) {
        float e = fmaf(dl, fmaf(dl, fmaf(dl, -C3[n], C2[n]), -C1[n]), 1.f);
        h[n] = fmaf(e, h[n], u * bb[n]);
      }
    } else {
#pragma unroll
      for (int n = 0; n < 16; ++n) {
        float e = __expf(-C1[n] * dl);
        h[n] = fmaf(e, h[n], u * bb[n]);
      }
    }
  }
  float* qp = q + ((bk * CCH + c) * ECH + dg) * NCH;
#pragma unroll
  for (int n = 0; n < 16; ++n) qp[n] = h[n];
  Ts[(bk * CCH + c) * ECH + dg] = Tsum;
}

// ---------------- K4b: cross-chunk combine (q -> per-chunk init states, in place) ----------------
__global__ __launch_bounds__(256) void k4b_comb(const float* __restrict__ Alog,
                                                const float* __restrict__ Ts,
                                                float* __restrict__ q) {
  int t = blockIdx.x * 256 + threadIdx.x;
  if (t >= 8 * ECH * NCH) return;
  int n = t & 15, d = (t >> 4) % ECH, bk = t / (NCH * ECH);
  int k = bk & 3;
  float A = Alog[(k * ECH + d) * NCH + n];
  float h = 0.f;
  for (int c = 0; c < CCH; ++c) {
    int base = ((bk * CCH + c) * ECH + d) * NCH + n;
    float qc = q[base];
    q[base] = h;  // becomes h_init for chunk c
    float xv = A * Ts[(bk * CCH + c) * ECH + d];
    float P = (xv <= 0.05f)
                  ? fmaf(xv, fmaf(xv, fmaf(xv, -(1.f / 6.f), 0.5f), -1.f), 1.f)
                  : __expf(-xv);
    h = fmaf(P, h, qc);
  }
}

// ---------------- K4c: chunk scan pass2 -> y, atomic accumulate into ys (B,L,E) ----------------
__global__ __launch_bounds__(256) void k4c_scan2(const float* __restrict__ dlt,
                                                 const float* __restrict__ xi,
                                                 const float* __restrict__ bT,
                                                 const float* __restrict__ cT,
                                                 const float* __restrict__ Alog,
                                                 const float* __restrict__ hin,
                                                 float* __restrict__ ys) {
  const int cb = blockIdx.x;
  const int db = blockIdx.y;
  const int bk = blockIdx.z;
  const int b = bk >> 2, k = bk & 3;
  const int l0 = cb * 96;
  __shared__ float sdl[96 * 64];
  __shared__ float sxi[96 * 64];
  __shared__ float sb[96 * NCH];
  __shared__ float sc[96 * NCH];
  const int tid = threadIdx.x;
  const int dd = tid & 63, cg = tid >> 6;
  const int dg = db * 64 + dd;
  for (int j = cg; j < 96; j += 4) {
    sdl[j * 64 + dd] = dlt[(bk * LTOT + l0 + j) * ECH + dg];
    int s = permS(k, l0 + j);
    sxi[j * 64 + dd] = xi[(b * LTOT + s) * ECH + dg];
  }
  for (int idx = tid; idx < 96 * NCH; idx += 256) {
    sb[idx] = bT[(bk * LTOT + l0) * NCH + idx];
    sc[idx] = cT[(bk * LTOT + l0) * NCH + idx];
  }
  __syncthreads();
  float C1[16], C2[16], C3[16], h[16];
  const int c = cb * 4 + cg;
  const float* hp = hin + ((bk * CCH + c) * ECH + dg) * NCH;
#pragma unroll
  for (int n = 0; n < 16; ++n) {
    float a = Alog[(k * ECH + dg) * NCH + n];
    C1[n] = a; C2[n] = 0.5f * a * a; C3[n] = (1.f / 6.f) * a * a * a;
    h[n] = hp[n];
  }
  for (int i = 0; i < SCH; ++i) {
    int j = cg * SCH + i;
    int l = l0 + j;
    float dl = sdl[j * 64 + dd];
    float u  = dl * sxi[j * 64 + dd];
    const float* bb = sb + j * NCH;
    if (dl <= 0.018f) {
#pragma unroll
      for (int n = 0; n < 16; ++n) {
        float e = fmaf(dl, fmaf(dl, fmaf(dl, -C3[n], C2[n]), -C1[n]), 1.f);
        h[n] = fmaf(e, h[n], u * bb[n]);
      }
    } else {
#pragma unroll
      for (int n = 0; n < 16; ++n) {
        float e = __expf(-C1[n] * dl);
        h[n] = fmaf(e, h[n], u * bb[n]);
      }
    }
    const float* cc = sc + j * NCH;
    float y = 0.f;
#pragma unroll
    for (int n = 0; n < 16; ++n) y = fmaf(h[n], cc[n], y);
    int s = permS(k, l);
    atomicAdd(&ys[(b * LTOT + s) * ECH + dg], y);
  }
}

// ---------------- K5: LayerNorm over E (+Ds) then multiply by z (in-place over z) ----------------
__global__ __launch_bounds__(256) void k5_ln(const float* __restrict__ ys,
                                             const float* __restrict__ Ds,
                                             const float* __restrict__ lng,
                                             const float* __restrict__ lnb,
                                             float* __restrict__ zu) {
  int p = blockIdx.x * 4 + (threadIdx.x >> 6);
  int lane = threadIdx.x & 63;
  const float* yp = ys + p * ECH;
  float vd[3], sd[3];
#pragma unroll
  for (int t = 0; t < 3; ++t) {
    int d = lane + t * 64;
    vd[t] = yp[d];
    sd[t] = Ds[d] + Ds[ECH + d] + Ds[2 * ECH + d] + Ds[3 * ECH + d];
  }
  float s1 = vd[0] + vd[1] + vd[2];
  float s2 = sd[0] + sd[1] + sd[2];
#pragma unroll
  for (int off = 32; off > 0; off >>= 1) {
    s1 += __shfl_xor(s1, off, 64);
    s2 += __shfl_xor(s2, off, 64);
  }
  float mean_dot = s1 * (1.f / 192.f);
  float mean_sd  = s2 * (1.f / 192.f);
  float dev[3];
  float ss = 0.f;
#pragma unroll
  for (int t = 0; t < 3; ++t) {
    dev[t] = (vd[t] - mean_dot) + (sd[t] - mean_sd);
    ss = fmaf(dev[t], dev[t], ss);
  }
#pragma unroll
  for (int off = 32; off > 0; off >>= 1) ss += __shfl_xor(ss, off, 64);
  float rstd = 1.f / sqrtf(ss * (1.f / 192.f) + 1e-5f);
#pragma unroll
  for (int t = 0; t < 3; ++t) {
    int d = lane + t * 64;
    float yn = (dev[t] * rstd) * lng[d] + lnb[d];
    zu[p * ECH + d] = yn * zu[p * ECH + d];
  }
}

// ---------------- K6: c1 1x1 GEMM (384x192) + bn1 + relu -> t1 (B,L,384) ----------------
__global__ __launch_bounds__(256) void k6_c1(const float* __restrict__ u,
                                             const float* __restrict__ W,
                                             const float* __restrict__ c1b,
                                             const float* __restrict__ g1,
                                             const float* __restrict__ b1,
                                             const float* __restrict__ m1,
                                             const float* __restrict__ v1,
                                             float* __restrict__ t1) {
  const int l0 = blockIdx.x * 64;
  const int o0 = blockIdx.y * 64;
  const int b  = blockIdx.z;
  __shared__ float xl[192 * 68];  // reused as output staging after compute
  const int tid = threadIdx.x;
  for (int idx = tid; idx < 192 * 64; idx += 256) {
    int c = idx % 192, i = idx / 192;
    xl[c * 68 + i] = u[(b * LTOT + l0 + i) * ECH + c];
  }
  __syncthreads();
  const int lane = tid & 63;
  const int w = __builtin_amdgcn_readfirstlane(tid >> 6);
  const int ow = o0 + w * 16;
  const float* __restrict__ Wp = W + ow * ECH;  // scalar base
  float acc[16];
#pragma unroll
  for (int t = 0; t < 16; ++t) acc[t] = 0.f;
#pragma unroll 4
  for (int c = 0; c < 192; ++c) {
    float xv = xl[c * 68 + lane];
#pragma unroll
    for (int t = 0; t < 16; ++t) acc[t] = fmaf(Wp[t * ECH + c], xv, acc[t]);
  }
  __syncthreads();  // everyone done reading xl
  float* ol = xl + w * (64 * 17);
#pragma unroll
  for (int t = 0; t < 16; ++t) {
    int o = ow + t;
    float sc = g1[o] / sqrtf(v1[o] + 1e-5f);
    float val = (acc[t] + c1b[o] - m1[o]) * sc + b1[o];
    ol[lane * 17 + t] = fmaxf(val, 0.f);
  }
  __syncthreads();
  for (int idx = tid; idx < 64 * 64; idx += 256) {
    int li = idx >> 6, oi = idx & 63;
    t1[(b * LTOT + l0 + li) * 384 + o0 + oi] = xl[(oi >> 4) * (64 * 17) + li * 17 + (oi & 15)];
  }
}

// ---------------- K7: depthwise 3x3 on t1 + bn2 + relu -> t2 (B,L,384) ----------------
__global__ __launch_bounds__(256) void k7_dw2(const float* __restrict__ t1,
                                              const float* __restrict__ cw,
                                              const float* __restrict__ cb,
                                              const float* __restrict__ g2,
                                              const float* __restrict__ b2,
                                              const float* __restrict__ m2,
                                              const float* __restrict__ v2,
                                              float* __restrict__ t2) {
  int g = blockIdx.x * 256 + threadIdx.x;
  if (g >= 2 * LTOT * 384) return;
  int o = g % 384; int l = (g / 384) % LTOT; int b = g / (384 * LTOT);
  int h = l / 48, wq = l % 48;
  float acc = cb[o];
#pragma unroll
  for (int kh = 0; kh < 3; ++kh) {
    int hh = h + kh - 1; if (hh < 0 || hh >= 48) continue;
#pragma unroll
    for (int kw = 0; kw < 3; ++kw) {
      int ww = wq + kw - 1; if (ww < 0 || ww >= 48) continue;
      acc = fmaf(cw[o * 9 + kh * 3 + kw], t1[(b * LTOT + hh * 48 + ww) * 384 + o], acc);
    }
  }
  float sc = g2[o] / sqrtf(v2[o] + 1e-5f);
  float val = (acc - m2[o]) * sc + b2[o];
  t2[g] = fmaxf(val, 0.f);
}

// ---------------- K8: c3 1x1 GEMM (96x384) -> t3 (B,96,L) + SE partial sums ----------------
__global__ __launch_bounds__(192) void k8_c3(const float* __restrict__ t2,
                                             const float* __restrict__ W,
                                             const float* __restrict__ c3b,
                                             float* __restrict__ t3,
                                             float* __restrict__ se) {
  const int l0 = blockIdx.x * 64;  // 36
  const int ot = blockIdx.y;       // 2
  const int b  = blockIdx.z;
  __shared__ float xl[96 * 68];
  __shared__ float ol[3][64 * 17];
  const int tid = threadIdx.x;
  const int lane = tid & 63;
  const int w = __builtin_amdgcn_readfirstlane(tid / 64);  // w < 3, SGPR
  const int ow = ot * 48 + w * 16;
  const float* __restrict__ Wp = W + ow * 384;  // scalar base
  float acc[16];
#pragma unroll
  for (int t = 0; t < 16; ++t) acc[t] = c3b[ow + t];
  for (int kc = 0; kc < 4; ++kc) {
    __syncthreads();
    for (int idx = tid; idx < 96 * 64; idx += 192) {
      int c = idx % 96, i = idx / 96;
      xl[c * 68 + i] = t2[(b * LTOT + l0 + i) * 384 + kc * 96 + c];
    }
    __syncthreads();
#pragma unroll 4
    for (int c = 0; c < 96; ++c) {
      float xv = xl[c * 68 + lane];
#pragma unroll
      for (int t = 0; t < 16; ++t) acc[t] = fmaf(Wp[t * 384 + kc * 96 + c], xv, acc[t]);
    }
  }
#pragma unroll
  for (int t = 0; t < 16; ++t) ol[w][lane * 17 + t] = acc[t];
  __syncthreads();
  // store t3 in OUTPUT layout (b, o, l): consecutive tid -> consecutive li -> coalesced
  for (int idx = tid; idx < 64 * 48; idx += 192) {
    int oi = idx / 64, li = idx % 64;
    t3[(b * 96 + ot * 48 + oi) * LTOT + l0 + li] = ol[oi >> 4][li * 17 + (oi & 15)];
  }
  if (tid < 48) {
    float ssum = 0.f;
#pragma unroll 8
    for (int li = 0; li < 64; ++li) ssum += ol[tid >> 4][li * 17 + (tid & 15)];
    atomicAdd(&se[b * 96 + ot * 48 + tid], ssum);
  }
}

// ---------------- K9a: SE MLP -> smul = 1 + sigmoid(...) ----------------
__global__ __launch_bounds__(256) void k9a_se(const float* __restrict__ se,
                                              const float* __restrict__ w1,
                                              const float* __restrict__ sb1,
                                              const float* __restrict__ w2,
                                              const float* __restrict__ sb2,
                                              float* __restrict__ smul) {
  __shared__ float sm[192];
  __shared__ float s1[96];
  int t = threadIdx.x;
  if (t < 192) sm[t] = se[t] * (1.f / 2304.f);
  __syncthreads();
  if (t < 96) {
    int b = t / 48, i = t % 48;
    float acc = sb1[i];
    for (int m = 0; m < 96; ++m) acc = fmaf(w1[i * 96 + m], sm[b * 96 + m], acc);
    s1[t] = fmaxf(acc, 0.f);
  }
  __syncthreads();
  if (t < 192) {
    int b = t / 96, j = t % 96;
    float acc = sb2[j];
    for (int i = 0; i < 48; ++i) acc = fmaf(w2[j * 48 + i], s1[b * 48 + i], acc);
    smul[t] = 1.f + 1.f / (1.f + __expf(-acc));
  }
}

// ---------------- K9b: out[b,j,l] = t3[b,j,l] * smul[b,j] (pure streaming) ----------------
__global__ __launch_bounds__(256) void k9b_out(const float* __restrict__ t3,
                                               const float* __restrict__ smul,
                                               float* __restrict__ out) {
  int g = blockIdx.x * 256 + threadIdx.x;
  if (g >= 2 * 96 * LTOT) return;
  int bj = g / LTOT;
  out[g] = t3[g] * smul[bj];
}

extern "C" void kernel_launch(void* const* d_in, const int* in_sizes, int n_in,
                              void* d_out, int out_size, void* d_ws, size_t ws_size,
                              hipStream_t stream) {
  const float* x     = (const float*)d_in[0];
  const float* inw   = (const float*)d_in[1];
  const float* convw = (const float*)d_in[2];
  const float* convb = (const float*)d_in[3];
  const float* xpw   = (const float*)d_in[4];
  const float* dtw   = (const float*)d_in[5];
  const float* dtb   = (const float*)d_in[6];
  const float* Alog  = (const float*)d_in[7];
  const float* Ds    = (const float*)d_in[8];
  const float* lng   = (const float*)d_in[9];
  const float* lnb   = (const float*)d_in[10];
  const float* c1w   = (const float*)d_in[11];
  const float* c1b   = (const float*)d_in[12];
  const float* bn1g  = (const float*)d_in[13];
  const float* bn1b  = (const float*)d_in[14];
  const float* bn1m  = (const float*)d_in[15];
  const float* bn1v  = (const float*)d_in[16];
  const float* c2w   = (const float*)d_in[17];
  const float* c2b   = (const float*)d_in[18];
  const float* bn2g  = (const float*)d_in[19];
  const float* bn2b  = (const float*)d_in[20];
  const float* bn2m  = (const float*)d_in[21];
  const float* bn2v  = (const float*)d_in[22];
  const float* c3w   = (const float*)d_in[23];
  const float* c3b   = (const float*)d_in[24];
  const float* se1w  = (const float*)d_in[25];
  const float* se1b  = (const float*)d_in[26];
  const float* se2w  = (const float*)d_in[27];
  const float* se2b  = (const float*)d_in[28];

  float* ws = (float*)d_ws;
  float* xi_pre = ws;                    // 884736
  float* z      = ws + 884736;           // 884736  (becomes u after k5)
  float* xi     = ws + 1769472;          // 884736
  float* dlt    = ws + 2654208;          // 3538944 (reused as t1/t2)
  float* bT     = ws + 6193152;          // 589824
  float* cT     = ws + 6782976;          // 589824  (reused as t3)
  float* ys     = ws + 7372800;          // 884736
  float* q      = ws + 8257536;          // 2359296
  float* Ts     = ws + 10616832;         // 147456
  float* se     = ws + 10764288;         // 192
  float* smul   = ws + 10764480;         // 192
  float* t1 = dlt;
  float* t2 = dlt + 1769472;
  float* t3 = cT;

  hipMemsetAsync(ys, 0, 884736 * sizeof(float), stream);
  hipMemsetAsync(se, 0, 192 * sizeof(float), stream);

  k1_inproj<<<dim3(36, 6, 2), 256, 0, stream>>>(x, inw, xi_pre, z);
  k2_dwconv<<<3456, 256, 0, stream>>>(xi_pre, convw, convb, xi);
  k3_xproj<<<dim3(36, 4, 2), 256, 0, stream>>>(xi, xpw, dtw, dtb, dlt, bT, cT);
  k4a_scan1<<<dim3(24, 3, 8), 256, 0, stream>>>(dlt, xi, bT, Alog, q, Ts);
  k4b_comb<<<96, 256, 0, stream>>>(Alog, Ts, q);
  k4c_scan2<<<dim3(24, 3, 8), 256, 0, stream>>>(dlt, xi, bT, cT, Alog, q, ys);
  k5_ln<<<1152, 256, 0, stream>>>(ys, Ds, lng, lnb, z);
  k6_c1<<<dim3(36, 6, 2), 256, 0, stream>>>(z, c1w, c1b, bn1g, bn1b, bn1m, bn1v, t1);
  k7_dw2<<<6912, 256, 0, stream>>>(t1, c2w, c2b, bn2g, bn2b, bn2m, bn2v, t2);
  k8_c3<<<dim3(36, 2, 2), 192, 0, stream>>>(t2, c3w, c3b, t3, se);
  k9a_se<<<1, 256, 0, stream>>>(se, se1w, se1b, se2w, se2b, smul);
  k9b_out<<<1728, 256, 0, stream>>>(t3, smul, (float*)d_out);
}

// Round 4
// 391.567 us; speedup vs baseline: 1.1364x; 1.0136x over previous
//
#include <hip/hip_runtime.h>
#include <hip/hip_bf16.h>

#define LTOT 2304
#define ECH  192
#define NCH  16
#define CCH  96   // chunks over L
#define SCH  24   // steps per chunk

__device__ __forceinline__ int permS(int k, int l) {
  if (k == 0) return l;
  if (k == 1) return LTOT - 1 - l;
  int m = (k == 2) ? l : (LTOT - 1 - l);
  return (m % 48) * 48 + (m / 48);
}

__device__ __forceinline__ float softplusf(float x) {
  return (x > 20.f) ? x : log1pf(__expf(x));
}

// ---------------- K1: in_proj GEMM (384x96) -> xi_pre (B,L,E), z (B,L,E) ----------------
__global__ __launch_bounds__(256) void k1_inproj(const float* __restrict__ x,
                                                 const float* __restrict__ W,
                                                 float* __restrict__ xi_pre,
                                                 float* __restrict__ z) {
  const int l0 = blockIdx.x * 64;
  const int o0 = blockIdx.y * 64;
  const int b  = blockIdx.z;
  __shared__ float xl[96 * 68];
  __shared__ float ol[4][64 * 17];
  const int tid = threadIdx.x;
  for (int idx = tid; idx < 96 * 64; idx += 256) {
    int c = idx >> 6, i = idx & 63;
    xl[c * 68 + i] = x[(b * 96 + c) * LTOT + l0 + i];
  }
  __syncthreads();
  const int lane = tid & 63;
  const int w = __builtin_amdgcn_readfirstlane(tid >> 6);
  const int ow = o0 + w * 16;
  const float* __restrict__ Wp = W + ow * 96;
  float acc[16];
#pragma unroll
  for (int t = 0; t < 16; ++t) acc[t] = 0.f;
#pragma unroll 4
  for (int c = 0; c < 96; ++c) {
    float xv = xl[c * 68 + lane];
#pragma unroll
    for (int t = 0; t < 16; ++t) acc[t] = fmaf(Wp[t * 96 + c], xv, acc[t]);
  }
#pragma unroll
  for (int t = 0; t < 16; ++t) ol[w][lane * 17 + t] = acc[t];
  __syncthreads();
  for (int idx = tid; idx < 64 * 64; idx += 256) {
    int li = idx >> 6, oi = idx & 63;
    float v = ol[oi >> 4][li * 17 + (oi & 15)];
    int o = o0 + oi;
    int l = l0 + li;
    if (o < ECH) xi_pre[(b * LTOT + l) * ECH + o] = v;
    else         z[(b * LTOT + l) * ECH + (o - ECH)] = v;
  }
}

// ---------------- K2: depthwise 3x3 conv + SiLU -> xi (B,L,E) ----------------
__global__ __launch_bounds__(256) void k2_dwconv(const float* __restrict__ xi_pre,
                                                 const float* __restrict__ cw,
                                                 const float* __restrict__ cb,
                                                 float* __restrict__ xi) {
  int g = blockIdx.x * 256 + threadIdx.x;
  if (g >= 2 * LTOT * ECH) return;
  int e = g % ECH; int l = (g / ECH) % LTOT; int b = g / (ECH * LTOT);
  int h = l / 48, wq = l % 48;
  float acc = cb[e];
#pragma unroll
  for (int kh = 0; kh < 3; ++kh) {
    int hh = h + kh - 1; if (hh < 0 || hh >= 48) continue;
#pragma unroll
    for (int kw = 0; kw < 3; ++kw) {
      int ww = wq + kw - 1; if (ww < 0 || ww >= 48) continue;
      acc = fmaf(cw[e * 9 + kh * 3 + kw], xi_pre[(b * LTOT + hh * 48 + ww) * ECH + e], acc);
    }
  }
  xi[g] = acc / (1.f + __expf(-acc));
}

// ---------------- K3: x_proj (38x192) + dt_proj (192x6) + softplus ----------------
// v3: W staged in LDS [c][40] (float4 broadcast reads); per-thread 2pos x 4rows;
// grid 576 blocks (L-tile 32), LDS 56KB -> 2 blocks/CU.
__global__ __launch_bounds__(256) void k3_xproj(const float* __restrict__ xi,
                                                const float* __restrict__ xw,
                                                const float* __restrict__ dtw,
                                                const float* __restrict__ dtb,
                                                float* __restrict__ dlt,
                                                float* __restrict__ bT,
                                                float* __restrict__ cT) {
  const int l0 = blockIdx.x * 32;  // 72
  const int k  = blockIdx.y;       // 4
  const int b  = blockIdx.z;       // 2
  __shared__ __align__(16) float xs[32 * 193];  // [j][c]
  __shared__ __align__(16) float Wl[192 * 40];  // [c][r]
  __shared__ float dl6[6 * 33];
  const int tid = threadIdx.x;
  for (int idx = tid; idx < 32 * 192; idx += 256) {
    int j = idx / 192, c = idx - j * 192;
    int s = permS(k, l0 + j);
    xs[j * 193 + c] = xi[(b * LTOT + s) * ECH + c];
  }
  const float* wsrc = xw + k * 38 * ECH;
  for (int idx = tid; idx < 38 * 192; idx += 256) {
    int r = idx / 192, c = idx - r * 192;
    Wl[c * 40 + r] = wsrc[idx];
  }
  __syncthreads();
  const int lane = tid & 63, w = tid >> 6;
  const int jj = lane & 15;
  const int rq = w * 4 + (lane >> 4);   // [0,16), active < 10
  const int rqc = rq < 9 ? rq : 9;
  const int j0 = 2 * jj;
  float a00 = 0.f, a01 = 0.f, a02 = 0.f, a03 = 0.f;
  float a10 = 0.f, a11 = 0.f, a12 = 0.f, a13 = 0.f;
#pragma unroll 4
  for (int c = 0; c < 192; ++c) {
    float x0 = xs[j0 * 193 + c];
    float x1 = xs[j0 * 193 + 193 + c];
    const float4 wv = *(const float4*)&Wl[c * 40 + 4 * rqc];
    a00 = fmaf(wv.x, x0, a00); a01 = fmaf(wv.y, x0, a01);
    a02 = fmaf(wv.z, x0, a02); a03 = fmaf(wv.w, x0, a03);
    a10 = fmaf(wv.x, x1, a10); a11 = fmaf(wv.y, x1, a11);
    a12 = fmaf(wv.z, x1, a12); a13 = fmaf(wv.w, x1, a13);
  }
  const int bk = b * 4 + k;
  if (rq < 10) {
    float av[2][4] = {{a00, a01, a02, a03}, {a10, a11, a12, a13}};
#pragma unroll
    for (int t = 0; t < 4; ++t) {
      int r = 4 * rq + t;
      if (r >= 38) continue;
#pragma unroll
      for (int p = 0; p < 2; ++p) {
        int j = j0 + p;
        float v = av[p][t];
        if (r < 6)       dl6[r * 33 + j] = v;
        else if (r < 22) bT[((bk * LTOT) + l0 + j) * NCH + (r - 6)] = v;
        else             cT[((bk * LTOT) + l0 + j) * NCH + (r - 22)] = v;
      }
    }
  }
  __syncthreads();
  for (int idx = tid; idx < 32 * 192; idx += 256) {
    int j = idx / 192, d = idx - j * 192;
    float a = dtb[k * ECH + d];
    const float* wd = dtw + (k * ECH + d) * 6;
#pragma unroll
    for (int r = 0; r < 6; ++r) a = fmaf(wd[r], dl6[r * 33 + j], a);
    dlt[((bk * LTOT) + l0 + j) * ECH + d] = softplusf(a);
  }
}

// ---------------- K4a: chunk scan pass1 -> q (end states), Ts (chunk dlt sums) ----------------
__global__ __launch_bounds__(256) void k4a_scan1(const float* __restrict__ dlt,
                                                 const float* __restrict__ xi,
                                                 const float* __restrict__ bT,
                                                 const float* __restrict__ Alog,
                                                 float* __restrict__ q,
                                                 float* __restrict__ Ts) {
  const int cb = blockIdx.x;  // 24
  const int db = blockIdx.y;  // 3
  const int bk = blockIdx.z;  // 8
  const int b = bk >> 2, k = bk & 3;
  const int l0 = cb * 96;
  __shared__ float sdl[96 * 64];
  __shared__ float sxi[96 * 64];
  __shared__ float sb[96 * NCH];
  const int tid = threadIdx.x;
  const int dd = tid & 63, cg = tid >> 6;
  const int dg = db * 64 + dd;
  for (int j = cg; j < 96; j += 4) {
    sdl[j * 64 + dd] = dlt[(bk * LTOT + l0 + j) * ECH + dg];
    int s = permS(k, l0 + j);
    sxi[j * 64 + dd] = xi[(b * LTOT + s) * ECH + dg];
  }
  for (int idx = tid; idx < 96 * NCH; idx += 256) sb[idx] = bT[(bk * LTOT + l0) * NCH + idx];
  __syncthreads();
  float C1[16], C2[16], C3[16], h[16];
#pragma unroll
  for (int n = 0; n < 16; ++n) {
    float a = Alog[(k * ECH + dg) * NCH + n];
    C1[n] = a; C2[n] = 0.5f * a * a; C3[n] = (1.f / 6.f) * a * a * a;
    h[n] = 0.f;
  }
  float Tsum = 0.f;
  const int c = cb * 4 + cg;
  for (int i = 0; i < SCH; ++i) {
    int j = cg * SCH + i;
    float dl = sdl[j * 64 + dd];
    float u  = dl * sxi[j * 64 + dd];
    Tsum += dl;
    const float* bb = sb + j * NCH;
    if (dl <= 0.018f) {
#pragma unroll
      for (int n = 0; n < 16; ++n) {
        float e = fmaf(dl, fmaf(dl, fmaf(dl, -C3[n], C2[n]), -C1[n]), 1.f);
        h[n] = fmaf(e, h[n], u * bb[n]);
      }
    } else {
#pragma unroll
      for (int n = 0; n < 16; ++n) {
        float e = __expf(-C1[n] * dl);
        h[n] = fmaf(e, h[n], u * bb[n]);
      }
    }
  }
  float* qp = q + ((bk * CCH + c) * ECH + dg) * NCH;
#pragma unroll
  for (int n = 0; n < 16; ++n) qp[n] = h[n];
  Ts[(bk * CCH + c) * ECH + dg] = Tsum;
}

// ---------------- K4b: cross-chunk combine (q -> per-chunk init states, in place) ----------------
__global__ __launch_bounds__(256) void k4b_comb(const float* __restrict__ Alog,
                                                const float* __restrict__ Ts,
                                                float* __restrict__ q) {
  int t = blockIdx.x * 256 + threadIdx.x;
  if (t >= 8 * ECH * NCH) return;
  int n = t & 15, d = (t >> 4) % ECH, bk = t / (NCH * ECH);
  int k = bk & 3;
  float A = Alog[(k * ECH + d) * NCH + n];
  float h = 0.f;
  for (int c = 0; c < CCH; ++c) {
    int base = ((bk * CCH + c) * ECH + d) * NCH + n;
    float qc = q[base];
    q[base] = h;  // becomes h_init for chunk c
    float xv = A * Ts[(bk * CCH + c) * ECH + d];
    float P = (xv <= 0.05f)
                  ? fmaf(xv, fmaf(xv, fmaf(xv, -(1.f / 6.f), 0.5f), -1.f), 1.f)
                  : __expf(-xv);
    h = fmaf(P, h, qc);
  }
}

// ---------------- K4c: chunk scan pass2 -> y, atomic accumulate into ys (B,L,E) ----------------
__global__ __launch_bounds__(256) void k4c_scan2(const float* __restrict__ dlt,
                                                 const float* __restrict__ xi,
                                                 const float* __restrict__ bT,
                                                 const float* __restrict__ cT,
                                                 const float* __restrict__ Alog,
                                                 const float* __restrict__ hin,
                                                 float* __restrict__ ys) {
  const int cb = blockIdx.x;
  const int db = blockIdx.y;
  const int bk = blockIdx.z;
  const int b = bk >> 2, k = bk & 3;
  const int l0 = cb * 96;
  __shared__ float sdl[96 * 64];
  __shared__ float sxi[96 * 64];
  __shared__ float sb[96 * NCH];
  __shared__ float sc[96 * NCH];
  const int tid = threadIdx.x;
  const int dd = tid & 63, cg = tid >> 6;
  const int dg = db * 64 + dd;
  for (int j = cg; j < 96; j += 4) {
    sdl[j * 64 + dd] = dlt[(bk * LTOT + l0 + j) * ECH + dg];
    int s = permS(k, l0 + j);
    sxi[j * 64 + dd] = xi[(b * LTOT + s) * ECH + dg];
  }
  for (int idx = tid; idx < 96 * NCH; idx += 256) {
    sb[idx] = bT[(bk * LTOT + l0) * NCH + idx];
    sc[idx] = cT[(bk * LTOT + l0) * NCH + idx];
  }
  __syncthreads();
  float C1[16], C2[16], C3[16], h[16];
  const int c = cb * 4 + cg;
  const float* hp = hin + ((bk * CCH + c) * ECH + dg) * NCH;
#pragma unroll
  for (int n = 0; n < 16; ++n) {
    float a = Alog[(k * ECH + dg) * NCH + n];
    C1[n] = a; C2[n] = 0.5f * a * a; C3[n] = (1.f / 6.f) * a * a * a;
    h[n] = hp[n];
  }
  for (int i = 0; i < SCH; ++i) {
    int j = cg * SCH + i;
    int l = l0 + j;
    float dl = sdl[j * 64 + dd];
    float u  = dl * sxi[j * 64 + dd];
    const float* bb = sb + j * NCH;
    if (dl <= 0.018f) {
#pragma unroll
      for (int n = 0; n < 16; ++n) {
        float e = fmaf(dl, fmaf(dl, fmaf(dl, -C3[n], C2[n]), -C1[n]), 1.f);
        h[n] = fmaf(e, h[n], u * bb[n]);
      }
    } else {
#pragma unroll
      for (int n = 0; n < 16; ++n) {
        float e = __expf(-C1[n] * dl);
        h[n] = fmaf(e, h[n], u * bb[n]);
      }
    }
    const float* cc = sc + j * NCH;
    float y = 0.f;
#pragma unroll
    for (int n = 0; n < 16; ++n) y = fmaf(h[n], cc[n], y);
    int s = permS(k, l);
    atomicAdd(&ys[(b * LTOT + s) * ECH + dg], y);
  }
}

// ---------------- K5: LayerNorm over E (+Ds) then multiply by z (in-place over z) ----------------
__global__ __launch_bounds__(256) void k5_ln(const float* __restrict__ ys,
                                             const float* __restrict__ Ds,
                                             const float* __restrict__ lng,
                                             const float* __restrict__ lnb,
                                             float* __restrict__ zu) {
  int p = blockIdx.x * 4 + (threadIdx.x >> 6);
  int lane = threadIdx.x & 63;
  const float* yp = ys + p * ECH;
  float vd[3], sd[3];
#pragma unroll
  for (int t = 0; t < 3; ++t) {
    int d = lane + t * 64;
    vd[t] = yp[d];
    sd[t] = Ds[d] + Ds[ECH + d] + Ds[2 * ECH + d] + Ds[3 * ECH + d];
  }
  float s1 = vd[0] + vd[1] + vd[2];
  float s2 = sd[0] + sd[1] + sd[2];
#pragma unroll
  for (int off = 32; off > 0; off >>= 1) {
    s1 += __shfl_xor(s1, off, 64);
    s2 += __shfl_xor(s2, off, 64);
  }
  float mean_dot = s1 * (1.f / 192.f);
  float mean_sd  = s2 * (1.f / 192.f);
  float dev[3];
  float ss = 0.f;
#pragma unroll
  for (int t = 0; t < 3; ++t) {
    dev[t] = (vd[t] - mean_dot) + (sd[t] - mean_sd);
    ss = fmaf(dev[t], dev[t], ss);
  }
#pragma unroll
  for (int off = 32; off > 0; off >>= 1) ss += __shfl_xor(ss, off, 64);
  float rstd = 1.f / sqrtf(ss * (1.f / 192.f) + 1e-5f);
#pragma unroll
  for (int t = 0; t < 3; ++t) {
    int d = lane + t * 64;
    float yn = (dev[t] * rstd) * lng[d] + lnb[d];
    zu[p * ECH + d] = yn * zu[p * ECH + d];
  }
}

// ---------------- K6: c1 1x1 GEMM (384x192) + bn1 + relu -> t1 (B,L,384) ----------------
__global__ __launch_bounds__(256) void k6_c1(const float* __restrict__ u,
                                             const float* __restrict__ W,
                                             const float* __restrict__ c1b,
                                             const float* __restrict__ g1,
                                             const float* __restrict__ b1,
                                             const float* __restrict__ m1,
                                             const float* __restrict__ v1,
                                             float* __restrict__ t1) {
  const int l0 = blockIdx.x * 64;
  const int o0 = blockIdx.y * 64;
  const int b  = blockIdx.z;
  __shared__ float xl[192 * 69];  // pad 69: staging bank-stride 5, conflict-free
  const int tid = threadIdx.x;
  for (int idx = tid; idx < 192 * 64; idx += 256) {
    int c = idx % 192, i = idx / 192;
    xl[c * 69 + i] = u[(b * LTOT + l0 + i) * ECH + c];
  }
  __syncthreads();
  const int lane = tid & 63;
  const int w = __builtin_amdgcn_readfirstlane(tid >> 6);
  const int ow = o0 + w * 16;
  const float* __restrict__ Wp = W + ow * ECH;
  float acc[16];
#pragma unroll
  for (int t = 0; t < 16; ++t) acc[t] = 0.f;
#pragma unroll 4
  for (int c = 0; c < 192; ++c) {
    float xv = xl[c * 69 + lane];
#pragma unroll
    for (int t = 0; t < 16; ++t) acc[t] = fmaf(Wp[t * ECH + c], xv, acc[t]);
  }
  __syncthreads();  // everyone done reading xl
  float* ol = xl + w * (64 * 17);
#pragma unroll
  for (int t = 0; t < 16; ++t) {
    int o = ow + t;
    float sc = g1[o] / sqrtf(v1[o] + 1e-5f);
    float val = (acc[t] + c1b[o] - m1[o]) * sc + b1[o];
    ol[lane * 17 + t] = fmaxf(val, 0.f);
  }
  __syncthreads();
  for (int idx = tid; idx < 64 * 64; idx += 256) {
    int li = idx >> 6, oi = idx & 63;
    t1[(b * LTOT + l0 + li) * 384 + o0 + oi] = xl[(oi >> 4) * (64 * 17) + li * 17 + (oi & 15)];
  }
}

// ---------------- K7: depthwise 3x3 on t1 + bn2 + relu -> t2 (B,L,384) ----------------
__global__ __launch_bounds__(256) void k7_dw2(const float* __restrict__ t1,
                                              const float* __restrict__ cw,
                                              const float* __restrict__ cb,
                                              const float* __restrict__ g2,
                                              const float* __restrict__ b2,
                                              const float* __restrict__ m2,
                                              const float* __restrict__ v2,
                                              float* __restrict__ t2) {
  int g = blockIdx.x * 256 + threadIdx.x;
  if (g >= 2 * LTOT * 384) return;
  int o = g % 384; int l = (g / 384) % LTOT; int b = g / (384 * LTOT);
  int h = l / 48, wq = l % 48;
  float acc = cb[o];
#pragma unroll
  for (int kh = 0; kh < 3; ++kh) {
    int hh = h + kh - 1; if (hh < 0 || hh >= 48) continue;
#pragma unroll
    for (int kw = 0; kw < 3; ++kw) {
      int ww = wq + kw - 1; if (ww < 0 || ww >= 48) continue;
      acc = fmaf(cw[o * 9 + kh * 3 + kw], t1[(b * LTOT + hh * 48 + ww) * 384 + o], acc);
    }
  }
  float sc = g2[o] / sqrtf(v2[o] + 1e-5f);
  float val = (acc - m2[o]) * sc + b2[o];
  t2[g] = fmaxf(val, 0.f);
}

// ---------------- K8: c3 1x1 GEMM (96x384) -> t3 (B,96,L) + SE partial sums ----------------
// v3: L-tile 16, grid 288; per-thread 1pos x 8rows; W LDS [c][104] float4 broadcast.
__global__ __launch_bounds__(256) void k8_c3(const float* __restrict__ t2,
                                             const float* __restrict__ W,
                                             const float* __restrict__ c3b,
                                             float* __restrict__ t3,
                                             float* __restrict__ se) {
  const int l0 = blockIdx.x * 16;  // 144
  const int b  = blockIdx.y;       // 2
  __shared__ __align__(16) float xc[16 * 97];
  __shared__ __align__(16) float Wl[96 * 104];
  const int tid = threadIdx.x;
  const int lane = tid & 63, w = tid >> 6;
  const int jj = lane & 15;
  const int rq = w * 4 + (lane >> 4);   // [0,16), active < 12
  const int rqc = rq < 12 ? rq : 11;
  const int r0 = 8 * rqc;
  float acc[8];
#pragma unroll
  for (int t = 0; t < 8; ++t) acc[t] = c3b[r0 + t];
  for (int kc = 0; kc < 4; ++kc) {
    __syncthreads();
    for (int idx = tid; idx < 16 * 96; idx += 256) {
      int j = idx / 96, c = idx - j * 96;
      xc[j * 97 + c] = t2[(b * LTOT + l0 + j) * 384 + kc * 96 + c];
    }
    for (int idx = tid; idx < 96 * 96; idx += 256) {
      int r = idx / 96, c = idx - r * 96;
      Wl[c * 104 + r] = W[r * 384 + kc * 96 + c];
    }
    __syncthreads();
#pragma unroll 2
    for (int c = 0; c < 96; ++c) {
      float xv = xc[jj * 97 + c];
      const float4 w0 = *(const float4*)&Wl[c * 104 + r0];
      const float4 w1 = *(const float4*)&Wl[c * 104 + r0 + 4];
      acc[0] = fmaf(w0.x, xv, acc[0]); acc[1] = fmaf(w0.y, xv, acc[1]);
      acc[2] = fmaf(w0.z, xv, acc[2]); acc[3] = fmaf(w0.w, xv, acc[3]);
      acc[4] = fmaf(w1.x, xv, acc[4]); acc[5] = fmaf(w1.y, xv, acc[5]);
      acc[6] = fmaf(w1.z, xv, acc[6]); acc[7] = fmaf(w1.w, xv, acc[7]);
    }
  }
#pragma unroll
  for (int t = 0; t < 8; ++t) {
    float v = acc[t];
    v += __shfl_xor(v, 1); v += __shfl_xor(v, 2);
    v += __shfl_xor(v, 4); v += __shfl_xor(v, 8);
    if (rq < 12) {
      t3[(b * 96 + r0 + t) * LTOT + l0 + jj] = acc[t];
      if (jj == 0) atomicAdd(&se[b * 96 + r0 + t], v);
    }
  }
}

// ---------------- K9a: SE MLP -> smul = 1 + sigmoid(...) ----------------
__global__ __launch_bounds__(256) void k9a_se(const float* __restrict__ se,
                                              const float* __restrict__ w1,
                                              const float* __restrict__ sb1,
                                              const float* __restrict__ w2,
                                              const float* __restrict__ sb2,
                                              float* __restrict__ smul) {
  __shared__ float sm[192];
  __shared__ float s1[96];
  int t = threadIdx.x;
  if (t < 192) sm[t] = se[t] * (1.f / 2304.f);
  __syncthreads();
  if (t < 96) {
    int b = t / 48, i = t % 48;
    float acc = sb1[i];
    for (int m = 0; m < 96; ++m) acc = fmaf(w1[i * 96 + m], sm[b * 96 + m], acc);
    s1[t] = fmaxf(acc, 0.f);
  }
  __syncthreads();
  if (t < 192) {
    int b = t / 96, j = t % 96;
    float acc = sb2[j];
    for (int i = 0; i < 48; ++i) acc = fmaf(w2[j * 48 + i], s1[b * 48 + i], acc);
    smul[t] = 1.f + 1.f / (1.f + __expf(-acc));
  }
}

// ---------------- K9b: out[b,j,l] = t3[b,j,l] * smul[b,j] (pure streaming) ----------------
__global__ __launch_bounds__(256) void k9b_out(const float* __restrict__ t3,
                                               const float* __restrict__ smul,
                                               float* __restrict__ out) {
  int g = blockIdx.x * 256 + threadIdx.x;
  if (g >= 2 * 96 * LTOT) return;
  int bj = g / LTOT;
  out[g] = t3[g] * smul[bj];
}

extern "C" void kernel_launch(void* const* d_in, const int* in_sizes, int n_in,
                              void* d_out, int out_size, void* d_ws, size_t ws_size,
                              hipStream_t stream) {
  const float* x     = (const float*)d_in[0];
  const float* inw   = (const float*)d_in[1];
  const float* convw = (const float*)d_in[2];
  const float* convb = (const float*)d_in[3];
  const float* xpw   = (const float*)d_in[4];
  const float* dtw   = (const float*)d_in[5];
  const float* dtb   = (const float*)d_in[6];
  const float* Alog  = (const float*)d_in[7];
  const float* Ds    = (const float*)d_in[8];
  const float* lng   = (const float*)d_in[9];
  const float* lnb   = (const float*)d_in[10];
  const float* c1w   = (const float*)d_in[11];
  const float* c1b   = (const float*)d_in[12];
  const float* bn1g  = (const float*)d_in[13];
  const float* bn1b  = (const float*)d_in[14];
  const float* bn1m  = (const float*)d_in[15];
  const float* bn1v  = (const float*)d_in[16];
  const float* c2w   = (const float*)d_in[17];
  const float* c2b   = (const float*)d_in[18];
  const float* bn2g  = (const float*)d_in[19];
  const float* bn2b  = (const float*)d_in[20];
  const float* bn2m  = (const float*)d_in[21];
  const float* bn2v  = (const float*)d_in[22];
  const float* c3w   = (const float*)d_in[23];
  const float* c3b   = (const float*)d_in[24];
  const float* se1w  = (const float*)d_in[25];
  const float* se1b  = (const float*)d_in[26];
  const float* se2w  = (const float*)d_in[27];
  const float* se2b  = (const float*)d_in[28];

  float* ws = (float*)d_ws;
  float* xi_pre = ws;                    // 884736
  float* z      = ws + 884736;           // 884736  (becomes u after k5)
  float* xi     = ws + 1769472;          // 884736
  float* dlt    = ws + 2654208;          // 3538944 (reused as t1/t2)
  float* bT     = ws + 6193152;          // 589824
  float* cT     = ws + 6782976;          // 589824  (reused as t3)
  float* ys     = ws + 7372800;          // 884736
  float* q      = ws + 8257536;          // 2359296
  float* Ts     = ws + 10616832;         // 147456
  float* se     = ws + 10764288;         // 192
  float* smul   = ws + 10764480;         // 192
  float* t1 = dlt;
  float* t2 = dlt + 1769472;
  float* t3 = cT;

  hipMemsetAsync(ys, 0, 884736 * sizeof(float), stream);
  hipMemsetAsync(se, 0, 192 * sizeof(float), stream);

  k1_inproj<<<dim3(36, 6, 2), 256, 0, stream>>>(x, inw, xi_pre, z);
  k2_dwconv<<<3456, 256, 0, stream>>>(xi_pre, convw, convb, xi);
  k3_xproj<<<dim3(72, 4, 2), 256, 0, stream>>>(xi, xpw, dtw, dtb, dlt, bT, cT);
  k4a_scan1<<<dim3(24, 3, 8), 256, 0, stream>>>(dlt, xi, bT, Alog, q, Ts);
  k4b_comb<<<96, 256, 0, stream>>>(Alog, Ts, q);
  k4c_scan2<<<dim3(24, 3, 8), 256, 0, stream>>>(dlt, xi, bT, cT, Alog, q, ys);
  k5_ln<<<1152, 256, 0, stream>>>(ys, Ds, lng, lnb, z);
  k6_c1<<<dim3(36, 6, 2), 256, 0, stream>>>(z, c1w, c1b, bn1g, bn1b, bn1m, bn1v, t1);
  k7_dw2<<<6912, 256, 0, stream>>>(t1, c2w, c2b, bn2g, bn2b, bn2m, bn2v, t2);
  k8_c3<<<dim3(144, 2), 256, 0, stream>>>(t2, c3w, c3b, t3, se);
  k9a_se<<<1, 256, 0, stream>>>(se, se1w, se1b, se2w, se2b, smul);
  k9b_out<<<1728, 256, 0, stream>>>(t3, smul, (float*)d_out);
}

// Round 5
// 349.373 us; speedup vs baseline: 1.2736x; 1.1208x over previous
//
#include <hip/hip_runtime.h>
#include <hip/hip_bf16.h>

#define LTOT 2304
#define ECH  192
#define NCH  16
#define CCH  96   // chunks over L
#define SCH  24   // steps per chunk

__device__ __forceinline__ int permS(int k, int l) {
  if (k == 0) return l;
  if (k == 1) return LTOT - 1 - l;
  int m = (k == 2) ? l : (LTOT - 1 - l);
  return (m % 48) * 48 + (m / 48);
}

__device__ __forceinline__ float softplusf(float x) {
  return (x > 20.f) ? x : log1pf(__expf(x));
}

// ---------------- K1: in_proj GEMM (384x96) -> xi_pre (B,L,E), z (B,L,E) ----------------
// 4pos x 4rows/thread; x LDS [pos][c] pad97; W LDS [c][r] pad68 broadcast b128.
__global__ __launch_bounds__(256) void k1_inproj(const float* __restrict__ x,
                                                 const float* __restrict__ W,
                                                 float* __restrict__ xi_pre,
                                                 float* __restrict__ z) {
  const int l0 = blockIdx.x * 64;
  const int o0 = blockIdx.y * 64;
  const int b  = blockIdx.z;
  __shared__ __align__(16) float xs[64 * 97];
  __shared__ __align__(16) float Wl[96 * 68];
  const int tid = threadIdx.x;
  for (int idx = tid; idx < 96 * 64; idx += 256) {
    int i = idx & 63, c = idx >> 6;
    xs[i * 97 + c] = x[(b * 96 + c) * LTOT + l0 + i];
  }
  for (int idx = tid; idx < 64 * 96; idx += 256) {
    int r = idx / 96, c = idx - r * 96;
    Wl[c * 68 + r] = W[(o0 + r) * 96 + c];
  }
  __syncthreads();
  const int lane = tid & 63, w = tid >> 6;
  const int jj = lane & 15, rq = lane >> 4;
  const int rbase = 16 * w + 4 * rq;
  float acc[4][4];
#pragma unroll
  for (int p = 0; p < 4; ++p)
#pragma unroll
    for (int t = 0; t < 4; ++t) acc[p][t] = 0.f;
#pragma unroll 2
  for (int c = 0; c < 96; ++c) {
    const float4 wv = *(const float4*)&Wl[c * 68 + rbase];
    float xv[4];
#pragma unroll
    for (int p = 0; p < 4; ++p) xv[p] = xs[(jj + 16 * p) * 97 + c];
#pragma unroll
    for (int p = 0; p < 4; ++p) {
      acc[p][0] = fmaf(wv.x, xv[p], acc[p][0]);
      acc[p][1] = fmaf(wv.y, xv[p], acc[p][1]);
      acc[p][2] = fmaf(wv.z, xv[p], acc[p][2]);
      acc[p][3] = fmaf(wv.w, xv[p], acc[p][3]);
    }
  }
  __syncthreads();
  float* ol = xs;  // reuse: [r][pos] pad 65
#pragma unroll
  for (int p = 0; p < 4; ++p)
#pragma unroll
    for (int t = 0; t < 4; ++t) ol[(rbase + t) * 65 + jj + 16 * p] = acc[p][t];
  __syncthreads();
  for (int idx = tid; idx < 64 * 64; idx += 256) {
    int r = idx & 63, pos = idx >> 6;
    float v = ol[r * 65 + pos];
    int o = o0 + r, l = l0 + pos;
    if (o < ECH) xi_pre[(b * LTOT + l) * ECH + o] = v;
    else         z[(b * LTOT + l) * ECH + (o - ECH)] = v;
  }
}

// ---------------- K2: depthwise 3x3 conv + SiLU -> xi (B,L,E) ----------------
__global__ __launch_bounds__(256) void k2_dwconv(const float* __restrict__ xi_pre,
                                                 const float* __restrict__ cw,
                                                 const float* __restrict__ cb,
                                                 float* __restrict__ xi) {
  int g = blockIdx.x * 256 + threadIdx.x;
  if (g >= 2 * LTOT * ECH) return;
  int e = g % ECH; int l = (g / ECH) % LTOT; int b = g / (ECH * LTOT);
  int h = l / 48, wq = l % 48;
  float acc = cb[e];
#pragma unroll
  for (int kh = 0; kh < 3; ++kh) {
    int hh = h + kh - 1; if (hh < 0 || hh >= 48) continue;
#pragma unroll
    for (int kw = 0; kw < 3; ++kw) {
      int ww = wq + kw - 1; if (ww < 0 || ww >= 48) continue;
      acc = fmaf(cw[e * 9 + kh * 3 + kw], xi_pre[(b * LTOT + hh * 48 + ww) * ECH + e], acc);
    }
  }
  xi[g] = acc / (1.f + __expf(-acc));
}

// ---------------- K3: x_proj (38x192) + dt_proj (192x6) + softplus ----------------
__global__ __launch_bounds__(256) void k3_xproj(const float* __restrict__ xi,
                                                const float* __restrict__ xw,
                                                const float* __restrict__ dtw,
                                                const float* __restrict__ dtb,
                                                float* __restrict__ dlt,
                                                float* __restrict__ bT,
                                                float* __restrict__ cT) {
  const int l0 = blockIdx.x * 32;  // 72
  const int k  = blockIdx.y;       // 4
  const int b  = blockIdx.z;       // 2
  __shared__ __align__(16) float xs[32 * 193];  // [j][c]
  __shared__ __align__(16) float Wl[192 * 40];  // [c][r]
  __shared__ float dl6[6 * 33];
  const int tid = threadIdx.x;
  for (int idx = tid; idx < 32 * 192; idx += 256) {
    int j = idx / 192, c = idx - j * 192;
    int s = permS(k, l0 + j);
    xs[j * 193 + c] = xi[(b * LTOT + s) * ECH + c];
  }
  const float* wsrc = xw + k * 38 * ECH;
  for (int idx = tid; idx < 38 * 192; idx += 256) {
    int r = idx / 192, c = idx - r * 192;
    Wl[c * 40 + r] = wsrc[idx];
  }
  __syncthreads();
  const int lane = tid & 63, w = tid >> 6;
  const int jj = lane & 15;
  const int rq = w * 4 + (lane >> 4);   // [0,16), active < 10
  const int rqc = rq < 9 ? rq : 9;
  const int j0 = 2 * jj;
  float a00 = 0.f, a01 = 0.f, a02 = 0.f, a03 = 0.f;
  float a10 = 0.f, a11 = 0.f, a12 = 0.f, a13 = 0.f;
#pragma unroll 4
  for (int c = 0; c < 192; ++c) {
    float x0 = xs[j0 * 193 + c];
    float x1 = xs[j0 * 193 + 193 + c];
    const float4 wv = *(const float4*)&Wl[c * 40 + 4 * rqc];
    a00 = fmaf(wv.x, x0, a00); a01 = fmaf(wv.y, x0, a01);
    a02 = fmaf(wv.z, x0, a02); a03 = fmaf(wv.w, x0, a03);
    a10 = fmaf(wv.x, x1, a10); a11 = fmaf(wv.y, x1, a11);
    a12 = fmaf(wv.z, x1, a12); a13 = fmaf(wv.w, x1, a13);
  }
  const int bk = b * 4 + k;
  if (rq < 10) {
    float av[2][4] = {{a00, a01, a02, a03}, {a10, a11, a12, a13}};
#pragma unroll
    for (int t = 0; t < 4; ++t) {
      int r = 4 * rq + t;
      if (r >= 38) continue;
#pragma unroll
      for (int p = 0; p < 2; ++p) {
        int j = j0 + p;
        float v = av[p][t];
        if (r < 6)       dl6[r * 33 + j] = v;
        else if (r < 22) bT[((bk * LTOT) + l0 + j) * NCH + (r - 6)] = v;
        else             cT[((bk * LTOT) + l0 + j) * NCH + (r - 22)] = v;
      }
    }
  }
  __syncthreads();
  for (int idx = tid; idx < 32 * 192; idx += 256) {
    int j = idx / 192, d = idx - j * 192;
    float a = dtb[k * ECH + d];
    const float* wd = dtw + (k * ECH + d) * 6;
#pragma unroll
    for (int r = 0; r < 6; ++r) a = fmaf(wd[r], dl6[r * 33 + j], a);
    dlt[((bk * LTOT) + l0 + j) * ECH + d] = softplusf(a);
  }
}

// ---------------- K4a: chunk scan pass1 -> q (end states), Ts (chunk dlt sums) ----------------
__global__ __launch_bounds__(256) void k4a_scan1(const float* __restrict__ dlt,
                                                 const float* __restrict__ xi,
                                                 const float* __restrict__ bT,
                                                 const float* __restrict__ Alog,
                                                 float* __restrict__ q,
                                                 float* __restrict__ Ts) {
  const int cb = blockIdx.x;  // 24
  const int db = blockIdx.y;  // 3
  const int bk = blockIdx.z;  // 8
  const int b = bk >> 2, k = bk & 3;
  const int l0 = cb * 96;
  __shared__ float sdl[96 * 64];
  __shared__ float sxi[96 * 64];
  __shared__ __align__(16) float sb[96 * NCH];
  const int tid = threadIdx.x;
  const int dd = tid & 63, cg = tid >> 6;
  const int dg = db * 64 + dd;
  for (int j = cg; j < 96; j += 4) {
    sdl[j * 64 + dd] = dlt[(bk * LTOT + l0 + j) * ECH + dg];
    int s = permS(k, l0 + j);
    sxi[j * 64 + dd] = xi[(b * LTOT + s) * ECH + dg];
  }
  for (int idx = tid; idx < 96 * NCH; idx += 256) sb[idx] = bT[(bk * LTOT + l0) * NCH + idx];
  __syncthreads();
  float C1[16], C2[16], C3[16], h[16];
#pragma unroll
  for (int n = 0; n < 16; ++n) {
    float a = Alog[(k * ECH + dg) * NCH + n];
    C1[n] = a; C2[n] = 0.5f * a * a; C3[n] = (1.f / 6.f) * a * a * a;
    h[n] = 0.f;
  }
  float Tsum = 0.f;
  const int c = cb * 4 + cg;
  for (int i = 0; i < SCH; ++i) {
    int j = cg * SCH + i;
    float dl = sdl[j * 64 + dd];
    float u  = dl * sxi[j * 64 + dd];
    Tsum += dl;
    const float4* bb4 = (const float4*)(sb + j * NCH);
    float4 q0 = bb4[0], q1 = bb4[1], q2 = bb4[2], q3 = bb4[3];
    float bbl[16] = {q0.x, q0.y, q0.z, q0.w, q1.x, q1.y, q1.z, q1.w,
                     q2.x, q2.y, q2.z, q2.w, q3.x, q3.y, q3.z, q3.w};
    if (dl <= 0.018f) {
#pragma unroll
      for (int n = 0; n < 16; ++n) {
        float e = fmaf(dl, fmaf(dl, fmaf(dl, -C3[n], C2[n]), -C1[n]), 1.f);
        h[n] = fmaf(e, h[n], u * bbl[n]);
      }
    } else {
#pragma unroll
      for (int n = 0; n < 16; ++n) {
        float e = __expf(-C1[n] * dl);
        h[n] = fmaf(e, h[n], u * bbl[n]);
      }
    }
  }
  float* qp = q + ((bk * CCH + c) * ECH + dg) * NCH;
#pragma unroll
  for (int n = 0; n < 16; ++n) qp[n] = h[n];
  Ts[(bk * CCH + c) * ECH + dg] = Tsum;
}

// ---------------- K4b: cross-chunk combine (q -> per-chunk init states, in place) ----------------
__global__ __launch_bounds__(256) void k4b_comb(const float* __restrict__ Alog,
                                                const float* __restrict__ Ts,
                                                float* __restrict__ q) {
  int t = blockIdx.x * 256 + threadIdx.x;
  if (t >= 8 * ECH * NCH) return;
  int n = t & 15, d = (t >> 4) % ECH, bk = t / (NCH * ECH);
  int k = bk & 3;
  float A = Alog[(k * ECH + d) * NCH + n];
  float h = 0.f;
  for (int c = 0; c < CCH; ++c) {
    int base = ((bk * CCH + c) * ECH + d) * NCH + n;
    float qc = q[base];
    q[base] = h;  // becomes h_init for chunk c
    float xv = A * Ts[(bk * CCH + c) * ECH + d];
    float P = (xv <= 0.05f)
                  ? fmaf(xv, fmaf(xv, fmaf(xv, -(1.f / 6.f), 0.5f), -1.f), 1.f)
                  : __expf(-xv);
    h = fmaf(P, h, qc);
  }
}

// ---------------- K4c: chunk scan pass2 -> y, atomic accumulate into ys (B,L,E) ----------------
__global__ __launch_bounds__(256) void k4c_scan2(const float* __restrict__ dlt,
                                                 const float* __restrict__ xi,
                                                 const float* __restrict__ bT,
                                                 const float* __restrict__ cT,
                                                 const float* __restrict__ Alog,
                                                 const float* __restrict__ hin,
                                                 float* __restrict__ ys) {
  const int cb = blockIdx.x;
  const int db = blockIdx.y;
  const int bk = blockIdx.z;
  const int b = bk >> 2, k = bk & 3;
  const int l0 = cb * 96;
  __shared__ float sdl[96 * 64];
  __shared__ float sxi[96 * 64];
  __shared__ __align__(16) float sb[96 * NCH];
  __shared__ __align__(16) float sc[96 * NCH];
  const int tid = threadIdx.x;
  const int dd = tid & 63, cg = tid >> 6;
  const int dg = db * 64 + dd;
  for (int j = cg; j < 96; j += 4) {
    sdl[j * 64 + dd] = dlt[(bk * LTOT + l0 + j) * ECH + dg];
    int s = permS(k, l0 + j);
    sxi[j * 64 + dd] = xi[(b * LTOT + s) * ECH + dg];
  }
  for (int idx = tid; idx < 96 * NCH; idx += 256) {
    sb[idx] = bT[(bk * LTOT + l0) * NCH + idx];
    sc[idx] = cT[(bk * LTOT + l0) * NCH + idx];
  }
  __syncthreads();
  float C1[16], C2[16], C3[16], h[16];
  const int c = cb * 4 + cg;
  const float* hp = hin + ((bk * CCH + c) * ECH + dg) * NCH;
#pragma unroll
  for (int n = 0; n < 16; ++n) {
    float a = Alog[(k * ECH + dg) * NCH + n];
    C1[n] = a; C2[n] = 0.5f * a * a; C3[n] = (1.f / 6.f) * a * a * a;
    h[n] = hp[n];
  }
  for (int i = 0; i < SCH; ++i) {
    int j = cg * SCH + i;
    int l = l0 + j;
    float dl = sdl[j * 64 + dd];
    float u  = dl * sxi[j * 64 + dd];
    const float4* bb4 = (const float4*)(sb + j * NCH);
    float4 q0 = bb4[0], q1 = bb4[1], q2 = bb4[2], q3 = bb4[3];
    float bbl[16] = {q0.x, q0.y, q0.z, q0.w, q1.x, q1.y, q1.z, q1.w,
                     q2.x, q2.y, q2.z, q2.w, q3.x, q3.y, q3.z, q3.w};
    if (dl <= 0.018f) {
#pragma unroll
      for (int n = 0; n < 16; ++n) {
        float e = fmaf(dl, fmaf(dl, fmaf(dl, -C3[n], C2[n]), -C1[n]), 1.f);
        h[n] = fmaf(e, h[n], u * bbl[n]);
      }
    } else {
#pragma unroll
      for (int n = 0; n < 16; ++n) {
        float e = __expf(-C1[n] * dl);
        h[n] = fmaf(e, h[n], u * bbl[n]);
      }
    }
    const float4* cc4 = (const float4*)(sc + j * NCH);
    float4 c0 = cc4[0], c1 = cc4[1], c2 = cc4[2], c3 = cc4[3];
    float ccl[16] = {c0.x, c0.y, c0.z, c0.w, c1.x, c1.y, c1.z, c1.w,
                     c2.x, c2.y, c2.z, c2.w, c3.x, c3.y, c3.z, c3.w};
    float y = 0.f;
#pragma unroll
    for (int n = 0; n < 16; ++n) y = fmaf(h[n], ccl[n], y);
    int s = permS(k, l);
    atomicAdd(&ys[(b * LTOT + s) * ECH + dg], y);
  }
}

// ---------------- K5: LayerNorm over E (+Ds) then multiply by z (in-place over z) ----------------
__global__ __launch_bounds__(256) void k5_ln(const float* __restrict__ ys,
                                             const float* __restrict__ Ds,
                                             const float* __restrict__ lng,
                                             const float* __restrict__ lnb,
                                             float* __restrict__ zu) {
  int p = blockIdx.x * 4 + (threadIdx.x >> 6);
  int lane = threadIdx.x & 63;
  const float* yp = ys + p * ECH;
  float vd[3], sd[3];
#pragma unroll
  for (int t = 0; t < 3; ++t) {
    int d = lane + t * 64;
    vd[t] = yp[d];
    sd[t] = Ds[d] + Ds[ECH + d] + Ds[2 * ECH + d] + Ds[3 * ECH + d];
  }
  float s1 = vd[0] + vd[1] + vd[2];
  float s2 = sd[0] + sd[1] + sd[2];
#pragma unroll
  for (int off = 32; off > 0; off >>= 1) {
    s1 += __shfl_xor(s1, off, 64);
    s2 += __shfl_xor(s2, off, 64);
  }
  float mean_dot = s1 * (1.f / 192.f);
  float mean_sd  = s2 * (1.f / 192.f);
  float dev[3];
  float ss = 0.f;
#pragma unroll
  for (int t = 0; t < 3; ++t) {
    dev[t] = (vd[t] - mean_dot) + (sd[t] - mean_sd);
    ss = fmaf(dev[t], dev[t], ss);
  }
#pragma unroll
  for (int off = 32; off > 0; off >>= 1) ss += __shfl_xor(ss, off, 64);
  float rstd = 1.f / sqrtf(ss * (1.f / 192.f) + 1e-5f);
#pragma unroll
  for (int t = 0; t < 3; ++t) {
    int d = lane + t * 64;
    float yn = (dev[t] * rstd) * lng[d] + lnb[d];
    zu[p * ECH + d] = yn * zu[p * ECH + d];
  }
}

// ---------------- K6: c1 1x1 GEMM (384x192) + bn1 + relu -> t1 (B,384,L) ----------------
__global__ __launch_bounds__(256) void k6_c1(const float* __restrict__ u,
                                             const float* __restrict__ W,
                                             const float* __restrict__ c1b,
                                             const float* __restrict__ g1,
                                             const float* __restrict__ b1,
                                             const float* __restrict__ m1,
                                             const float* __restrict__ v1,
                                             float* __restrict__ t1) {
  const int l0 = blockIdx.x * 64;
  const int o0 = blockIdx.y * 64;
  const int b  = blockIdx.z;
  __shared__ __align__(16) float xs[64 * 97];
  __shared__ __align__(16) float Wl[96 * 68];
  const int tid = threadIdx.x;
  const int lane = tid & 63, w = tid >> 6;
  const int jj = lane & 15, rq = lane >> 4;
  const int rbase = 16 * w + 4 * rq;
  float acc[4][4];
#pragma unroll
  for (int p = 0; p < 4; ++p)
#pragma unroll
    for (int t = 0; t < 4; ++t) acc[p][t] = 0.f;
  for (int kc = 0; kc < 2; ++kc) {
    if (kc) __syncthreads();
    for (int idx = tid; idx < 64 * 96; idx += 256) {
      int i = idx / 96, c = idx - i * 96;
      xs[i * 97 + c] = u[(b * LTOT + l0 + i) * ECH + kc * 96 + c];
    }
    for (int idx = tid; idx < 64 * 96; idx += 256) {
      int r = idx / 96, c = idx - r * 96;
      Wl[c * 68 + r] = W[(o0 + r) * ECH + kc * 96 + c];
    }
    __syncthreads();
#pragma unroll 2
    for (int c = 0; c < 96; ++c) {
      const float4 wv = *(const float4*)&Wl[c * 68 + rbase];
      float xv[4];
#pragma unroll
      for (int p = 0; p < 4; ++p) xv[p] = xs[(jj + 16 * p) * 97 + c];
#pragma unroll
      for (int p = 0; p < 4; ++p) {
        acc[p][0] = fmaf(wv.x, xv[p], acc[p][0]);
        acc[p][1] = fmaf(wv.y, xv[p], acc[p][1]);
        acc[p][2] = fmaf(wv.z, xv[p], acc[p][2]);
        acc[p][3] = fmaf(wv.w, xv[p], acc[p][3]);
      }
    }
  }
  // bn + relu epilogue
#pragma unroll
  for (int t = 0; t < 4; ++t) {
    int o = o0 + rbase + t;
    float sc = g1[o] / sqrtf(v1[o] + 1e-5f);
    float bias = (c1b[o] - m1[o]) * sc + b1[o];
#pragma unroll
    for (int p = 0; p < 4; ++p) acc[p][t] = fmaxf(fmaf(acc[p][t], sc, bias), 0.f);
  }
  __syncthreads();
  float* ol = xs;  // [r][pos] pad 65
#pragma unroll
  for (int p = 0; p < 4; ++p)
#pragma unroll
    for (int t = 0; t < 4; ++t) ol[(rbase + t) * 65 + jj + 16 * p] = acc[p][t];
  __syncthreads();
  for (int idx = tid; idx < 64 * 64; idx += 256) {
    int pos = idx & 63, r = idx >> 6;
    t1[(b * 384 + o0 + r) * LTOT + l0 + pos] = ol[r * 65 + pos];
  }
}

// ---------------- K7: depthwise 3x3 on t1 (B,384,L) + bn2 + relu -> t2 (B,384,L) ----------------
__global__ __launch_bounds__(256) void k7_dw2(const float* __restrict__ t1,
                                              const float* __restrict__ cw,
                                              const float* __restrict__ cb,
                                              const float* __restrict__ g2,
                                              const float* __restrict__ b2,
                                              const float* __restrict__ m2,
                                              const float* __restrict__ v2,
                                              float* __restrict__ t2) {
  int g = blockIdx.x * 256 + threadIdx.x;
  if (g >= 2 * LTOT * 384) return;
  int l = g % LTOT; int o = (g / LTOT) % 384; int b = g / (LTOT * 384);
  int h = l / 48, wq = l % 48;
  const float* src = t1 + (b * 384 + o) * LTOT;
  float acc = cb[o];
#pragma unroll
  for (int kh = 0; kh < 3; ++kh) {
    int hh = h + kh - 1; if (hh < 0 || hh >= 48) continue;
#pragma unroll
    for (int kw = 0; kw < 3; ++kw) {
      int ww = wq + kw - 1; if (ww < 0 || ww >= 48) continue;
      acc = fmaf(cw[o * 9 + kh * 3 + kw], src[hh * 48 + ww], acc);
    }
  }
  float sc = g2[o] / sqrtf(v2[o] + 1e-5f);
  float val = (acc - m2[o]) * sc + b2[o];
  t2[g] = fmaxf(val, 0.f);
}

// ---------------- K8: c3 1x1 GEMM (96x384) on t2 (B,384,L) -> t3 (B,96,L) + SE sums ----------------
// 4pos x 2rows/thread, row-tile 32, K chunks of 96.
__global__ __launch_bounds__(256) void k8_c3(const float* __restrict__ t2,
                                             const float* __restrict__ W,
                                             const float* __restrict__ c3b,
                                             float* __restrict__ t3,
                                             float* __restrict__ se) {
  const int l0 = blockIdx.x * 64;  // 36
  const int r0 = blockIdx.y * 32;  // 3
  const int b  = blockIdx.z;       // 2
  __shared__ __align__(16) float xs[64 * 97];
  __shared__ __align__(16) float Wl[96 * 36];
  const int tid = threadIdx.x;
  const int lane = tid & 63, w = tid >> 6;
  const int jj = lane & 15, rq = lane >> 4;
  const int rloc = 8 * w + 2 * rq;  // local row base, 2 rows
  float acc[4][2];
#pragma unroll
  for (int p = 0; p < 4; ++p) { acc[p][0] = 0.f; acc[p][1] = 0.f; }
  for (int kc = 0; kc < 4; ++kc) {
    if (kc) __syncthreads();
    for (int idx = tid; idx < 64 * 96; idx += 256) {
      int i = idx & 63, c = idx >> 6;
      xs[i * 97 + c] = t2[(b * 384 + kc * 96 + c) * LTOT + l0 + i];
    }
    for (int idx = tid; idx < 32 * 96; idx += 256) {
      int r = idx / 96, c = idx - r * 96;
      Wl[c * 36 + r] = W[(r0 + r) * 384 + kc * 96 + c];
    }
    __syncthreads();
#pragma unroll 2
    for (int c = 0; c < 96; ++c) {
      const float2 wv = *(const float2*)&Wl[c * 36 + rloc];
      float xv[4];
#pragma unroll
      for (int p = 0; p < 4; ++p) xv[p] = xs[(jj + 16 * p) * 97 + c];
#pragma unroll
      for (int p = 0; p < 4; ++p) {
        acc[p][0] = fmaf(wv.x, xv[p], acc[p][0]);
        acc[p][1] = fmaf(wv.y, xv[p], acc[p][1]);
      }
    }
  }
#pragma unroll
  for (int t = 0; t < 2; ++t) {
    float bias = c3b[r0 + rloc + t];
#pragma unroll
    for (int p = 0; p < 4; ++p) acc[p][t] += bias;
  }
  // SE partial sums: reduce each row over this block's 64 positions
#pragma unroll
  for (int t = 0; t < 2; ++t) {
    float v = acc[0][t] + acc[1][t] + acc[2][t] + acc[3][t];
    v += __shfl_xor(v, 1); v += __shfl_xor(v, 2);
    v += __shfl_xor(v, 4); v += __shfl_xor(v, 8);
    if (jj == 0) atomicAdd(&se[b * 96 + r0 + rloc + t], v);
  }
  __syncthreads();
  float* ol = xs;  // [r][pos] pad 65
#pragma unroll
  for (int p = 0; p < 4; ++p)
#pragma unroll
    for (int t = 0; t < 2; ++t) ol[(rloc + t) * 65 + jj + 16 * p] = acc[p][t];
  __syncthreads();
  for (int idx = tid; idx < 32 * 64; idx += 256) {
    int pos = idx & 63, r = idx >> 6;
    t3[(b * 96 + r0 + r) * LTOT + l0 + pos] = ol[r * 65 + pos];
  }
}

// ---------------- K9a: SE MLP -> smul = 1 + sigmoid(...) ----------------
__global__ __launch_bounds__(256) void k9a_se(const float* __restrict__ se,
                                              const float* __restrict__ w1,
                                              const float* __restrict__ sb1,
                                              const float* __restrict__ w2,
                                              const float* __restrict__ sb2,
                                              float* __restrict__ smul) {
  __shared__ float sm[192];
  __shared__ float s1[96];
  int t = threadIdx.x;
  if (t < 192) sm[t] = se[t] * (1.f / 2304.f);
  __syncthreads();
  if (t < 96) {
    int b = t / 48, i = t % 48;
    float acc = sb1[i];
    for (int m = 0; m < 96; ++m) acc = fmaf(w1[i * 96 + m], sm[b * 96 + m], acc);
    s1[t] = fmaxf(acc, 0.f);
  }
  __syncthreads();
  if (t < 192) {
    int b = t / 96, j = t % 96;
    float acc = sb2[j];
    for (int i = 0; i < 48; ++i) acc = fmaf(w2[j * 48 + i], s1[b * 48 + i], acc);
    smul[t] = 1.f + 1.f / (1.f + __expf(-acc));
  }
}

// ---------------- K9b: out[b,j,l] = t3[b,j,l] * smul[b,j] (pure streaming) ----------------
__global__ __launch_bounds__(256) void k9b_out(const float* __restrict__ t3,
                                               const float* __restrict__ smul,
                                               float* __restrict__ out) {
  int g = blockIdx.x * 256 + threadIdx.x;
  if (g >= 2 * 96 * LTOT) return;
  int bj = g / LTOT;
  out[g] = t3[g] * smul[bj];
}

extern "C" void kernel_launch(void* const* d_in, const int* in_sizes, int n_in,
                              void* d_out, int out_size, void* d_ws, size_t ws_size,
                              hipStream_t stream) {
  const float* x     = (const float*)d_in[0];
  const float* inw   = (const float*)d_in[1];
  const float* convw = (const float*)d_in[2];
  const float* convb = (const float*)d_in[3];
  const float* xpw   = (const float*)d_in[4];
  const float* dtw   = (const float*)d_in[5];
  const float* dtb   = (const float*)d_in[6];
  const float* Alog  = (const float*)d_in[7];
  const float* Ds    = (const float*)d_in[8];
  const float* lng   = (const float*)d_in[9];
  const float* lnb   = (const float*)d_in[10];
  const float* c1w   = (const float*)d_in[11];
  const float* c1b   = (const float*)d_in[12];
  const float* bn1g  = (const float*)d_in[13];
  const float* bn1b  = (const float*)d_in[14];
  const float* bn1m  = (const float*)d_in[15];
  const float* bn1v  = (const float*)d_in[16];
  const float* c2w   = (const float*)d_in[17];
  const float* c2b   = (const float*)d_in[18];
  const float* bn2g  = (const float*)d_in[19];
  const float* bn2b  = (const float*)d_in[20];
  const float* bn2m  = (const float*)d_in[21];
  const float* bn2v  = (const float*)d_in[22];
  const float* c3w   = (const float*)d_in[23];
  const float* c3b   = (const float*)d_in[24];
  const float* se1w  = (const float*)d_in[25];
  const float* se1b  = (const float*)d_in[26];
  const float* se2w  = (const float*)d_in[27];
  const float* se2b  = (const float*)d_in[28];

  float* ws = (float*)d_ws;
  float* xi_pre = ws;                    // 884736
  float* z      = ws + 884736;           // 884736  (becomes u after k5)
  float* xi     = ws + 1769472;          // 884736
  float* dlt    = ws + 2654208;          // 3538944 (reused as t1/t2)
  float* bT     = ws + 6193152;          // 589824
  float* cT     = ws + 6782976;          // 589824  (reused as t3)
  float* ys     = ws + 7372800;          // 884736
  float* q      = ws + 8257536;          // 2359296
  float* Ts     = ws + 10616832;         // 147456
  float* se     = ws + 10764288;         // 192
  float* smul   = ws + 10764480;         // 192
  float* t1 = dlt;
  float* t2 = dlt + 1769472;
  float* t3 = cT;

  hipMemsetAsync(ys, 0, 884736 * sizeof(float), stream);
  hipMemsetAsync(se, 0, 192 * sizeof(float), stream);

  k1_inproj<<<dim3(36, 6, 2), 256, 0, stream>>>(x, inw, xi_pre, z);
  k2_dwconv<<<3456, 256, 0, stream>>>(xi_pre, convw, convb, xi);
  k3_xproj<<<dim3(72, 4, 2), 256, 0, stream>>>(xi, xpw, dtw, dtb, dlt, bT, cT);
  k4a_scan1<<<dim3(24, 3, 8), 256, 0, stream>>>(dlt, xi, bT, Alog, q, Ts);
  k4b_comb<<<96, 256, 0, stream>>>(Alog, Ts, q);
  k4c_scan2<<<dim3(24, 3, 8), 256, 0, stream>>>(dlt, xi, bT, cT, Alog, q, ys);
  k5_ln<<<1152, 256, 0, stream>>>(ys, Ds, lng, lnb, z);
  k6_c1<<<dim3(36, 6, 2), 256, 0, stream>>>(z, c1w, c1b, bn1g, bn1b, bn1m, bn1v, t1);
  k7_dw2<<<6912, 256, 0, stream>>>(t1, c2w, c2b, bn2g, bn2b, bn2m, bn2v, t2);
  k8_c3<<<dim3(36, 3, 2), 256, 0, stream>>>(t2, c3w, c3b, t3, se);
  k9a_se<<<1, 256, 0, stream>>>(se, se1w, se1b, se2w, se2b, smul);
  k9b_out<<<1728, 256, 0, stream>>>(t3, smul, (float*)d_out);
}

// Round 6
// 329.061 us; speedup vs baseline: 1.3522x; 1.0617x over previous
//
#include <hip/hip_runtime.h>
#include <hip/hip_bf16.h>

#define LTOT 2304
#define ECH  192
#define NCH  16
#define CCH  96   // chunks over L
#define SCH  24   // steps per chunk

__device__ __forceinline__ int permS(int k, int l) {
  if (k == 0) return l;
  if (k == 1) return LTOT - 1 - l;
  int m = (k == 2) ? l : (LTOT - 1 - l);
  return (m % 48) * 48 + (m / 48);
}

// fast softplus for x ~ -9: t=e^x tiny -> log1p(t) ~= t(1 - t/2 + t^2/3)
__device__ __forceinline__ float sp_fast(float x) {
  float t = __expf(x);
  return (t <= 0.018f) ? t * fmaf(t, fmaf(t, 0.33333334f, -0.5f), 1.f) : log1pf(t);
}

// ---------------- K1: in_proj GEMM (384x96) -> xi_pre (B,L,E), z (B,L,E) ----------------
__global__ __launch_bounds__(256) void k1_inproj(const float* __restrict__ x,
                                                 const float* __restrict__ W,
                                                 float* __restrict__ xi_pre,
                                                 float* __restrict__ z) {
  const int l0 = blockIdx.x * 64;
  const int o0 = blockIdx.y * 64;
  const int b  = blockIdx.z;
  __shared__ __align__(16) float xs[96 * 66];  // [c][pos] pad 66
  __shared__ __align__(16) float Wl[96 * 68];  // [c][r]   pad 68
  const int tid = threadIdx.x;
  for (int idx = tid; idx < 96 * 64; idx += 256) {
    int i = idx & 63, cc = idx >> 6;
    xs[cc * 66 + i] = x[(b * 96 + cc) * LTOT + l0 + i];
  }
  for (int idx = tid; idx < 64 * 96; idx += 256) {
    int r = idx / 96, cc = idx - r * 96;
    Wl[cc * 68 + r] = W[(o0 + r) * 96 + cc];
  }
  __syncthreads();
  const int lane = tid & 63, w = tid >> 6;
  const int jj = lane & 15, rqq = lane >> 4;
  const int rbase = 16 * w + 4 * rqq;
  float acc[4][4];  // [p][t], pos(p) = (p>>1)*32 + 2*jj + (p&1)
#pragma unroll
  for (int p = 0; p < 4; ++p)
#pragma unroll
    for (int t = 0; t < 4; ++t) acc[p][t] = 0.f;
#pragma unroll 2
  for (int cc = 0; cc < 96; ++cc) {
    const float4 wv = *(const float4*)&Wl[cc * 68 + rbase];
    const float2 xa = *(const float2*)&xs[cc * 66 + 2 * jj];
    const float2 xb = *(const float2*)&xs[cc * 66 + 32 + 2 * jj];
    acc[0][0] = fmaf(wv.x, xa.x, acc[0][0]); acc[0][1] = fmaf(wv.y, xa.x, acc[0][1]);
    acc[0][2] = fmaf(wv.z, xa.x, acc[0][2]); acc[0][3] = fmaf(wv.w, xa.x, acc[0][3]);
    acc[1][0] = fmaf(wv.x, xa.y, acc[1][0]); acc[1][1] = fmaf(wv.y, xa.y, acc[1][1]);
    acc[1][2] = fmaf(wv.z, xa.y, acc[1][2]); acc[1][3] = fmaf(wv.w, xa.y, acc[1][3]);
    acc[2][0] = fmaf(wv.x, xb.x, acc[2][0]); acc[2][1] = fmaf(wv.y, xb.x, acc[2][1]);
    acc[2][2] = fmaf(wv.z, xb.x, acc[2][2]); acc[2][3] = fmaf(wv.w, xb.x, acc[2][3]);
    acc[3][0] = fmaf(wv.x, xb.y, acc[3][0]); acc[3][1] = fmaf(wv.y, xb.y, acc[3][1]);
    acc[3][2] = fmaf(wv.z, xb.y, acc[3][2]); acc[3][3] = fmaf(wv.w, xb.y, acc[3][3]);
  }
  __syncthreads();
  float* ol = xs;  // [r][pos] pad 65 (64*65 <= 96*66)
#pragma unroll
  for (int t = 0; t < 4; ++t) {
    ol[(rbase + t) * 65 + 2 * jj]      = acc[0][t];
    ol[(rbase + t) * 65 + 2 * jj + 1]  = acc[1][t];
    ol[(rbase + t) * 65 + 2 * jj + 32] = acc[2][t];
    ol[(rbase + t) * 65 + 2 * jj + 33] = acc[3][t];
  }
  __syncthreads();
  for (int idx = tid; idx < 64 * 64; idx += 256) {
    int r = idx & 63, pos = idx >> 6;
    float v = ol[r * 65 + pos];
    int o = o0 + r, l = l0 + pos;
    if (o < ECH) xi_pre[(b * LTOT + l) * ECH + o] = v;
    else         z[(b * LTOT + l) * ECH + (o - ECH)] = v;
  }
}

// ---------------- K2: depthwise 3x3 conv + SiLU -> xi (B,L,E) ----------------
__global__ __launch_bounds__(256) void k2_dwconv(const float* __restrict__ xi_pre,
                                                 const float* __restrict__ cw,
                                                 const float* __restrict__ cb,
                                                 float* __restrict__ xi) {
  int g = blockIdx.x * 256 + threadIdx.x;
  if (g >= 2 * LTOT * ECH) return;
  int e = g % ECH; int l = (g / ECH) % LTOT; int b = g / (ECH * LTOT);
  int h = l / 48, wq = l % 48;
  float acc = cb[e];
#pragma unroll
  for (int kh = 0; kh < 3; ++kh) {
    int hh = h + kh - 1; if (hh < 0 || hh >= 48) continue;
#pragma unroll
    for (int kw = 0; kw < 3; ++kw) {
      int ww = wq + kw - 1; if (ww < 0 || ww >= 48) continue;
      acc = fmaf(cw[e * 9 + kh * 3 + kw], xi_pre[(b * LTOT + hh * 48 + ww) * ECH + e], acc);
    }
  }
  xi[g] = acc / (1.f + __expf(-acc));
}

// ---------------- K3: x_proj (38x192) -> dl6g (rank-6), bT, cT. Pure GEMM. ----------------
__global__ __launch_bounds__(256) void k3_xproj(const float* __restrict__ xi,
                                                const float* __restrict__ xw,
                                                float* __restrict__ dl6g,
                                                float* __restrict__ bT,
                                                float* __restrict__ cT) {
  const int l0 = blockIdx.x * 32;  // 72
  const int k  = blockIdx.y;       // 4
  const int b  = blockIdx.z;       // 2
  __shared__ __align__(16) float xs[96 * 34];   // [c][j] per c-chunk, pad 34
  __shared__ __align__(16) float Wl[192 * 40];  // [c][r] pad 40
  const int tid = threadIdx.x;
  const float* wsrc = xw + k * 38 * ECH;
  for (int idx = tid; idx < 38 * 192; idx += 256) {
    int r = idx / 192, cc = idx - r * 192;
    Wl[cc * 40 + r] = wsrc[idx];
  }
  const int lane = tid & 63, w = tid >> 6;
  const int jj = lane & 15;
  const int rq = w * 4 + (lane >> 4);   // [0,16), active < 10
  const int rqc = rq < 9 ? rq : 9;
  const int j0 = 2 * jj;
  float a00 = 0.f, a01 = 0.f, a02 = 0.f, a03 = 0.f;
  float a10 = 0.f, a11 = 0.f, a12 = 0.f, a13 = 0.f;
  for (int kc = 0; kc < 2; ++kc) {
    __syncthreads();  // covers W staging (kc=0) and xs reuse (kc=1)
    for (int idx = tid; idx < 32 * 96; idx += 256) {
      int j = idx / 96, cc = idx - j * 96;
      int s = permS(k, l0 + j);
      xs[cc * 34 + j] = xi[(b * LTOT + s) * ECH + kc * 96 + cc];
    }
    __syncthreads();
#pragma unroll 4
    for (int cc = 0; cc < 96; ++cc) {
      const float2 xv = *(const float2*)&xs[cc * 34 + j0];
      const float4 wv = *(const float4*)&Wl[(kc * 96 + cc) * 40 + 4 * rqc];
      a00 = fmaf(wv.x, xv.x, a00); a01 = fmaf(wv.y, xv.x, a01);
      a02 = fmaf(wv.z, xv.x, a02); a03 = fmaf(wv.w, xv.x, a03);
      a10 = fmaf(wv.x, xv.y, a10); a11 = fmaf(wv.y, xv.y, a11);
      a12 = fmaf(wv.z, xv.y, a12); a13 = fmaf(wv.w, xv.y, a13);
    }
  }
  const int bk = b * 4 + k;
  if (rq < 10) {
    float av[2][4] = {{a00, a01, a02, a03}, {a10, a11, a12, a13}};
#pragma unroll
    for (int t = 0; t < 4; ++t) {
      int r = 4 * rq + t;
      if (r >= 38) continue;
#pragma unroll
      for (int p = 0; p < 2; ++p) {
        int j = j0 + p;
        float v = av[p][t];
        if (r < 6)       dl6g[((bk * LTOT) + l0 + j) * 6 + r] = v;
        else if (r < 22) bT[((bk * LTOT) + l0 + j) * NCH + (r - 6)] = v;
        else             cT[((bk * LTOT) + l0 + j) * NCH + (r - 22)] = v;
      }
    }
  }
}

// ---------------- K4a: chunk scan pass1 (inline dlt) -> q, Ts ----------------
__global__ __launch_bounds__(256) void k4a_scan1(const float* __restrict__ dl6g,
                                                 const float* __restrict__ xi,
                                                 const float* __restrict__ bT,
                                                 const float* __restrict__ Alog,
                                                 const float* __restrict__ dtw,
                                                 const float* __restrict__ dtb,
                                                 float* __restrict__ q,
                                                 float* __restrict__ Ts) {
  const int cb = blockIdx.x;  // 24
  const int db = blockIdx.y;  // 3
  const int bk = blockIdx.z;  // 8
  const int b = bk >> 2, k = bk & 3;
  const int l0 = cb * 96;
  __shared__ __align__(16) float2 sdx[48 * 64];   // half-staged (dl, xi)
  __shared__ __align__(16) float  sb[96 * NCH];
  __shared__ __align__(16) float  sdl6[96 * 6];
  const int tid = threadIdx.x;
  const int dd = tid & 63, cg = tid >> 6;
  const int dg = db * 64 + dd;
  float b6 = dtb[k * ECH + dg];
  float w6[6];
  {
    const float2* d2 = (const float2*)(dtw + (k * ECH + dg) * 6);
    float2 u0 = d2[0], u1 = d2[1], u2 = d2[2];
    w6[0] = u0.x; w6[1] = u0.y; w6[2] = u1.x; w6[3] = u1.y; w6[4] = u2.x; w6[5] = u2.y;
  }
  for (int idx = tid; idx < 96 * 6; idx += 256) sdl6[idx] = dl6g[(bk * LTOT + l0) * 6 + idx];
  for (int idx = tid; idx < 96 * NCH; idx += 256) sb[idx] = bT[(bk * LTOT + l0) * NCH + idx];
  float C1[16], h[16];
#pragma unroll
  for (int n = 0; n < 16; ++n) {
    C1[n] = Alog[(k * ECH + dg) * NCH + n];
    h[n] = 0.f;
  }
  float Tsum = 0.f;
  const int c = cb * 4 + cg;
  for (int half = 0; half < 2; ++half) {
    __syncthreads();
    for (int e = tid; e < 48 * 64; e += 256) {  // e&63 == dd always (stride 256)
      int s = e >> 6;
      int j = (s / 12) * 24 + half * 12 + (s % 12);
      const float* d6 = sdl6 + j * 6;
      float xa = b6;
#pragma unroll
      for (int r = 0; r < 6; ++r) xa = fmaf(w6[r], d6[r], xa);
      float dl = sp_fast(xa);
      int sp = permS(k, l0 + j);
      float xiv = xi[(b * LTOT + sp) * ECH + dg];
      sdx[s * 64 + dd] = make_float2(dl, xiv);
    }
    __syncthreads();
    for (int i = 0; i < 12; ++i) {
      int j = cg * 24 + half * 12 + i;
      float2 dx = sdx[(cg * 12 + i) * 64 + dd];
      float dl = dx.x;
      float u  = dl * dx.y;
      Tsum += dl;
      const float4* bb4 = (const float4*)(sb + j * NCH);
      float4 q0 = bb4[0], q1 = bb4[1], q2 = bb4[2], q3 = bb4[3];
      float bbl[16] = {q0.x, q0.y, q0.z, q0.w, q1.x, q1.y, q1.z, q1.w,
                       q2.x, q2.y, q2.z, q2.w, q3.x, q3.y, q3.z, q3.w};
      if (dl <= 0.018f) {
#pragma unroll
        for (int n = 0; n < 16; ++n) {
          float xn = C1[n] * dl;
          float e = fmaf(xn, fmaf(xn, fmaf(xn, -(1.f / 6.f), 0.5f), -1.f), 1.f);
          h[n] = fmaf(e, h[n], u * bbl[n]);
        }
      } else {
#pragma unroll
        for (int n = 0; n < 16; ++n) {
          float e = __expf(-C1[n] * dl);
          h[n] = fmaf(e, h[n], u * bbl[n]);
        }
      }
    }
  }
  float4* qp = (float4*)(q + ((bk * CCH + c) * ECH + dg) * NCH);
  qp[0] = make_float4(h[0], h[1], h[2], h[3]);
  qp[1] = make_float4(h[4], h[5], h[6], h[7]);
  qp[2] = make_float4(h[8], h[9], h[10], h[11]);
  qp[3] = make_float4(h[12], h[13], h[14], h[15]);
  Ts[(bk * CCH + c) * ECH + dg] = Tsum;
}

// ---------------- K4b: cross-chunk combine (q -> per-chunk init states, in place) ----------------
__global__ __launch_bounds__(256) void k4b_comb(const float* __restrict__ Alog,
                                                const float* __restrict__ Ts,
                                                float* __restrict__ q) {
  int t = blockIdx.x * 256 + threadIdx.x;
  if (t >= 8 * ECH * NCH) return;
  int n = t & 15, d = (t >> 4) % ECH, bk = t / (NCH * ECH);
  int k = bk & 3;
  float A = Alog[(k * ECH + d) * NCH + n];
  float h = 0.f;
  for (int c = 0; c < CCH; ++c) {
    int base = ((bk * CCH + c) * ECH + d) * NCH + n;
    float qc = q[base];
    q[base] = h;  // becomes h_init for chunk c
    float xv = A * Ts[(bk * CCH + c) * ECH + d];
    float P = (xv <= 0.05f)
                  ? fmaf(xv, fmaf(xv, fmaf(xv, -(1.f / 6.f), 0.5f), -1.f), 1.f)
                  : __expf(-xv);
    h = fmaf(P, h, qc);
  }
}

// ---------------- K4c: chunk scan pass2 (inline dlt) -> yd[b][k][l][E] plain stores ----------------
__global__ __launch_bounds__(256) void k4c_scan2(const float* __restrict__ dl6g,
                                                 const float* __restrict__ xi,
                                                 const float* __restrict__ bT,
                                                 const float* __restrict__ cT,
                                                 const float* __restrict__ Alog,
                                                 const float* __restrict__ dtw,
                                                 const float* __restrict__ dtb,
                                                 const float* __restrict__ hin,
                                                 float* __restrict__ yd) {
  const int cb = blockIdx.x;
  const int db = blockIdx.y;
  const int bk = blockIdx.z;
  const int b = bk >> 2, k = bk & 3;
  const int l0 = cb * 96;
  __shared__ __align__(16) float2 sdx[48 * 64];
  __shared__ __align__(16) float  sb[96 * NCH];
  __shared__ __align__(16) float  sc[96 * NCH];
  __shared__ __align__(16) float  sdl6[96 * 6];
  const int tid = threadIdx.x;
  const int dd = tid & 63, cg = tid >> 6;
  const int dg = db * 64 + dd;
  float b6 = dtb[k * ECH + dg];
  float w6[6];
  {
    const float2* d2 = (const float2*)(dtw + (k * ECH + dg) * 6);
    float2 u0 = d2[0], u1 = d2[1], u2 = d2[2];
    w6[0] = u0.x; w6[1] = u0.y; w6[2] = u1.x; w6[3] = u1.y; w6[4] = u2.x; w6[5] = u2.y;
  }
  for (int idx = tid; idx < 96 * 6; idx += 256) sdl6[idx] = dl6g[(bk * LTOT + l0) * 6 + idx];
  for (int idx = tid; idx < 96 * NCH; idx += 256) {
    sb[idx] = bT[(bk * LTOT + l0) * NCH + idx];
    sc[idx] = cT[(bk * LTOT + l0) * NCH + idx];
  }
  float C1[16], h[16];
  const int c = cb * 4 + cg;
  const float4* hp = (const float4*)(hin + ((bk * CCH + c) * ECH + dg) * NCH);
  {
    float4 h0 = hp[0], h1 = hp[1], h2 = hp[2], h3 = hp[3];
    h[0]=h0.x; h[1]=h0.y; h[2]=h0.z; h[3]=h0.w;
    h[4]=h1.x; h[5]=h1.y; h[6]=h1.z; h[7]=h1.w;
    h[8]=h2.x; h[9]=h2.y; h[10]=h2.z; h[11]=h2.w;
    h[12]=h3.x; h[13]=h3.y; h[14]=h3.z; h[15]=h3.w;
  }
#pragma unroll
  for (int n = 0; n < 16; ++n) C1[n] = Alog[(k * ECH + dg) * NCH + n];
  float* ydk = yd + (b * 4 + k) * LTOT * ECH;
  for (int half = 0; half < 2; ++half) {
    __syncthreads();
    for (int e = tid; e < 48 * 64; e += 256) {
      int s = e >> 6;
      int j = (s / 12) * 24 + half * 12 + (s % 12);
      const float* d6 = sdl6 + j * 6;
      float xa = b6;
#pragma unroll
      for (int r = 0; r < 6; ++r) xa = fmaf(w6[r], d6[r], xa);
      float dl = sp_fast(xa);
      int sp = permS(k, l0 + j);
      float xiv = xi[(b * LTOT + sp) * ECH + dg];
      sdx[s * 64 + dd] = make_float2(dl, xiv);
    }
    __syncthreads();
    for (int i = 0; i < 12; ++i) {
      int j = cg * 24 + half * 12 + i;
      float2 dx = sdx[(cg * 12 + i) * 64 + dd];
      float dl = dx.x;
      float u  = dl * dx.y;
      const float4* bb4 = (const float4*)(sb + j * NCH);
      float4 q0 = bb4[0], q1 = bb4[1], q2 = bb4[2], q3 = bb4[3];
      float bbl[16] = {q0.x, q0.y, q0.z, q0.w, q1.x, q1.y, q1.z, q1.w,
                       q2.x, q2.y, q2.z, q2.w, q3.x, q3.y, q3.z, q3.w};
      if (dl <= 0.018f) {
#pragma unroll
        for (int n = 0; n < 16; ++n) {
          float xn = C1[n] * dl;
          float e = fmaf(xn, fmaf(xn, fmaf(xn, -(1.f / 6.f), 0.5f), -1.f), 1.f);
          h[n] = fmaf(e, h[n], u * bbl[n]);
        }
      } else {
#pragma unroll
        for (int n = 0; n < 16; ++n) {
          float e = __expf(-C1[n] * dl);
          h[n] = fmaf(e, h[n], u * bbl[n]);
        }
      }
      const float4* cc4 = (const float4*)(sc + j * NCH);
      float4 c0 = cc4[0], c1 = cc4[1], c2 = cc4[2], c3 = cc4[3];
      float ccl[16] = {c0.x, c0.y, c0.z, c0.w, c1.x, c1.y, c1.z, c1.w,
                       c2.x, c2.y, c2.z, c2.w, c3.x, c3.y, c3.z, c3.w};
      float y = 0.f;
#pragma unroll
      for (int n = 0; n < 16; ++n) y = fmaf(h[n], ccl[n], y);
      int sp = permS(k, l0 + j);
      ydk[sp * ECH + dg] = y;
    }
  }
}

// ---------------- K5: LayerNorm over E (+Ds), sum 4 direction buffers, * z ----------------
__global__ __launch_bounds__(256) void k5_ln(const float* __restrict__ yd,
                                             const float* __restrict__ Ds,
                                             const float* __restrict__ lng,
                                             const float* __restrict__ lnb,
                                             float* __restrict__ zu) {
  int p = blockIdx.x * 4 + (threadIdx.x >> 6);
  int lane = threadIdx.x & 63;
  int b = (p >= LTOT) ? 1 : 0;
  int l = p - b * LTOT;
  const float* y0 = yd + (b * 4) * LTOT * ECH + l * ECH;
  float vd[3], sd[3];
#pragma unroll
  for (int t = 0; t < 3; ++t) {
    int d = lane + t * 64;
    vd[t] = ((y0[d] + y0[LTOT * ECH + d]) + y0[2 * LTOT * ECH + d]) + y0[3 * LTOT * ECH + d];
    sd[t] = Ds[d] + Ds[ECH + d] + Ds[2 * ECH + d] + Ds[3 * ECH + d];
  }
  float s1 = vd[0] + vd[1] + vd[2];
  float s2 = sd[0] + sd[1] + sd[2];
#pragma unroll
  for (int off = 32; off > 0; off >>= 1) {
    s1 += __shfl_xor(s1, off, 64);
    s2 += __shfl_xor(s2, off, 64);
  }
  float mean_dot = s1 * (1.f / 192.f);
  float mean_sd  = s2 * (1.f / 192.f);
  float dev[3];
  float ss = 0.f;
#pragma unroll
  for (int t = 0; t < 3; ++t) {
    dev[t] = (vd[t] - mean_dot) + (sd[t] - mean_sd);
    ss = fmaf(dev[t], dev[t], ss);
  }
#pragma unroll
  for (int off = 32; off > 0; off >>= 1) ss += __shfl_xor(ss, off, 64);
  float rstd = 1.f / sqrtf(ss * (1.f / 192.f) + 1e-5f);
#pragma unroll
  for (int t = 0; t < 3; ++t) {
    int d = lane + t * 64;
    float yn = (dev[t] * rstd) * lng[d] + lnb[d];
    zu[p * ECH + d] = yn * zu[p * ECH + d];
  }
}

// ---------------- K6: c1 1x1 GEMM (384x192) + bn1 + relu -> t1 (B,384,L); zeroes se ----------------
__global__ __launch_bounds__(256) void k6_c1(const float* __restrict__ u,
                                             const float* __restrict__ W,
                                             const float* __restrict__ c1b,
                                             const float* __restrict__ g1,
                                             const float* __restrict__ b1,
                                             const float* __restrict__ m1,
                                             const float* __restrict__ v1,
                                             float* __restrict__ t1,
                                             float* __restrict__ se) {
  const int l0 = blockIdx.x * 64;
  const int o0 = blockIdx.y * 64;
  const int b  = blockIdx.z;
  const int tid = threadIdx.x;
  if (blockIdx.x == 0 && blockIdx.y == 0 && blockIdx.z == 0 && tid < 192) se[tid] = 0.f;
  __shared__ __align__(16) float xs[96 * 66];  // [c][pos]
  __shared__ __align__(16) float Wl[96 * 68];  // [c][r]
  const int lane = tid & 63, w = tid >> 6;
  const int jj = lane & 15, rqq = lane >> 4;
  const int rbase = 16 * w + 4 * rqq;
  float acc[4][4];
#pragma unroll
  for (int p = 0; p < 4; ++p)
#pragma unroll
    for (int t = 0; t < 4; ++t) acc[p][t] = 0.f;
  for (int kc = 0; kc < 2; ++kc) {
    if (kc) __syncthreads();
    for (int idx = tid; idx < 64 * 96; idx += 256) {
      int i = idx / 96, cc = idx - i * 96;
      xs[cc * 66 + i] = u[(b * LTOT + l0 + i) * ECH + kc * 96 + cc];
    }
    for (int idx = tid; idx < 64 * 96; idx += 256) {
      int r = idx / 96, cc = idx - r * 96;
      Wl[cc * 68 + r] = W[(o0 + r) * ECH + kc * 96 + cc];
    }
    __syncthreads();
#pragma unroll 2
    for (int cc = 0; cc < 96; ++cc) {
      const float4 wv = *(const float4*)&Wl[cc * 68 + rbase];
      const float2 xa = *(const float2*)&xs[cc * 66 + 2 * jj];
      const float2 xb = *(const float2*)&xs[cc * 66 + 32 + 2 * jj];
      acc[0][0] = fmaf(wv.x, xa.x, acc[0][0]); acc[0][1] = fmaf(wv.y, xa.x, acc[0][1]);
      acc[0][2] = fmaf(wv.z, xa.x, acc[0][2]); acc[0][3] = fmaf(wv.w, xa.x, acc[0][3]);
      acc[1][0] = fmaf(wv.x, xa.y, acc[1][0]); acc[1][1] = fmaf(wv.y, xa.y, acc[1][1]);
      acc[1][2] = fmaf(wv.z, xa.y, acc[1][2]); acc[1][3] = fmaf(wv.w, xa.y, acc[1][3]);
      acc[2][0] = fmaf(wv.x, xb.x, acc[2][0]); acc[2][1] = fmaf(wv.y, xb.x, acc[2][1]);
      acc[2][2] = fmaf(wv.z, xb.x, acc[2][2]); acc[2][3] = fmaf(wv.w, xb.x, acc[2][3]);
      acc[3][0] = fmaf(wv.x, xb.y, acc[3][0]); acc[3][1] = fmaf(wv.y, xb.y, acc[3][1]);
      acc[3][2] = fmaf(wv.z, xb.y, acc[3][2]); acc[3][3] = fmaf(wv.w, xb.y, acc[3][3]);
    }
  }
#pragma unroll
  for (int t = 0; t < 4; ++t) {
    int o = o0 + rbase + t;
    float sc = g1[o] / sqrtf(v1[o] + 1e-5f);
    float bias = (c1b[o] - m1[o]) * sc + b1[o];
#pragma unroll
    for (int p = 0; p < 4; ++p) acc[p][t] = fmaxf(fmaf(acc[p][t], sc, bias), 0.f);
  }
  __syncthreads();
  float* ol = xs;  // [r][pos] pad 65
#pragma unroll
  for (int t = 0; t < 4; ++t) {
    ol[(rbase + t) * 65 + 2 * jj]      = acc[0][t];
    ol[(rbase + t) * 65 + 2 * jj + 1]  = acc[1][t];
    ol[(rbase + t) * 65 + 2 * jj + 32] = acc[2][t];
    ol[(rbase + t) * 65 + 2 * jj + 33] = acc[3][t];
  }
  __syncthreads();
  for (int idx = tid; idx < 64 * 64; idx += 256) {
    int pos = idx & 63, r = idx >> 6;
    t1[(b * 384 + o0 + r) * LTOT + l0 + pos] = ol[r * 65 + pos];
  }
}

// ---------------- K7: depthwise 3x3 on t1 (B,384,L) + bn2 + relu -> t2 (B,384,L) ----------------
__global__ __launch_bounds__(256) void k7_dw2(const float* __restrict__ t1,
                                              const float* __restrict__ cw,
                                              const float* __restrict__ cb,
                                              const float* __restrict__ g2,
                                              const float* __restrict__ b2,
                                              const float* __restrict__ m2,
                                              const float* __restrict__ v2,
                                              float* __restrict__ t2) {
  int g = blockIdx.x * 256 + threadIdx.x;
  if (g >= 2 * LTOT * 384) return;
  int l = g % LTOT; int o = (g / LTOT) % 384; int b = g / (LTOT * 384);
  int h = l / 48, wq = l % 48;
  const float* src = t1 + (b * 384 + o) * LTOT;
  float acc = cb[o];
#pragma unroll
  for (int kh = 0; kh < 3; ++kh) {
    int hh = h + kh - 1; if (hh < 0 || hh >= 48) continue;
#pragma unroll
    for (int kw = 0; kw < 3; ++kw) {
      int ww = wq + kw - 1; if (ww < 0 || ww >= 48) continue;
      acc = fmaf(cw[o * 9 + kh * 3 + kw], src[hh * 48 + ww], acc);
    }
  }
  float sc = g2[o] / sqrtf(v2[o] + 1e-5f);
  float val = (acc - m2[o]) * sc + b2[o];
  t2[g] = fmaxf(val, 0.f);
}

// ---------------- K8: c3 1x1 GEMM (96x384) on t2 (B,384,L) -> t3 (B,96,L) + SE sums ----------------
__global__ __launch_bounds__(256) void k8_c3(const float* __restrict__ t2,
                                             const float* __restrict__ W,
                                             const float* __restrict__ c3b,
                                             float* __restrict__ t3,
                                             float* __restrict__ se) {
  const int l0 = blockIdx.x * 64;  // 36
  const int r0 = blockIdx.y * 32;  // 3
  const int b  = blockIdx.z;       // 2
  __shared__ __align__(16) float xs[96 * 66];  // [c][pos]
  __shared__ __align__(16) float Wl[96 * 36];  // [c][r]
  const int tid = threadIdx.x;
  const int lane = tid & 63, w = tid >> 6;
  const int jj = lane & 15, rqq = lane >> 4;
  const int rloc = 8 * w + 2 * rqq;  // 2 rows
  float acc[4][2];
#pragma unroll
  for (int p = 0; p < 4; ++p) { acc[p][0] = 0.f; acc[p][1] = 0.f; }
  for (int kc = 0; kc < 4; ++kc) {
    if (kc) __syncthreads();
    for (int idx = tid; idx < 64 * 96; idx += 256) {
      int i = idx & 63, cc = idx >> 6;
      xs[cc * 66 + i] = t2[(b * 384 + kc * 96 + cc) * LTOT + l0 + i];
    }
    for (int idx = tid; idx < 32 * 96; idx += 256) {
      int r = idx / 96, cc = idx - r * 96;
      Wl[cc * 36 + r] = W[(r0 + r) * 384 + kc * 96 + cc];
    }
    __syncthreads();
#pragma unroll 2
    for (int cc = 0; cc < 96; ++cc) {
      const float2 wv = *(const float2*)&Wl[cc * 36 + rloc];
      const float2 xa = *(const float2*)&xs[cc * 66 + 2 * jj];
      const float2 xb = *(const float2*)&xs[cc * 66 + 32 + 2 * jj];
      acc[0][0] = fmaf(wv.x, xa.x, acc[0][0]); acc[0][1] = fmaf(wv.y, xa.x, acc[0][1]);
      acc[1][0] = fmaf(wv.x, xa.y, acc[1][0]); acc[1][1] = fmaf(wv.y, xa.y, acc[1][1]);
      acc[2][0] = fmaf(wv.x, xb.x, acc[2][0]); acc[2][1] = fmaf(wv.y, xb.x, acc[2][1]);
      acc[3][0] = fmaf(wv.x, xb.y, acc[3][0]); acc[3][1] = fmaf(wv.y, xb.y, acc[3][1]);
    }
  }
#pragma unroll
  for (int t = 0; t < 2; ++t) {
    float bias = c3b[r0 + rloc + t];
#pragma unroll
    for (int p = 0; p < 4; ++p) acc[p][t] += bias;
  }
#pragma unroll
  for (int t = 0; t < 2; ++t) {
    float v = acc[0][t] + acc[1][t] + acc[2][t] + acc[3][t];
    v += __shfl_xor(v, 1); v += __shfl_xor(v, 2);
    v += __shfl_xor(v, 4); v += __shfl_xor(v, 8);
    if (jj == 0) atomicAdd(&se[b * 96 + r0 + rloc + t], v);
  }
  __syncthreads();
  float* ol = xs;  // [r][pos] pad 65
#pragma unroll
  for (int t = 0; t < 2; ++t) {
    ol[(rloc + t) * 65 + 2 * jj]      = acc[0][t];
    ol[(rloc + t) * 65 + 2 * jj + 1]  = acc[1][t];
    ol[(rloc + t) * 65 + 2 * jj + 32] = acc[2][t];
    ol[(rloc + t) * 65 + 2 * jj + 33] = acc[3][t];
  }
  __syncthreads();
  for (int idx = tid; idx < 32 * 64; idx += 256) {
    int pos = idx & 63, r = idx >> 6;
    t3[(b * 96 + r0 + r) * LTOT + l0 + pos] = ol[r * 65 + pos];
  }
}

// ---------------- K9a: SE MLP -> smul = 1 + sigmoid(...) ----------------
__global__ __launch_bounds__(256) void k9a_se(const float* __restrict__ se,
                                              const float* __restrict__ w1,
                                              const float* __restrict__ sb1,
                                              const float* __restrict__ w2,
                                              const float* __restrict__ sb2,
                                              float* __restrict__ smul) {
  __shared__ float sm[192];
  __shared__ float s1[96];
  int t = threadIdx.x;
  if (t < 192) sm[t] = se[t] * (1.f / 2304.f);
  __syncthreads();
  if (t < 96) {
    int b = t / 48, i = t % 48;
    float acc = sb1[i];
    for (int m = 0; m < 96; ++m) acc = fmaf(w1[i * 96 + m], sm[b * 96 + m], acc);
    s1[t] = fmaxf(acc, 0.f);
  }
  __syncthreads();
  if (t < 192) {
    int b = t / 96, j = t % 96;
    float acc = sb2[j];
    for (int i = 0; i < 48; ++i) acc = fmaf(w2[j * 48 + i], s1[b * 48 + i], acc);
    smul[t] = 1.f + 1.f / (1.f + __expf(-acc));
  }
}

// ---------------- K9b: out[b,j,l] = t3[b,j,l] * smul[b,j] (pure streaming) ----------------
__global__ __launch_bounds__(256) void k9b_out(const float* __restrict__ t3,
                                               const float* __restrict__ smul,
                                               float* __restrict__ out) {
  int g = blockIdx.x * 256 + threadIdx.x;
  if (g >= 2 * 96 * LTOT) return;
  int bj = g / LTOT;
  out[g] = t3[g] * smul[bj];
}

extern "C" void kernel_launch(void* const* d_in, const int* in_sizes, int n_in,
                              void* d_out, int out_size, void* d_ws, size_t ws_size,
                              hipStream_t stream) {
  const float* x     = (const float*)d_in[0];
  const float* inw   = (const float*)d_in[1];
  const float* convw = (const float*)d_in[2];
  const float* convb = (const float*)d_in[3];
  const float* xpw   = (const float*)d_in[4];
  const float* dtw   = (const float*)d_in[5];
  const float* dtb   = (const float*)d_in[6];
  const float* Alog  = (const float*)d_in[7];
  const float* Ds    = (const float*)d_in[8];
  const float* lng   = (const float*)d_in[9];
  const float* lnb   = (const float*)d_in[10];
  const float* c1w   = (const float*)d_in[11];
  const float* c1b   = (const float*)d_in[12];
  const float* bn1g  = (const float*)d_in[13];
  const float* bn1b  = (const float*)d_in[14];
  const float* bn1m  = (const float*)d_in[15];
  const float* bn1v  = (const float*)d_in[16];
  const float* c2w   = (const float*)d_in[17];
  const float* c2b   = (const float*)d_in[18];
  const float* bn2g  = (const float*)d_in[19];
  const float* bn2b  = (const float*)d_in[20];
  const float* bn2m  = (const float*)d_in[21];
  const float* bn2v  = (const float*)d_in[22];
  const float* c3w   = (const float*)d_in[23];
  const float* c3b   = (const float*)d_in[24];
  const float* se1w  = (const float*)d_in[25];
  const float* se1b  = (const float*)d_in[26];
  const float* se2w  = (const float*)d_in[27];
  const float* se2b  = (const float*)d_in[28];

  float* ws = (float*)d_ws;
  float* xi_pre = ws;                    // 884736
  float* z      = ws + 884736;           // 884736 (becomes u after k5)
  float* xi     = ws + 1769472;          // 884736
  float* dl6g   = ws + 2654208;          // 110592
  float* bT     = ws + 2764800;          // 589824
  float* cT     = ws + 3354624;          // 589824
  float* q      = ws + 3944448;          // 2359296 ; t3 reuses (dead after k4c)
  float* Ts     = ws + 6303744;          // 147456
  float* se     = ws + 6451200;          // 192
  float* smul   = ws + 6451392;          // 192
  float* yd     = ws + 6451584;          // 3538944 ; t1/t2 reuse (dead after k5)
  float* t1 = yd;
  float* t2 = yd + 1769472;
  float* t3 = q;

  k1_inproj<<<dim3(36, 6, 2), 256, 0, stream>>>(x, inw, xi_pre, z);
  k2_dwconv<<<3456, 256, 0, stream>>>(xi_pre, convw, convb, xi);
  k3_xproj<<<dim3(72, 4, 2), 256, 0, stream>>>(xi, xpw, dl6g, bT, cT);
  k4a_scan1<<<dim3(24, 3, 8), 256, 0, stream>>>(dl6g, xi, bT, Alog, dtw, dtb, q, Ts);
  k4b_comb<<<96, 256, 0, stream>>>(Alog, Ts, q);
  k4c_scan2<<<dim3(24, 3, 8), 256, 0, stream>>>(dl6g, xi, bT, cT, Alog, dtw, dtb, q, yd);
  k5_ln<<<1152, 256, 0, stream>>>(yd, Ds, lng, lnb, z);
  k6_c1<<<dim3(36, 6, 2), 256, 0, stream>>>(z, c1w, c1b, bn1g, bn1b, bn1m, bn1v, t1, se);
  k7_dw2<<<6912, 256, 0, stream>>>(t1, c2w, c2b, bn2g, bn2b, bn2m, bn2v, t2);
  k8_c3<<<dim3(36, 3, 2), 256, 0, stream>>>(t2, c3w, c3b, t3, se);
  k9a_se<<<1, 256, 0, stream>>>(se, se1w, se1b, se2w, se2b, smul);
  k9b_out<<<1728, 256, 0, stream>>>(t3, smul, (float*)d_out);
}

// Round 7
// 317.512 us; speedup vs baseline: 1.4014x; 1.0364x over previous
//
#include <hip/hip_runtime.h>
#include <hip/hip_bf16.h>

#define LTOT 2304
#define ECH  192
#define NCH  16
#define CCH  96   // chunks over L
#define SCH  24   // steps per chunk

__device__ __forceinline__ int permS(int k, int l) {
  if (k == 0) return l;
  if (k == 1) return LTOT - 1 - l;
  int m = (k == 2) ? l : (LTOT - 1 - l);
  return (m % 48) * 48 + (m / 48);
}

// fast softplus for x ~ -9: t=e^x tiny -> log1p(t) ~= t(1 - t/2 + t^2/3)
__device__ __forceinline__ float sp_fast(float x) {
  float t = __expf(x);
  return (t <= 0.018f) ? t * fmaf(t, fmaf(t, 0.33333334f, -0.5f), 1.f) : log1pf(t);
}

// ---------------- K1: in_proj GEMM (384x96) -> xi_pre (B,L,E), z (B,L,E) ----------------
__global__ __launch_bounds__(256) void k1_inproj(const float* __restrict__ x,
                                                 const float* __restrict__ W,
                                                 float* __restrict__ xi_pre,
                                                 float* __restrict__ z) {
  const int l0 = blockIdx.x * 64;
  const int o0 = blockIdx.y * 64;
  const int b  = blockIdx.z;
  __shared__ __align__(16) float xs[96 * 66];  // [c][pos] pad 66
  __shared__ __align__(16) float Wl[96 * 68];  // [c][r]   pad 68
  const int tid = threadIdx.x;
  for (int idx = tid; idx < 96 * 64; idx += 256) {
    int i = idx & 63, cc = idx >> 6;
    xs[cc * 66 + i] = x[(b * 96 + cc) * LTOT + l0 + i];
  }
  for (int idx = tid; idx < 64 * 96; idx += 256) {
    int r = idx / 96, cc = idx - r * 96;
    Wl[cc * 68 + r] = W[(o0 + r) * 96 + cc];
  }
  __syncthreads();
  const int lane = tid & 63, w = tid >> 6;
  const int jj = lane & 15, rqq = lane >> 4;
  const int rbase = 16 * w + 4 * rqq;
  float acc[4][4];  // [p][t], pos(p) = (p>>1)*32 + 2*jj + (p&1)
#pragma unroll
  for (int p = 0; p < 4; ++p)
#pragma unroll
    for (int t = 0; t < 4; ++t) acc[p][t] = 0.f;
#pragma unroll 2
  for (int cc = 0; cc < 96; ++cc) {
    const float4 wv = *(const float4*)&Wl[cc * 68 + rbase];
    const float2 xa = *(const float2*)&xs[cc * 66 + 2 * jj];
    const float2 xb = *(const float2*)&xs[cc * 66 + 32 + 2 * jj];
    acc[0][0] = fmaf(wv.x, xa.x, acc[0][0]); acc[0][1] = fmaf(wv.y, xa.x, acc[0][1]);
    acc[0][2] = fmaf(wv.z, xa.x, acc[0][2]); acc[0][3] = fmaf(wv.w, xa.x, acc[0][3]);
    acc[1][0] = fmaf(wv.x, xa.y, acc[1][0]); acc[1][1] = fmaf(wv.y, xa.y, acc[1][1]);
    acc[1][2] = fmaf(wv.z, xa.y, acc[1][2]); acc[1][3] = fmaf(wv.w, xa.y, acc[1][3]);
    acc[2][0] = fmaf(wv.x, xb.x, acc[2][0]); acc[2][1] = fmaf(wv.y, xb.x, acc[2][1]);
    acc[2][2] = fmaf(wv.z, xb.x, acc[2][2]); acc[2][3] = fmaf(wv.w, xb.x, acc[2][3]);
    acc[3][0] = fmaf(wv.x, xb.y, acc[3][0]); acc[3][1] = fmaf(wv.y, xb.y, acc[3][1]);
    acc[3][2] = fmaf(wv.z, xb.y, acc[3][2]); acc[3][3] = fmaf(wv.w, xb.y, acc[3][3]);
  }
  __syncthreads();
  float* ol = xs;  // [r][pos] pad 65 (64*65 <= 96*66)
#pragma unroll
  for (int t = 0; t < 4; ++t) {
    ol[(rbase + t) * 65 + 2 * jj]      = acc[0][t];
    ol[(rbase + t) * 65 + 2 * jj + 1]  = acc[1][t];
    ol[(rbase + t) * 65 + 2 * jj + 32] = acc[2][t];
    ol[(rbase + t) * 65 + 2 * jj + 33] = acc[3][t];
  }
  __syncthreads();
  for (int idx = tid; idx < 64 * 64; idx += 256) {
    int r = idx & 63, pos = idx >> 6;
    float v = ol[r * 65 + pos];
    int o = o0 + r, l = l0 + pos;
    if (o < ECH) xi_pre[(b * LTOT + l) * ECH + o] = v;
    else         z[(b * LTOT + l) * ECH + (o - ECH)] = v;
  }
}

// ---------------- K2: depthwise 3x3 conv + SiLU -> xi (B,L,E) ----------------
__global__ __launch_bounds__(256) void k2_dwconv(const float* __restrict__ xi_pre,
                                                 const float* __restrict__ cw,
                                                 const float* __restrict__ cb,
                                                 float* __restrict__ xi) {
  int g = blockIdx.x * 256 + threadIdx.x;
  if (g >= 2 * LTOT * ECH) return;
  int e = g % ECH; int l = (g / ECH) % LTOT; int b = g / (ECH * LTOT);
  int h = l / 48, wq = l % 48;
  float acc = cb[e];
#pragma unroll
  for (int kh = 0; kh < 3; ++kh) {
    int hh = h + kh - 1; if (hh < 0 || hh >= 48) continue;
#pragma unroll
    for (int kw = 0; kw < 3; ++kw) {
      int ww = wq + kw - 1; if (ww < 0 || ww >= 48) continue;
      acc = fmaf(cw[e * 9 + kh * 3 + kw], xi_pre[(b * LTOT + hh * 48 + ww) * ECH + e], acc);
    }
  }
  xi[g] = acc / (1.f + __expf(-acc));
}

// ---------------- K3: x_proj (38x192) -> dl6g (rank-6), bT, cT. Pure GEMM. ----------------
__global__ __launch_bounds__(256) void k3_xproj(const float* __restrict__ xi,
                                                const float* __restrict__ xw,
                                                float* __restrict__ dl6g,
                                                float* __restrict__ bT,
                                                float* __restrict__ cT) {
  const int l0 = blockIdx.x * 32;  // 72
  const int k  = blockIdx.y;       // 4
  const int b  = blockIdx.z;       // 2
  __shared__ __align__(16) float xs[96 * 34];   // [c][j] per c-chunk, pad 34
  __shared__ __align__(16) float Wl[192 * 40];  // [c][r] pad 40
  __shared__ float dl6[6 * 33];
  const int tid = threadIdx.x;
  const float* wsrc = xw + k * 38 * ECH;
  for (int idx = tid; idx < 38 * 192; idx += 256) {
    int r = idx / 192, cc = idx - r * 192;
    Wl[cc * 40 + r] = wsrc[idx];
  }
  const int lane = tid & 63, w = tid >> 6;
  const int jj = lane & 15;
  const int rq = w * 4 + (lane >> 4);   // [0,16), active < 10
  const int rqc = rq < 9 ? rq : 9;
  const int j0 = 2 * jj;
  float a00 = 0.f, a01 = 0.f, a02 = 0.f, a03 = 0.f;
  float a10 = 0.f, a11 = 0.f, a12 = 0.f, a13 = 0.f;
  for (int kc = 0; kc < 2; ++kc) {
    __syncthreads();  // covers W staging (kc=0) and xs reuse (kc=1)
    for (int idx = tid; idx < 32 * 96; idx += 256) {
      int j = idx / 96, cc = idx - j * 96;
      int s = permS(k, l0 + j);
      xs[cc * 34 + j] = xi[(b * LTOT + s) * ECH + kc * 96 + cc];
    }
    __syncthreads();
#pragma unroll 4
    for (int cc = 0; cc < 96; ++cc) {
      const float2 xv = *(const float2*)&xs[cc * 34 + j0];
      const float4 wv = *(const float4*)&Wl[(kc * 96 + cc) * 40 + 4 * rqc];
      a00 = fmaf(wv.x, xv.x, a00); a01 = fmaf(wv.y, xv.x, a01);
      a02 = fmaf(wv.z, xv.x, a02); a03 = fmaf(wv.w, xv.x, a03);
      a10 = fmaf(wv.x, xv.y, a10); a11 = fmaf(wv.y, xv.y, a11);
      a12 = fmaf(wv.z, xv.y, a12); a13 = fmaf(wv.w, xv.y, a13);
    }
  }
  const int bk = b * 4 + k;
  if (rq < 10) {
    float av[2][4] = {{a00, a01, a02, a03}, {a10, a11, a12, a13}};
#pragma unroll
    for (int t = 0; t < 4; ++t) {
      int r = 4 * rq + t;
      if (r >= 38) continue;
#pragma unroll
      for (int p = 0; p < 2; ++p) {
        int j = j0 + p;
        float v = av[p][t];
        if (r < 6)       dl6g[((bk * LTOT) + l0 + j) * 6 + r] = v;
        else if (r < 22) bT[((bk * LTOT) + l0 + j) * NCH + (r - 6)] = v;
        else             cT[((bk * LTOT) + l0 + j) * NCH + (r - 22)] = v;
      }
    }
  }
}

// ---------------- K4a: chunk scan pass1 (inline dlt) -> q, Ts ----------------
__global__ __launch_bounds__(256) void k4a_scan1(const float* __restrict__ dl6g,
                                                 const float* __restrict__ xi,
                                                 const float* __restrict__ bT,
                                                 const float* __restrict__ Alog,
                                                 const float* __restrict__ dtw,
                                                 const float* __restrict__ dtb,
                                                 float* __restrict__ q,
                                                 float* __restrict__ Ts) {
  const int cb = blockIdx.x;  // 24
  const int db = blockIdx.y;  // 3
  const int bk = blockIdx.z;  // 8
  const int b = bk >> 2, k = bk & 3;
  const int l0 = cb * 96;
  __shared__ __align__(16) float2 sdx[48 * 64];   // half-staged (dl, xi)
  __shared__ __align__(16) float  sb[96 * NCH];
  __shared__ __align__(16) float  sdl6[96 * 6];
  const int tid = threadIdx.x;
  const int dd = tid & 63, cg = tid >> 6;
  const int dg = db * 64 + dd;
  float b6 = dtb[k * ECH + dg];
  float w6[6];
  {
    const float2* d2 = (const float2*)(dtw + (k * ECH + dg) * 6);
    float2 u0 = d2[0], u1 = d2[1], u2 = d2[2];
    w6[0] = u0.x; w6[1] = u0.y; w6[2] = u1.x; w6[3] = u1.y; w6[4] = u2.x; w6[5] = u2.y;
  }
  for (int idx = tid; idx < 96 * 6; idx += 256) sdl6[idx] = dl6g[(bk * LTOT + l0) * 6 + idx];
  for (int idx = tid; idx < 96 * NCH; idx += 256) sb[idx] = bT[(bk * LTOT + l0) * NCH + idx];
  float C1[16], h[16];
#pragma unroll
  for (int n = 0; n < 16; ++n) {
    C1[n] = Alog[(k * ECH + dg) * NCH + n];
    h[n] = 0.f;
  }
  float Tsum = 0.f;
  const int c = cb * 4 + cg;
  for (int half = 0; half < 2; ++half) {
    __syncthreads();
    for (int e = tid; e < 48 * 64; e += 256) {  // e&63 == dd always (stride 256)
      int s = e >> 6;
      int j = (s / 12) * 24 + half * 12 + (s % 12);
      const float* d6 = sdl6 + j * 6;
      float xa = b6;
#pragma unroll
      for (int r = 0; r < 6; ++r) xa = fmaf(w6[r], d6[r], xa);
      float dl = sp_fast(xa);
      int sp = permS(k, l0 + j);
      float xiv = xi[(b * LTOT + sp) * ECH + dg];
      sdx[s * 64 + dd] = make_float2(dl, xiv);
    }
    __syncthreads();
    for (int i = 0; i < 12; ++i) {
      int j = cg * 24 + half * 12 + i;
      float2 dx = sdx[(cg * 12 + i) * 64 + dd];
      float dl = dx.x;
      float u  = dl * dx.y;
      Tsum += dl;
      const float4* bb4 = (const float4*)(sb + j * NCH);
      float4 q0 = bb4[0], q1 = bb4[1], q2 = bb4[2], q3 = bb4[3];
      float bbl[16] = {q0.x, q0.y, q0.z, q0.w, q1.x, q1.y, q1.z, q1.w,
                       q2.x, q2.y, q2.z, q2.w, q3.x, q3.y, q3.z, q3.w};
      if (dl <= 0.018f) {
#pragma unroll
        for (int n = 0; n < 16; ++n) {
          float xn = C1[n] * dl;
          float e = fmaf(xn, fmaf(xn, fmaf(xn, -(1.f / 6.f), 0.5f), -1.f), 1.f);
          h[n] = fmaf(e, h[n], u * bbl[n]);
        }
      } else {
#pragma unroll
        for (int n = 0; n < 16; ++n) {
          float e = __expf(-C1[n] * dl);
          h[n] = fmaf(e, h[n], u * bbl[n]);
        }
      }
    }
  }
  float4* qp = (float4*)(q + ((bk * CCH + c) * ECH + dg) * NCH);
  qp[0] = make_float4(h[0], h[1], h[2], h[3]);
  qp[1] = make_float4(h[4], h[5], h[6], h[7]);
  qp[2] = make_float4(h[8], h[9], h[10], h[11]);
  qp[3] = make_float4(h[12], h[13], h[14], h[15]);
  Ts[(bk * CCH + c) * ECH + dg] = Tsum;
}

// ---------------- K4b: cross-chunk combine (q -> per-chunk init states, in place) ----------------
__global__ __launch_bounds__(256) void k4b_comb(const float* __restrict__ Alog,
                                                const float* __restrict__ Ts,
                                                float* __restrict__ q) {
  int t = blockIdx.x * 256 + threadIdx.x;
  if (t >= 8 * ECH * NCH) return;
  int n = t & 15, d = (t >> 4) % ECH, bk = t / (NCH * ECH);
  int k = bk & 3;
  float A = Alog[(k * ECH + d) * NCH + n];
  float h = 0.f;
  for (int c = 0; c < CCH; ++c) {
    int base = ((bk * CCH + c) * ECH + d) * NCH + n;
    float qc = q[base];
    q[base] = h;  // becomes h_init for chunk c
    float xv = A * Ts[(bk * CCH + c) * ECH + d];
    float P = (xv <= 0.05f)
                  ? fmaf(xv, fmaf(xv, fmaf(xv, -(1.f / 6.f), 0.5f), -1.f), 1.f)
                  : __expf(-xv);
    h = fmaf(P, h, qc);
  }
}

// ---------------- K4c: chunk scan pass2 (inline dlt) -> yd[b][k][l][E] plain stores ----------------
__global__ __launch_bounds__(256) void k4c_scan2(const float* __restrict__ dl6g,
                                                 const float* __restrict__ xi,
                                                 const float* __restrict__ bT,
                                                 const float* __restrict__ cT,
                                                 const float* __restrict__ Alog,
                                                 const float* __restrict__ dtw,
                                                 const float* __restrict__ dtb,
                                                 const float* __restrict__ hin,
                                                 float* __restrict__ yd) {
  const int cb = blockIdx.x;
  const int db = blockIdx.y;
  const int bk = blockIdx.z;
  const int b = bk >> 2, k = bk & 3;
  const int l0 = cb * 96;
  __shared__ __align__(16) float2 sdx[48 * 64];
  __shared__ __align__(16) float  sb[96 * NCH];
  __shared__ __align__(16) float  sc[96 * NCH];
  __shared__ __align__(16) float  sdl6[96 * 6];
  const int tid = threadIdx.x;
  const int dd = tid & 63, cg = tid >> 6;
  const int dg = db * 64 + dd;
  float b6 = dtb[k * ECH + dg];
  float w6[6];
  {
    const float2* d2 = (const float2*)(dtw + (k * ECH + dg) * 6);
    float2 u0 = d2[0], u1 = d2[1], u2 = d2[2];
    w6[0] = u0.x; w6[1] = u0.y; w6[2] = u1.x; w6[3] = u1.y; w6[4] = u2.x; w6[5] = u2.y;
  }
  for (int idx = tid; idx < 96 * 6; idx += 256) sdl6[idx] = dl6g[(bk * LTOT + l0) * 6 + idx];
  for (int idx = tid; idx < 96 * NCH; idx += 256) {
    sb[idx] = bT[(bk * LTOT + l0) * NCH + idx];
    sc[idx] = cT[(bk * LTOT + l0) * NCH + idx];
  }
  float C1[16], h[16];
  const int c = cb * 4 + cg;
  const float4* hp = (const float4*)(hin + ((bk * CCH + c) * ECH + dg) * NCH);
  {
    float4 h0 = hp[0], h1 = hp[1], h2 = hp[2], h3 = hp[3];
    h[0]=h0.x; h[1]=h0.y; h[2]=h0.z; h[3]=h0.w;
    h[4]=h1.x; h[5]=h1.y; h[6]=h1.z; h[7]=h1.w;
    h[8]=h2.x; h[9]=h2.y; h[10]=h2.z; h[11]=h2.w;
    h[12]=h3.x; h[13]=h3.y; h[14]=h3.z; h[15]=h3.w;
  }
#pragma unroll
  for (int n = 0; n < 16; ++n) C1[n] = Alog[(k * ECH + dg) * NCH + n];
  float* ydk = yd + (b * 4 + k) * LTOT * ECH;
  for (int half = 0; half < 2; ++half) {
    __syncthreads();
    for (int e = tid; e < 48 * 64; e += 256) {
      int s = e >> 6;
      int j = (s / 12) * 24 + half * 12 + (s % 12);
      const float* d6 = sdl6 + j * 6;
      float xa = b6;
#pragma unroll
      for (int r = 0; r < 6; ++r) xa = fmaf(w6[r], d6[r], xa);
      float dl = sp_fast(xa);
      int sp = permS(k, l0 + j);
      float xiv = xi[(b * LTOT + sp) * ECH + dg];
      sdx[s * 64 + dd] = make_float2(dl, xiv);
    }
    __syncthreads();
    for (int i = 0; i < 12; ++i) {
      int j = cg * 24 + half * 12 + i;
      float2 dx = sdx[(cg * 12 + i) * 64 + dd];
      float dl = dx.x;
      float u  = dl * dx.y;
      const float4* bb4 = (const float4*)(sb + j * NCH);
      float4 q0 = bb4[0], q1 = bb4[1], q2 = bb4[2], q3 = bb4[3];
      float bbl[16] = {q0.x, q0.y, q0.z, q0.w, q1.x, q1.y, q1.z, q1.w,
                       q2.x, q2.y, q2.z, q2.w, q3.x, q3.y, q3.z, q3.w};
      if (dl <= 0.018f) {
#pragma unroll
        for (int n = 0; n < 16; ++n) {
          float xn = C1[n] * dl;
          float e = fmaf(xn, fmaf(xn, fmaf(xn, -(1.f / 6.f), 0.5f), -1.f), 1.f);
          h[n] = fmaf(e, h[n], u * bbl[n]);
        }
      } else {
#pragma unroll
        for (int n = 0; n < 16; ++n) {
          float e = __expf(-C1[n] * dl);
          h[n] = fmaf(e, h[n], u * bbl[n]);
        }
      }
      const float4* cc4 = (const float4*)(sc + j * NCH);
      float4 c0 = cc4[0], c1 = cc4[1], c2 = cc4[2], c3 = cc4[3];
      float ccl[16] = {c0.x, c0.y, c0.z, c0.w, c1.x, c1.y, c1.z, c1.w,
                       c2.x, c2.y, c2.z, c2.w, c3.x, c3.y, c3.z, c3.w};
      float y = 0.f;
#pragma unroll
      for (int n = 0; n < 16; ++n) y = fmaf(h[n], ccl[n], y);
      int sp = permS(k, l0 + j);
      ydk[sp * ECH + dg] = y;
    }
  }
}

// ---------------- K5: LayerNorm over E (+Ds), sum 4 direction buffers, * z ----------------
__global__ __launch_bounds__(256) void k5_ln(const float* __restrict__ yd,
                                             const float* __restrict__ Ds,
                                             const float* __restrict__ lng,
                                             const float* __restrict__ lnb,
                                             float* __restrict__ zu) {
  int p = blockIdx.x * 4 + (threadIdx.x >> 6);
  int lane = threadIdx.x & 63;
  int b = (p >= LTOT) ? 1 : 0;
  int l = p - b * LTOT;
  const float* y0 = yd + (b * 4) * LTOT * ECH + l * ECH;
  float vd[3], sd[3];
#pragma unroll
  for (int t = 0; t < 3; ++t) {
    int d = lane + t * 64;
    vd[t] = ((y0[d] + y0[LTOT * ECH + d]) + y0[2 * LTOT * ECH + d]) + y0[3 * LTOT * ECH + d];
    sd[t] = Ds[d] + Ds[ECH + d] + Ds[2 * ECH + d] + Ds[3 * ECH + d];
  }
  float s1 = vd[0] + vd[1] + vd[2];
  float s2 = sd[0] + sd[1] + sd[2];
#pragma unroll
  for (int off = 32; off > 0; off >>= 1) {
    s1 += __shfl_xor(s1, off, 64);
    s2 += __shfl_xor(s2, off, 64);
  }
  float mean_dot = s1 * (1.f / 192.f);
  float mean_sd  = s2 * (1.f / 192.f);
  float dev[3];
  float ss = 0.f;
#pragma unroll
  for (int t = 0; t < 3; ++t) {
    dev[t] = (vd[t] - mean_dot) + (sd[t] - mean_sd);
    ss = fmaf(dev[t], dev[t], ss);
  }
#pragma unroll
  for (int off = 32; off > 0; off >>= 1) ss += __shfl_xor(ss, off, 64);
  float rstd = 1.f / sqrtf(ss * (1.f / 192.f) + 1e-5f);
#pragma unroll
  for (int t = 0; t < 3; ++t) {
    int d = lane + t * 64;
    float yn = (dev[t] * rstd) * lng[d] + lnb[d];
    zu[p * ECH + d] = yn * zu[p * ECH + d];
  }
}

// ---------------- K6: c1 1x1 GEMM (384x192) + bn1 + relu -> t1 (B,384,L); zeroes se ----------------
__global__ __launch_bounds__(256) void k6_c1(const float* __restrict__ u,
                                             const float* __restrict__ W,
                                             const float* __restrict__ c1b,
                                             const float* __restrict__ g1,
                                             const float* __restrict__ b1,
                                             const float* __restrict__ m1,
                                             const float* __restrict__ v1,
                                             float* __restrict__ t1,
                                             float* __restrict__ se) {
  const int l0 = blockIdx.x * 64;
  const int o0 = blockIdx.y * 64;
  const int b  = blockIdx.z;
  const int tid = threadIdx.x;
  if (blockIdx.x == 0 && blockIdx.y == 0 && blockIdx.z == 0 && tid < 192) se[tid] = 0.f;
  __shared__ __align__(16) float xs[96 * 66];  // [c][pos]
  __shared__ __align__(16) float Wl[96 * 68];  // [c][r]
  const int lane = tid & 63, w = tid >> 6;
  const int jj = lane & 15, rqq = lane >> 4;
  const int rbase = 16 * w + 4 * rqq;
  float acc[4][4];
#pragma unroll
  for (int p = 0; p < 4; ++p)
#pragma unroll
    for (int t = 0; t < 4; ++t) acc[p][t] = 0.f;
  for (int kc = 0; kc < 2; ++kc) {
    if (kc) __syncthreads();
    for (int idx = tid; idx < 64 * 96; idx += 256) {
      int i = idx / 96, cc = idx - i * 96;
      xs[cc * 66 + i] = u[(b * LTOT + l0 + i) * ECH + kc * 96 + cc];
    }
    for (int idx = tid; idx < 64 * 96; idx += 256) {
      int r = idx / 96, cc = idx - r * 96;
      Wl[cc * 68 + r] = W[(o0 + r) * ECH + kc * 96 + cc];
    }
    __syncthreads();
#pragma unroll 2
    for (int cc = 0; cc < 96; ++cc) {
      const float4 wv = *(const float4*)&Wl[cc * 68 + rbase];
      const float2 xa = *(const float2*)&xs[cc * 66 + 2 * jj];
      const float2 xb = *(const float2*)&xs[cc * 66 + 32 + 2 * jj];
      acc[0][0] = fmaf(wv.x, xa.x, acc[0][0]); acc[0][1] = fmaf(wv.y, xa.x, acc[0][1]);
      acc[0][2] = fmaf(wv.z, xa.x, acc[0][2]); acc[0][3] = fmaf(wv.w, xa.x, acc[0][3]);
      acc[1][0] = fmaf(wv.x, xa.y, acc[1][0]); acc[1][1] = fmaf(wv.y, xa.y, acc[1][1]);
      acc[1][2] = fmaf(wv.z, xa.y, acc[1][2]); acc[1][3] = fmaf(wv.w, xa.y, acc[1][3]);
      acc[2][0] = fmaf(wv.x, xb.x, acc[2][0]); acc[2][1] = fmaf(wv.y, xb.x, acc[2][1]);
      acc[2][2] = fmaf(wv.z, xb.x, acc[2][2]); acc[2][3] = fmaf(wv.w, xb.x, acc[2][3]);
      acc[3][0] = fmaf(wv.x, xb.y, acc[3][0]); acc[3][1] = fmaf(wv.y, xb.y, acc[3][1]);
      acc[3][2] = fmaf(wv.z, xb.y, acc[3][2]); acc[3][3] = fmaf(wv.w, xb.y, acc[3][3]);
    }
  }
#pragma unroll
  for (int t = 0; t < 4; ++t) {
    int o = o0 + rbase + t;
    float sc = g1[o] / sqrtf(v1[o] + 1e-5f);
    float bias = (c1b[o] - m1[o]) * sc + b1[o];
#pragma unroll
    for (int p = 0; p < 4; ++p) acc[p][t] = fmaxf(fmaf(acc[p][t], sc, bias), 0.f);
  }
  __syncthreads();
  float* ol = xs;  // [r][pos] pad 65
#pragma unroll
  for (int t = 0; t < 4; ++t) {
    ol[(rbase + t) * 65 + 2 * jj]      = acc[0][t];
    ol[(rbase + t) * 65 + 2 * jj + 1]  = acc[1][t];
    ol[(rbase + t) * 65 + 2 * jj + 32] = acc[2][t];
    ol[(rbase + t) * 65 + 2 * jj + 33] = acc[3][t];
  }
  __syncthreads();
  for (int idx = tid; idx < 64 * 64; idx += 256) {
    int pos = idx & 63, r = idx >> 6;
    t1[(b * 384 + o0 + r) * LTOT + l0 + pos] = ol[r * 65 + pos];
  }
}

// ---------------- K7: depthwise 3x3 on t1 (B,384,L) + bn2 + relu -> t2 (B,384,L) ----------------
__global__ __launch_bounds__(256) void k7_dw2(const float* __restrict__ t1,
                                              const float* __restrict__ cw,
                                              const float* __restrict__ cb,
                                              const float* __restrict__ g2,
                                              const float* __restrict__ b2,
                                              const float* __restrict__ m2,
                                              const float* __restrict__ v2,
                                              float* __restrict__ t2) {
  int g = blockIdx.x * 256 + threadIdx.x;
  if (g >= 2 * LTOT * 384) return;
  int l = g % LTOT; int o = (g / LTOT) % 384; int b = g / (LTOT * 384);
  int h = l / 48, wq = l % 48;
  const float* src = t1 + (b * 384 + o) * LTOT;
  float acc = cb[o];
#pragma unroll
  for (int kh = 0; kh < 3; ++kh) {
    int hh = h + kh - 1; if (hh < 0 || hh >= 48) continue;
#pragma unroll
    for (int kw = 0; kw < 3; ++kw) {
      int ww = wq + kw - 1; if (ww < 0 || ww >= 48) continue;
      acc = fmaf(cw[o * 9 + kh * 3 + kw], src[hh * 48 + ww], acc);
    }
  }
  float sc = g2[o] / sqrtf(v2[o] + 1e-5f);
  float val = (acc - m2[o]) * sc + b2[o];
  t2[g] = fmaxf(val, 0.f);
}

// ---------------- K8: c3 1x1 GEMM (96x384) on t2 (B,384,L) -> t3 (B,96,L) + SE sums ----------------
// v4: Ltile 32, rtile 32, grid 432; W staged ONCE [384c][34r] (broadcast b64);
// x staged in 2 K-halves [192c][34]; 4 barriers total. LDS 78KB -> 2 blocks/CU.
__global__ __launch_bounds__(256) void k8_c3(const float* __restrict__ t2,
                                             const float* __restrict__ W,
                                             const float* __restrict__ c3b,
                                             float* __restrict__ t3,
                                             float* __restrict__ se) {
  const int l0 = blockIdx.x * 32;  // 72
  const int r0 = blockIdx.y * 32;  // 3
  const int b  = blockIdx.z;       // 2
  __shared__ __align__(16) float Wl[384 * 34];  // [c][r] pad 34
  __shared__ __align__(16) float xs[192 * 34];  // [c][i] per K-half
  const int tid = threadIdx.x;
  const int lane = tid & 63, w = tid >> 6;
  const int jj = lane & 15, rqq = lane >> 4;
  const int rloc = 8 * w + 2 * rqq;  // 2 rows
  for (int idx = tid; idx < 32 * 384; idx += 256) {
    int r = idx / 384, cc = idx - r * 384;
    Wl[cc * 34 + r] = W[(r0 + r) * 384 + cc];
  }
  float acc[2][2];  // [pos][row]
  acc[0][0] = acc[0][1] = acc[1][0] = acc[1][1] = 0.f;
  for (int kc = 0; kc < 2; ++kc) {
    if (kc) __syncthreads();
    for (int idx = tid; idx < 192 * 32; idx += 256) {
      int i = idx & 31, cc = idx >> 5;
      xs[cc * 34 + i] = t2[(b * 384 + kc * 192 + cc) * LTOT + l0 + i];
    }
    __syncthreads();
#pragma unroll 4
    for (int cc = 0; cc < 192; ++cc) {
      const float2 wv = *(const float2*)&Wl[(kc * 192 + cc) * 34 + rloc];
      const float2 xv = *(const float2*)&xs[cc * 34 + 2 * jj];
      acc[0][0] = fmaf(wv.x, xv.x, acc[0][0]); acc[0][1] = fmaf(wv.y, xv.x, acc[0][1]);
      acc[1][0] = fmaf(wv.x, xv.y, acc[1][0]); acc[1][1] = fmaf(wv.y, xv.y, acc[1][1]);
    }
  }
  {
    float b0 = c3b[r0 + rloc], b1v = c3b[r0 + rloc + 1];
    acc[0][0] += b0; acc[1][0] += b0; acc[0][1] += b1v; acc[1][1] += b1v;
  }
#pragma unroll
  for (int t = 0; t < 2; ++t) {
    float v = acc[0][t] + acc[1][t];
    v += __shfl_xor(v, 1); v += __shfl_xor(v, 2);
    v += __shfl_xor(v, 4); v += __shfl_xor(v, 8);
    if (jj == 0) atomicAdd(&se[b * 96 + r0 + rloc + t], v);
  }
  __syncthreads();
  float* ol = xs;  // [r][pos] pad 33 (32*33 <= 192*34)
#pragma unroll
  for (int t = 0; t < 2; ++t) {
    ol[(rloc + t) * 33 + 2 * jj]     = acc[0][t];
    ol[(rloc + t) * 33 + 2 * jj + 1] = acc[1][t];
  }
  __syncthreads();
  for (int idx = tid; idx < 32 * 32; idx += 256) {
    int pos = idx & 31, r = idx >> 5;
    t3[(b * 96 + r0 + r) * LTOT + l0 + pos] = ol[r * 33 + pos];
  }
}

// ---------------- K9a: SE MLP -> smul = 1 + sigmoid(...) ----------------
__global__ __launch_bounds__(256) void k9a_se(const float* __restrict__ se,
                                              const float* __restrict__ w1,
                                              const float* __restrict__ sb1,
                                              const float* __restrict__ w2,
                                              const float* __restrict__ sb2,
                                              float* __restrict__ smul) {
  __shared__ float sm[192];
  __shared__ float s1[96];
  int t = threadIdx.x;
  if (t < 192) sm[t] = se[t] * (1.f / 2304.f);
  __syncthreads();
  if (t < 96) {
    int b = t / 48, i = t % 48;
    float acc = sb1[i];
    for (int m = 0; m < 96; ++m) acc = fmaf(w1[i * 96 + m], sm[b * 96 + m], acc);
    s1[t] = fmaxf(acc, 0.f);
  }
  __syncthreads();
  if (t < 192) {
    int b = t / 96, j = t % 96;
    float acc = sb2[j];
    for (int i = 0; i < 48; ++i) acc = fmaf(w2[j * 48 + i], s1[b * 48 + i], acc);
    smul[t] = 1.f + 1.f / (1.f + __expf(-acc));
  }
}

// ---------------- K9b: out[b,j,l] = t3[b,j,l] * smul[b,j] (pure streaming) ----------------
__global__ __launch_bounds__(256) void k9b_out(const float* __restrict__ t3,
                                               const float* __restrict__ smul,
                                               float* __restrict__ out) {
  int g = blockIdx.x * 256 + threadIdx.x;
  if (g >= 2 * 96 * LTOT) return;
  int bj = g / LTOT;
  out[g] = t3[g] * smul[bj];
}

extern "C" void kernel_launch(void* const* d_in, const int* in_sizes, int n_in,
                              void* d_out, int out_size, void* d_ws, size_t ws_size,
                              hipStream_t stream) {
  const float* x     = (const float*)d_in[0];
  const float* inw   = (const float*)d_in[1];
  const float* convw = (const float*)d_in[2];
  const float* convb = (const float*)d_in[3];
  const float* xpw   = (const float*)d_in[4];
  const float* dtw   = (const float*)d_in[5];
  const float* dtb   = (const float*)d_in[6];
  const float* Alog  = (const float*)d_in[7];
  const float* Ds    = (const float*)d_in[8];
  const float* lng   = (const float*)d_in[9];
  const float* lnb   = (const float*)d_in[10];
  const float* c1w   = (const float*)d_in[11];
  const float* c1b   = (const float*)d_in[12];
  const float* bn1g  = (const float*)d_in[13];
  const float* bn1b  = (const float*)d_in[14];
  const float* bn1m  = (const float*)d_in[15];
  const float* bn1v  = (const float*)d_in[16];
  const float* c2w   = (const float*)d_in[17];
  const float* c2b   = (const float*)d_in[18];
  const float* bn2g  = (const float*)d_in[19];
  const float* bn2b  = (const float*)d_in[20];
  const float* bn2m  = (const float*)d_in[21];
  const float* bn2v  = (const float*)d_in[22];
  const float* c3w   = (const float*)d_in[23];
  const float* c3b   = (const float*)d_in[24];
  const float* se1w  = (const float*)d_in[25];
  const float* se1b  = (const float*)d_in[26];
  const float* se2w  = (const float*)d_in[27];
  const float* se2b  = (const float*)d_in[28];

  float* ws = (float*)d_ws;
  float* xi_pre = ws;                    // 884736
  float* z      = ws + 884736;           // 884736 (becomes u after k5)
  float* xi     = ws + 1769472;          // 884736
  float* dl6g   = ws + 2654208;          // 110592
  float* bT     = ws + 2764800;          // 589824
  float* cT     = ws + 3354624;          // 589824
  float* q      = ws + 3944448;          // 2359296 ; t3 reuses (dead after k4c)
  float* Ts     = ws + 6303744;          // 147456
  float* se     = ws + 6451200;          // 192
  float* smul   = ws + 6451392;          // 192
  float* yd     = ws + 6451584;          // 3538944 ; t1/t2 reuse (dead after k5)
  float* t1 = yd;
  float* t2 = yd + 1769472;
  float* t3 = q;

  k1_inproj<<<dim3(36, 6, 2), 256, 0, stream>>>(x, inw, xi_pre, z);
  k2_dwconv<<<3456, 256, 0, stream>>>(xi_pre, convw, convb, xi);
  k3_xproj<<<dim3(72, 4, 2), 256, 0, stream>>>(xi, xpw, dl6g, bT, cT);
  k4a_scan1<<<dim3(24, 3, 8), 256, 0, stream>>>(dl6g, xi, bT, Alog, dtw, dtb, q, Ts);
  k4b_comb<<<96, 256, 0, stream>>>(Alog, Ts, q);
  k4c_scan2<<<dim3(24, 3, 8), 256, 0, stream>>>(dl6g, xi, bT, cT, Alog, dtw, dtb, q, yd);
  k5_ln<<<1152, 256, 0, stream>>>(yd, Ds, lng, lnb, z);
  k6_c1<<<dim3(36, 6, 2), 256, 0, stream>>>(z, c1w, c1b, bn1g, bn1b, bn1m, bn1v, t1, se);
  k7_dw2<<<6912, 256, 0, stream>>>(t1, c2w, c2b, bn2g, bn2b, bn2m, bn2v, t2);
  k8_c3<<<dim3(72, 3, 2), 256, 0, stream>>>(t2, c3w, c3b, t3, se);
  k9a_se<<<1, 256, 0, stream>>>(se, se1w, se1b, se2w, se2b, smul);
  k9b_out<<<1728, 256, 0, stream>>>(t3, smul, (float*)d_out);
}